// Round 6
// baseline (480.048 us; speedup 1.0000x reference)
//
#include <hip/hip_runtime.h>
#include <hip/hip_bf16.h>

// Problem constants
#define NN 10000
#define EE 160000
#define IN_DIM 128
#define HID 128
#define HEADS 8
#define F1 (HEADS*HID)   // 1024
#define INT_DIM 512
#define OUT_DIM 3
#define MPAD 10112       // 79 * 128

typedef __attribute__((ext_vector_type(8))) short bf16x8;
typedef __attribute__((ext_vector_type(4))) float f32x4;

// wave-local LDS fence: wait all this wave's DS ops, and pin program order
#define WAVE_SYNC() do { asm volatile("s_waitcnt lgkmcnt(0)" ::: "memory"); \
                         __builtin_amdgcn_sched_barrier(0); } while(0)

__device__ inline short f2bf(float v){
    union { __hip_bfloat16 b; short s; } u;
    u.b = __float2bfloat16(v);
    return u.s;
}
__device__ inline float bf2f(short s){
    union { short s; __hip_bfloat16 b; } u;
    u.s = s;
    return __bfloat162float(u.b);
}

// ---------------- CSR build ----------------
__global__ __launch_bounds__(256) void count_kernel(const int* __restrict__ dst, int E, int* __restrict__ cnt){
    int e = blockIdx.x*256 + threadIdx.x;
    if(e < E) atomicAdd(&cnt[dst[e]], 1);
}

__global__ __launch_bounds__(256) void scan_kernel(const int* __restrict__ cnt, int* __restrict__ rowp,
                                                   int* __restrict__ cursor, int n){
    __shared__ int sh[256];
    __shared__ int stotal;
    int t = threadIdx.x;
    if(t==0) stotal = 0;
    __syncthreads();
    for(int base=0; base<n; base+=256){
        int i = base + t;
        int v = (i<n) ? cnt[i] : 0;
        sh[t] = v;
        __syncthreads();
        #pragma unroll
        for(int off=1; off<256; off<<=1){
            int add = (t>=off) ? sh[t-off] : 0;
            __syncthreads();
            sh[t] += add;
            __syncthreads();
        }
        int excl = sh[t] - v;
        if(i<n){ rowp[i] = stotal + excl; cursor[i] = stotal + excl; }
        int chunk_total = sh[255];
        __syncthreads();
        if(t==0) stotal += chunk_total;
        __syncthreads();
    }
    if(t==0) rowp[n] = stotal;
}

__global__ __launch_bounds__(256) void fill_kernel(const int* __restrict__ src, const int* __restrict__ dst,
                                                   int E, int* __restrict__ cursor, int* __restrict__ colsrc){
    int e = blockIdx.x*256 + threadIdx.x;
    if(e < E){
        int d = dst[e];
        int pos = atomicAdd(&cursor[d], 1);
        colsrc[pos] = src[e];
    }
}

// ---------------- split + transpose weights: B[K,N] fp32 -> T_hi/T_lo [N,K] bf16 ----------------
__global__ __launch_bounds__(256) void splitT_kernel(const float* __restrict__ B, short* __restrict__ Th,
                                                     short* __restrict__ Tl, int K, int N){
    __shared__ float tile[32][33];
    const int tx = threadIdx.x & 31, ty = threadIdx.x >> 5;   // 32 x 8
    const int n0 = blockIdx.x * 32, k0 = blockIdx.y * 32;
    #pragma unroll
    for(int i = 0; i < 32; i += 8)
        tile[ty + i][tx] = B[(size_t)(k0 + ty + i) * N + n0 + tx];
    __syncthreads();
    #pragma unroll
    for(int i = 0; i < 32; i += 8){
        int n = ty + i;
        float v = tile[tx][n];             // = B[k0+tx][n0+n]
        short hv = f2bf(v);
        Th[(size_t)(n0 + n) * K + k0 + tx] = hv;
        Tl[(size_t)(n0 + n) * K + k0 + tx] = f2bf(v - bf2f(hv));
    }
}

// ---------------- aw1[j][k] = sum_c a[j][c] * W1[k, hj*128+c]  (j<8: a_src, j>=8: a_dst) ----------------
__global__ __launch_bounds__(256) void aw1_kernel(const float* __restrict__ W1,
                                                  const float* __restrict__ a_src,
                                                  const float* __restrict__ a_dst,
                                                  float* __restrict__ aw){
    int idx = blockIdx.x*256 + threadIdx.x;
    if(idx >= 16*IN_DIM) return;
    int j = idx >> 7, k = idx & 127;
    int hj = j & 7;
    const float* av = (j < 8 ? a_src : a_dst) + hj*HID;
    const float* wr = W1 + (size_t)k*F1 + hj*HID;
    float s = 0.f;
    #pragma unroll 4
    for(int c = 0; c < HID; c++) s += av[c] * wr[c];
    aw[idx] = s;
}

// ---------------- alpha1[n, j] = x[n,:] @ aw[j,:]  -> asrc/adst [NN,8] ----------------
__global__ __launch_bounds__(256) void alpha1_kernel(const float* __restrict__ x,
                                                     const float* __restrict__ aw,
                                                     float* __restrict__ asrc, float* __restrict__ adst){
    __shared__ float xs[16][128];
    __shared__ float aws[16][128];
    int t = threadIdx.x;
    int nb = blockIdx.x * 16;
    for(int i = t; i < 16*128; i += 256){
        xs[i >> 7][i & 127] = x[(size_t)nb*128 + i];
        aws[i >> 7][i & 127] = aw[i];
    }
    __syncthreads();
    int nl = t >> 4, j = t & 15;
    float s = 0.f;
    #pragma unroll 4
    for(int c = 0; c < 128; c++) s += xs[nl][c] * aws[j][c];
    int node = nb + nl;
    if(j < 8) asrc[node*8 + j] = s;
    else      adst[node*8 + (j-8)] = s;
}

// ---------------- agg1: per-head softmax-agg of RAW x; 4 nodes/block, 1 wave/node ----------------
__global__ __launch_bounds__(256) void agg1_kernel(const float* __restrict__ x,
                                                   const float* __restrict__ asrc,
                                                   const float* __restrict__ adst,
                                                   const int* __restrict__ rowp,
                                                   const int* __restrict__ colsrc,
                                                   short* __restrict__ oh, short* __restrict__ ol){
    const int w = threadIdx.x >> 6, l = threadIdx.x & 63;
    const int node = blockIdx.x*4 + w;
    __shared__ float sh_ee[4][64][8];
    int beg = rowp[node], end = rowp[node+1];
    float rd = adst[node*8 + (l & 7)];
    float acc0[8], acc1[8];
    #pragma unroll
    for(int h=0;h<8;h++){ acc0[h]=0.f; acc1[h]=0.f; }
    float dpart = 0.f;
    for(int base=beg; base<end; base+=64){
        int clen = min(64, end-base);
        WAVE_SYNC();                        // prior chunk's ee reads complete
        int sreg = (l < clen) ? colsrc[base + l] : 0;
        for(int it=l; it<clen*8; it+=64){
            int j = it >> 3;
            int s = colsrc[base + j];
            float e = asrc[s*8 + (l & 7)] + rd;
            e = (e > 0.f) ? e : 0.2f*e;
            float ee = expf(e);
            sh_ee[w][j][l & 7] = ee;
            dpart += ee;
        }
        WAVE_SYNC();                        // ee visible wave-wide
        #pragma unroll 2
        for(int j=0;j<clen;j++){
            int s = __shfl(sreg, j);
            float2 xv = ((const float2*)(x + (size_t)s*128))[l];
            #pragma unroll
            for(int h=0;h<8;h++){
                float wt = sh_ee[w][j][h];
                acc0[h] += wt * xv.x;
                acc1[h] += wt * xv.y;
            }
        }
    }
    dpart += __shfl_xor(dpart, 8);
    dpart += __shfl_xor(dpart, 16);
    dpart += __shfl_xor(dpart, 32);         // lane l holds denom for head l&7
    #pragma unroll
    for(int h=0;h<8;h++){
        float dn = __shfl(dpart, h) + 1e-16f;
        float v0 = acc0[h]/dn, v1 = acc1[h]/dn;
        short h0 = f2bf(v0), h1 = f2bf(v1);
        short2 hi = { h0, h1 };
        short2 lo = { f2bf(v0 - bf2f(h0)), f2bf(v1 - bf2f(h1)) };
        size_t off = (size_t)node*F1 + h*128 + 2*l;
        *(short2*)(oh + off) = hi;
        *(short2*)(ol + off) = lo;
    }
}

// ---------------- agg2: softmax-agg of h2 fp32 [1024]; 4 nodes/block, 1 wave/node ----------------
__global__ __launch_bounds__(256) void agg2_kernel(const float* __restrict__ hbuf,
                                                   const float* __restrict__ asrc,
                                                   const float* __restrict__ adst,
                                                   const int* __restrict__ rowp,
                                                   const int* __restrict__ colsrc,
                                                   const float* __restrict__ bias,
                                                   short* __restrict__ oh, short* __restrict__ ol){
    const int w = threadIdx.x >> 6, l = threadIdx.x & 63;
    const int node = blockIdx.x*4 + w;
    __shared__ float sh_ee[4][64][8];
    int beg = rowp[node], end = rowp[node+1];
    float rd = adst[node*8 + (l & 7)];
    float acc[16];
    #pragma unroll
    for(int k=0;k<16;k++) acc[k]=0.f;
    float dpart = 0.f;
    for(int base=beg; base<end; base+=64){
        int clen = min(64, end-base);
        WAVE_SYNC();
        int sreg = (l < clen) ? colsrc[base + l] : 0;
        for(int it=l; it<clen*8; it+=64){
            int j = it >> 3;
            int s = colsrc[base + j];
            float e = asrc[s*8 + (l & 7)] + rd;
            e = (e > 0.f) ? e : 0.2f*e;
            float ee = expf(e);
            sh_ee[w][j][l & 7] = ee;
            dpart += ee;
        }
        WAVE_SYNC();
        #pragma unroll 2
        for(int j=0;j<clen;j++){
            int s = __shfl(sreg, j);
            const float4* hr = (const float4*)(hbuf + (size_t)s*F1);
            #pragma unroll
            for(int k=0;k<4;k++){
                float4 v = hr[l + 64*k];
                float wt = sh_ee[w][j][2*k + (l>>5)];
                acc[4*k+0] += wt*v.x; acc[4*k+1] += wt*v.y;
                acc[4*k+2] += wt*v.z; acc[4*k+3] += wt*v.w;
            }
        }
    }
    dpart += __shfl_xor(dpart, 8);
    dpart += __shfl_xor(dpart, 16);
    dpart += __shfl_xor(dpart, 32);
    #pragma unroll
    for(int k=0;k<4;k++){
        float dn = __shfl(dpart, 2*k + (l>>5)) + 1e-16f;
        int f = 4*(l + 64*k);
        float4 bb = *(const float4*)(bias + f);
        float v0 = fmaxf(acc[4*k+0]/dn + bb.x, 0.f);
        float v1 = fmaxf(acc[4*k+1]/dn + bb.y, 0.f);
        float v2 = fmaxf(acc[4*k+2]/dn + bb.z, 0.f);
        float v3 = fmaxf(acc[4*k+3]/dn + bb.w, 0.f);
        short h0=f2bf(v0), h1=f2bf(v1), h2=f2bf(v2), h3=f2bf(v3);
        short4 hi = { h0, h1, h2, h3 };
        short4 lo = { f2bf(v0-bf2f(h0)), f2bf(v1-bf2f(h1)), f2bf(v2-bf2f(h2)), f2bf(v3-bf2f(h3)) };
        size_t off = (size_t)node*F1 + f;
        *(short4*)(oh + off) = hi;
        *(short4*)(ol + off) = lo;
    }
}

// ---------------- agg3: softmax-agg of h3 fp32 [512] H=1; 4 nodes/block, 1 wave/node, no LDS ----------------
__global__ __launch_bounds__(256) void agg3_kernel(const float* __restrict__ hbuf,
                                                   const float* __restrict__ asrc,
                                                   const float* __restrict__ adst,
                                                   const int* __restrict__ rowp,
                                                   const int* __restrict__ colsrc,
                                                   const float* __restrict__ bias,
                                                   short* __restrict__ oh, short* __restrict__ ol){
    const int w = threadIdx.x >> 6, l = threadIdx.x & 63;
    const int node = blockIdx.x*4 + w;
    int beg = rowp[node], end = rowp[node+1];
    float rd = adst[node];
    float acc[8];
    #pragma unroll
    for(int k=0;k<8;k++) acc[k]=0.f;
    float dpart = 0.f;
    for(int base=beg; base<end; base+=64){
        int clen = min(64, end-base);
        int sreg = 0; float eereg = 0.f;
        if(l < clen){
            sreg = colsrc[base + l];
            float e = asrc[sreg] + rd;
            e = (e > 0.f) ? e : 0.2f*e;
            eereg = expf(e);
            dpart += eereg;
        }
        #pragma unroll 2
        for(int j=0;j<clen;j++){
            int s = __shfl(sreg, j);
            float wt = __shfl(eereg, j);
            const float4* hr = (const float4*)(hbuf + (size_t)s*INT_DIM);
            #pragma unroll
            for(int k=0;k<2;k++){
                float4 v = hr[l + 64*k];
                acc[4*k+0] += wt*v.x; acc[4*k+1] += wt*v.y;
                acc[4*k+2] += wt*v.z; acc[4*k+3] += wt*v.w;
            }
        }
    }
    #pragma unroll
    for(int off=1; off<64; off<<=1) dpart += __shfl_xor(dpart, off);
    float dn = dpart + 1e-16f;
    #pragma unroll
    for(int k=0;k<2;k++){
        int f = 4*(l + 64*k);
        float4 bb = *(const float4*)(bias + f);
        float v0 = fmaxf(acc[4*k+0]/dn + bb.x, 0.f);
        float v1 = fmaxf(acc[4*k+1]/dn + bb.y, 0.f);
        float v2 = fmaxf(acc[4*k+2]/dn + bb.z, 0.f);
        float v3 = fmaxf(acc[4*k+3]/dn + bb.w, 0.f);
        short h0=f2bf(v0), h1=f2bf(v1), h2=f2bf(v2), h3=f2bf(v3);
        short4 hi = { h0, h1, h2, h3 };
        short4 lo = { f2bf(v0-bf2f(h0)), f2bf(v1-bf2f(h1)), f2bf(v2-bf2f(h2)), f2bf(v3-bf2f(h3)) };
        size_t off = (size_t)node*INT_DIM + f;
        *(short4*)(oh + off) = hi;
        *(short4*)(ol + off) = lo;
    }
}

// ---------------- fused split-bf16 MFMA GEMM (generalized: lda/ldb/ldc, blockIdx.z offsets) ----------------
template<int FUSE, int SPLIT>
__global__ __launch_bounds__(256) void mfma_gemm_kernel(
    const short* __restrict__ Ah, const short* __restrict__ Al, int lda, int za,
    const short* __restrict__ Bh, const short* __restrict__ Bl, int ldb, int zb,
    const float* __restrict__ bias, float* __restrict__ C,
    short* __restrict__ Gh, short* __restrict__ Gl, int ldc, int zc,
    int K, int gx)
{
    __shared__ short lAh[128*32];   // 8 KB each
    __shared__ short lAl[128*32];
    __shared__ short lBh[128*32];
    __shared__ short lBl[128*32];
    const int tid  = threadIdx.x;
    const int lane = tid & 63;
    const int w    = tid >> 6;
    const int wm   = w >> 1, wn = w & 1;
    const int z    = blockIdx.z;

    // XCD-bijective swizzle
    const int nwg = gridDim.x;
    const int q = nwg >> 3, r = nwg & 7;
    const int xcd = blockIdx.x & 7, idx = blockIdx.x >> 3;
    const int wgid = (xcd < r ? xcd*(q+1) : r*(q+1) + (xcd-r)*q) + idx;
    const int row0 = (wgid / gx) * 128, col0 = (wgid % gx) * 128;

    f32x4 acc[4][4];
    #pragma unroll
    for(int i=0;i<4;i++)
        #pragma unroll
        for(int j=0;j<4;j++) acc[i][j] = (f32x4){0.f,0.f,0.f,0.f};

    const int r1 = tid >> 2,  s1 = (tid & 3) ^ (r1 & 3);
    const int r2 = r1 + 64,   s2 = (tid & 3) ^ (r2 & 3);
    const size_t aoff1 = (size_t)(row0 + r1) * lda + (size_t)z*za + s1 * 8;
    const size_t aoff2 = (size_t)(row0 + r2) * lda + (size_t)z*za + s2 * 8;
    const size_t boff1 = (size_t)(col0 + r1) * ldb + (size_t)z*zb + s1 * 8;
    const size_t boff2 = (size_t)(col0 + r2) * ldb + (size_t)z*zb + s2 * 8;

    typedef __attribute__((address_space(3))) char lds_char;
    lds_char* dAh1 = (lds_char*)(&lAh[0]) + w*1024;  lds_char* dAh2 = dAh1 + 4096;
    lds_char* dAl1 = (lds_char*)(&lAl[0]) + w*1024;  lds_char* dAl2 = dAl1 + 4096;
    lds_char* dBh1 = (lds_char*)(&lBh[0]) + w*1024;  lds_char* dBh2 = dBh1 + 4096;
    lds_char* dBl1 = (lds_char*)(&lBl[0]) + w*1024;  lds_char* dBl2 = dBl1 + 4096;

    int arow[4], brow[4];
    const int slotx = ((lane >> 4) ^ (lane & 3)) << 4;
    #pragma unroll
    for(int i=0;i<4;i++){
        arow[i] = (wm*64 + i*16 + (lane & 15)) * 64 + slotx;
        brow[i] = (wn*64 + i*16 + (lane & 15)) * 64 + slotx;
    }

    #pragma unroll 1
    for(int k0 = 0; k0 < K; k0 += 32){
        __syncthreads();
        #define GLDS(src, dst) __builtin_amdgcn_global_load_lds( \
            (__attribute__((address_space(1))) void*)(src), \
            (__attribute__((address_space(3))) void*)(dst), 16, 0, 0)
        GLDS(Ah + aoff1 + k0, dAh1);  GLDS(Ah + aoff2 + k0, dAh2);
        GLDS(Al + aoff1 + k0, dAl1);  GLDS(Al + aoff2 + k0, dAl2);
        GLDS(Bh + boff1 + k0, dBh1);  GLDS(Bh + boff2 + k0, dBh2);
        GLDS(Bl + boff1 + k0, dBl1);  GLDS(Bl + boff2 + k0, dBl2);
        #undef GLDS
        __syncthreads();
        bf16x8 afh[4], afl[4];
        #pragma unroll
        for(int i=0;i<4;i++){
            afh[i] = *(const bf16x8*)((const char*)lAh + arow[i]);
            afl[i] = *(const bf16x8*)((const char*)lAl + arow[i]);
        }
        #pragma unroll
        for(int j=0;j<4;j++){
            bf16x8 bh = *(const bf16x8*)((const char*)lBh + brow[j]);
            bf16x8 bl = *(const bf16x8*)((const char*)lBl + brow[j]);
            #pragma unroll
            for(int i=0;i<4;i++){
                acc[i][j] = __builtin_amdgcn_mfma_f32_16x16x32_bf16(afh[i], bh, acc[i][j], 0, 0, 0);
                acc[i][j] = __builtin_amdgcn_mfma_f32_16x16x32_bf16(afh[i], bl, acc[i][j], 0, 0, 0);
                acc[i][j] = __builtin_amdgcn_mfma_f32_16x16x32_bf16(afl[i], bh, acc[i][j], 0, 0, 0);
            }
        }
    }

    // epilogue: C/D layout col=lane&15, row=(lane>>4)*4+reg
    #pragma unroll
    for(int i=0;i<4;i++){
        const int rr = row0 + wm*64 + i*16 + ((lane >> 4) << 2);
        #pragma unroll
        for(int j=0;j<4;j++){
            const int gc = z*zc + col0 + wn*64 + j*16 + (lane & 15);
            float b = FUSE ? bias[gc] : 0.f;
            #pragma unroll
            for(int rg=0;rg<4;rg++){
                float v = acc[i][j][rg];
                if(FUSE) v = fmaxf(v + b, 0.f);
                if(SPLIT){
                    short hv = f2bf(v);
                    Gh[(size_t)(rr + rg) * ldc + gc] = hv;
                    Gl[(size_t)(rr + rg) * ldc + gc] = f2bf(v - bf2f(hv));
                } else {
                    C[(size_t)(rr + rg) * ldc + gc] = v;
                }
            }
        }
    }
}

// ---------------- alpha: per-node per-head dot(h[n,h,:], a[h,:])  (project-first layers) ----------------
template<int H, int C>
__global__ __launch_bounds__(128) void alpha_kernel(const float* __restrict__ hbuf,
                                                    const float* __restrict__ a_src,
                                                    const float* __restrict__ a_dst,
                                                    float* __restrict__ asrc, float* __restrict__ adst, int n){
    constexpr int F = H*C;
    int node = blockIdx.x;
    int t = threadIdx.x;          // 128 threads
    float ps[H], pd[H];
    #pragma unroll
    for(int h=0;h<H;h++){ ps[h]=0.f; pd[h]=0.f; }
    #pragma unroll
    for(int k=0;k<F/128;k++){
        int idx = t + k*128;
        int h = (k*128)/C;
        float v = hbuf[(size_t)node*F + idx];
        ps[h] += v * a_src[idx];
        pd[h] += v * a_dst[idx];
    }
    int lane = t & 63, wv = t >> 6;
    __shared__ float shs[2][H], shd[2][H];
    #pragma unroll
    for(int h=0;h<H;h++){
        float v = ps[h], w2 = pd[h];
        #pragma unroll
        for(int off=32; off; off>>=1){ v += __shfl_down(v, off); w2 += __shfl_down(w2, off); }
        if(lane==0){ shs[wv][h]=v; shd[wv][h]=w2; }
    }
    __syncthreads();
    if(t < H){
        asrc[(size_t)node*H + t] = shs[0][t] + shs[1][t];
        adst[(size_t)node*H + t] = shd[0][t] + shd[1][t];
    }
}

// ---------------- classifier: out[n,3] = h[n,:512] @ Wc + bc ----------------
__global__ __launch_bounds__(256) void cls_kernel(const float* __restrict__ h, const float* __restrict__ Wc,
                                                  const float* __restrict__ bc, float* __restrict__ out, int n){
    int node = blockIdx.x*4 + (threadIdx.x >> 6);
    int lane = threadIdx.x & 63;
    if(node >= n) return;
    float s0=0.f, s1=0.f, s2=0.f;
    const float* hr = h + (size_t)node*INT_DIM;
    for(int k=lane; k<INT_DIM; k+=64){
        float v = hr[k];
        s0 += v * Wc[k*3+0];
        s1 += v * Wc[k*3+1];
        s2 += v * Wc[k*3+2];
    }
    #pragma unroll
    for(int off=32; off; off>>=1){
        s0 += __shfl_down(s0, off);
        s1 += __shfl_down(s1, off);
        s2 += __shfl_down(s2, off);
    }
    if(lane==0){
        out[(size_t)node*3+0] = s0 + bc[0];
        out[(size_t)node*3+1] = s1 + bc[1];
        out[(size_t)node*3+2] = s2 + bc[2];
    }
}

extern "C" void kernel_launch(void* const* d_in, const int* in_sizes, int n_in,
                              void* d_out, int out_size, void* d_ws, size_t ws_size,
                              hipStream_t stream){
    const float* x      = (const float*)d_in[0];
    const int*   ei     = (const int*)d_in[1];
    const float* W1     = (const float*)d_in[2];
    const float* a_src1 = (const float*)d_in[3];
    const float* a_dst1 = (const float*)d_in[4];
    const float* b1     = (const float*)d_in[5];
    const float* W2     = (const float*)d_in[6];
    const float* a_src2 = (const float*)d_in[7];
    const float* a_dst2 = (const float*)d_in[8];
    const float* b2     = (const float*)d_in[9];
    const float* W3     = (const float*)d_in[10];
    const float* a_src3 = (const float*)d_in[11];
    const float* a_dst3 = (const float*)d_in[12];
    const float* b3     = (const float*)d_in[13];
    const float* Wl     = (const float*)d_in[14];
    const float* bl     = (const float*)d_in[15];
    const float* Wc     = (const float*)d_in[16];
    const float* bc     = (const float*)d_in[17];
    float* out = (float*)d_out;

    const int* src = ei;
    const int* dst = ei + EE;

    // workspace carve: two big regions (41.4 MB each) + weights + small
    char* p = (char*)d_ws;
    char* regA = p;  p += (size_t)MPAD*F1*4;            // pair {ph,pl} OR fp32 buffer
    char* regB = p;  p += (size_t)MPAD*F1*4;            // pair {qh,ql}
    short* wt_h = (short*)p;  p += (size_t)F1*F1*2;     // 2.1 MB
    short* wt_l = (short*)p;  p += (size_t)F1*F1*2;     // 2.1 MB
    float* aw1  = (float*)p;  p += 16*IN_DIM*4;
    float* asrc = (float*)p;  p += (size_t)NN*HEADS*4;
    float* adst = (float*)p;  p += (size_t)NN*HEADS*4;
    int* cnt    = (int*)p;    p += NN*4;
    int* rowp   = (int*)p;    p += (NN+1)*4;
    int* cursor = (int*)p;    p += NN*4;
    int* colsrc = (int*)p;    p += EE*4;

    short* ph = (short*)regA;  short* pl = ph + (size_t)MPAD*F1;
    float* Af = (float*)regA;
    short* qh = (short*)regB;  short* ql = qh + (size_t)MPAD*F1;

    // ---- CSR build (by dst) ----
    hipMemsetAsync(cnt, 0, NN*sizeof(int), stream);
    count_kernel<<<(EE+255)/256, 256, 0, stream>>>(dst, EE, cnt);
    scan_kernel<<<1, 256, 0, stream>>>(cnt, rowp, cursor, NN);
    fill_kernel<<<(EE+255)/256, 256, 0, stream>>>(src, dst, EE, cursor, colsrc);

    // ---- Layer 1 (agg-first via linearity) ----
    splitT_kernel<<<dim3(F1/32, IN_DIM/32), 256, 0, stream>>>(W1, wt_h, wt_l, IN_DIM, F1);
    aw1_kernel<<<8, 256, 0, stream>>>(W1, a_src1, a_dst1, aw1);
    alpha1_kernel<<<NN/16, 256, 0, stream>>>(x, aw1, asrc, adst);
    agg1_kernel<<<NN/4, 256, 0, stream>>>(x, asrc, adst, rowp, colsrc, ph, pl);
    // out1 = relu(xa @ W1 + b1), block-diagonal per head, split output -> regB
    mfma_gemm_kernel<1,1><<<dim3(MPAD/128, 1, HEADS), 256, 0, stream>>>(
        ph, pl, F1, 128,  wt_h, wt_l, IN_DIM, 128*IN_DIM,
        b1, nullptr, qh, ql, F1, 128,  IN_DIM, 1);

    // ---- Layer 2 (project-first) ----
    splitT_kernel<<<dim3(F1/32, F1/32), 256, 0, stream>>>(W2, wt_h, wt_l, F1, F1);
    mfma_gemm_kernel<0,0><<<dim3((F1/128)*(MPAD/128), 1, 1), 256, 0, stream>>>(
        qh, ql, F1, 0,  wt_h, wt_l, F1, 0,
        nullptr, Af, nullptr, nullptr, F1, 0,  F1, F1/128);
    alpha_kernel<HEADS, HID><<<NN, 128, 0, stream>>>(Af, a_src2, a_dst2, asrc, adst, NN);
    agg2_kernel<<<NN/4, 256, 0, stream>>>(Af, asrc, adst, rowp, colsrc, b2, qh, ql);

    // ---- Layer 3 (project-first, H=1) ----
    splitT_kernel<<<dim3(INT_DIM/32, F1/32), 256, 0, stream>>>(W3, wt_h, wt_l, F1, INT_DIM);
    mfma_gemm_kernel<0,0><<<dim3((INT_DIM/128)*(MPAD/128), 1, 1), 256, 0, stream>>>(
        qh, ql, F1, 0,  wt_h, wt_l, F1, 0,
        nullptr, Af, nullptr, nullptr, INT_DIM, 0,  F1, INT_DIM/128);
    alpha_kernel<1, INT_DIM><<<NN, 128, 0, stream>>>(Af, a_src3, a_dst3, asrc, adst, NN);
    agg3_kernel<<<NN/4, 256, 0, stream>>>(Af, asrc, adst, rowp, colsrc, b3, qh, ql);

    // ---- Linear: relu(out3 @ Wl + bl) -> Af fp32 [NN,512] ----
    splitT_kernel<<<dim3(INT_DIM/32, INT_DIM/32), 256, 0, stream>>>(Wl, wt_h, wt_l, INT_DIM, INT_DIM);
    mfma_gemm_kernel<1,0><<<dim3((INT_DIM/128)*(MPAD/128), 1, 1), 256, 0, stream>>>(
        qh, ql, INT_DIM, 0,  wt_h, wt_l, INT_DIM, 0,
        bl, Af, nullptr, nullptr, INT_DIM, 0,  INT_DIM, INT_DIM/128);

    // ---- Classifier ----
    cls_kernel<<<(NN+3)/4, 256, 0, stream>>>(Af, Wc, bc, out, NN);
}

// Round 7
// 475.016 us; speedup vs baseline: 1.0106x; 1.0106x over previous
//
#include <hip/hip_runtime.h>
#include <hip/hip_bf16.h>

// Problem constants
#define NN 10000
#define EE 160000
#define IN_DIM 128
#define HID 128
#define HEADS 8
#define F1 (HEADS*HID)   // 1024
#define INT_DIM 512
#define OUT_DIM 3
#define MPAD 10112       // 79 * 128

typedef __attribute__((ext_vector_type(8))) short bf16x8;
typedef __attribute__((ext_vector_type(4))) float f32x4;

// wave-local LDS fence: wait all this wave's DS ops, and pin program order
#define WAVE_SYNC() do { asm volatile("s_waitcnt lgkmcnt(0)" ::: "memory"); \
                         __builtin_amdgcn_sched_barrier(0); } while(0)

__device__ inline short f2bf(float v){
    union { __hip_bfloat16 b; short s; } u;
    u.b = __float2bfloat16(v);
    return u.s;
}
__device__ inline float bf2f(short s){
    union { short s; __hip_bfloat16 b; } u;
    u.s = s;
    return __bfloat162float(u.b);
}

// ---------------- CSR build ----------------
__global__ __launch_bounds__(256) void count_kernel(const int* __restrict__ dst, int E, int* __restrict__ cnt){
    int e = blockIdx.x*256 + threadIdx.x;
    if(e < E) atomicAdd(&cnt[dst[e]], 1);
}

__global__ __launch_bounds__(256) void scan_kernel(const int* __restrict__ cnt, int* __restrict__ rowp,
                                                   int* __restrict__ cursor, int n){
    __shared__ int sh[256];
    __shared__ int stotal;
    int t = threadIdx.x;
    if(t==0) stotal = 0;
    __syncthreads();
    for(int base=0; base<n; base+=256){
        int i = base + t;
        int v = (i<n) ? cnt[i] : 0;
        sh[t] = v;
        __syncthreads();
        #pragma unroll
        for(int off=1; off<256; off<<=1){
            int add = (t>=off) ? sh[t-off] : 0;
            __syncthreads();
            sh[t] += add;
            __syncthreads();
        }
        int excl = sh[t] - v;
        if(i<n){ rowp[i] = stotal + excl; cursor[i] = stotal + excl; }
        int chunk_total = sh[255];
        __syncthreads();
        if(t==0) stotal += chunk_total;
        __syncthreads();
    }
    if(t==0) rowp[n] = stotal;
}

__global__ __launch_bounds__(256) void fill_kernel(const int* __restrict__ src, const int* __restrict__ dst,
                                                   int E, int* __restrict__ cursor, int* __restrict__ colsrc){
    int e = blockIdx.x*256 + threadIdx.x;
    if(e < E){
        int d = dst[e];
        int pos = atomicAdd(&cursor[d], 1);
        colsrc[pos] = src[e];
    }
}

// ---------------- split + transpose weights: B[K,N] fp32 -> T_hi/T_lo [N,K] bf16 ----------------
__global__ __launch_bounds__(256) void splitT_kernel(const float* __restrict__ B, short* __restrict__ Th,
                                                     short* __restrict__ Tl, int K, int N){
    __shared__ float tile[32][33];
    const int tx = threadIdx.x & 31, ty = threadIdx.x >> 5;   // 32 x 8
    const int n0 = blockIdx.x * 32, k0 = blockIdx.y * 32;
    #pragma unroll
    for(int i = 0; i < 32; i += 8)
        tile[ty + i][tx] = B[(size_t)(k0 + ty + i) * N + n0 + tx];
    __syncthreads();
    #pragma unroll
    for(int i = 0; i < 32; i += 8){
        int n = ty + i;
        float v = tile[tx][n];             // = B[k0+tx][n0+n]
        short hv = f2bf(v);
        Th[(size_t)(n0 + n) * K + k0 + tx] = hv;
        Tl[(size_t)(n0 + n) * K + k0 + tx] = f2bf(v - bf2f(hv));
    }
}

// ---------------- aw1[j][k] = sum_c a[j][c] * W1[k, hj*128+c]  (j<8: a_src, j>=8: a_dst) ----------------
__global__ __launch_bounds__(256) void aw1_kernel(const float* __restrict__ W1,
                                                  const float* __restrict__ a_src,
                                                  const float* __restrict__ a_dst,
                                                  float* __restrict__ aw){
    int idx = blockIdx.x*256 + threadIdx.x;
    if(idx >= 16*IN_DIM) return;
    int j = idx >> 7, k = idx & 127;
    int hj = j & 7;
    const float* av = (j < 8 ? a_src : a_dst) + hj*HID;
    const float* wr = W1 + (size_t)k*F1 + hj*HID;
    float s = 0.f;
    #pragma unroll 4
    for(int c = 0; c < HID; c++) s += av[c] * wr[c];
    aw[idx] = s;
}

// ---------------- alpha1[n, j] = x[n,:] @ aw[j,:]  -> asrc/adst [NN,8] ----------------
__global__ __launch_bounds__(256) void alpha1_kernel(const float* __restrict__ x,
                                                     const float* __restrict__ aw,
                                                     float* __restrict__ asrc, float* __restrict__ adst){
    __shared__ float xs[16][128];
    __shared__ float aws[16][128];
    int t = threadIdx.x;
    int nb = blockIdx.x * 16;
    for(int i = t; i < 16*128; i += 256){
        xs[i >> 7][i & 127] = x[(size_t)nb*128 + i];
        aws[i >> 7][i & 127] = aw[i];
    }
    __syncthreads();
    int nl = t >> 4, j = t & 15;
    float s = 0.f;
    #pragma unroll 4
    for(int c = 0; c < 128; c++) s += xs[nl][c] * aws[j][c];
    int node = nb + nl;
    if(j < 8) asrc[node*8 + j] = s;
    else      adst[node*8 + (j-8)] = s;
}

// ---------------- agg1: per-head softmax-agg of RAW x; 4 nodes/block, 1 wave/node ----------------
__global__ __launch_bounds__(256) void agg1_kernel(const float* __restrict__ x,
                                                   const float* __restrict__ asrc,
                                                   const float* __restrict__ adst,
                                                   const int* __restrict__ rowp,
                                                   const int* __restrict__ colsrc,
                                                   short* __restrict__ oh, short* __restrict__ ol){
    const int w = threadIdx.x >> 6, l = threadIdx.x & 63;
    const int node = blockIdx.x*4 + w;
    __shared__ float sh_ee[4][64][8];
    int beg = rowp[node], end = rowp[node+1];
    float rd = adst[node*8 + (l & 7)];
    float acc0[8], acc1[8];
    #pragma unroll
    for(int h=0;h<8;h++){ acc0[h]=0.f; acc1[h]=0.f; }
    float dpart = 0.f;
    for(int base=beg; base<end; base+=64){
        int clen = min(64, end-base);
        WAVE_SYNC();                        // prior chunk's ee reads complete
        int sreg = (l < clen) ? colsrc[base + l] : 0;
        for(int it=l; it<clen*8; it+=64){
            int j = it >> 3;
            int s = colsrc[base + j];
            float e = asrc[s*8 + (l & 7)] + rd;
            e = (e > 0.f) ? e : 0.2f*e;
            float ee = expf(e);
            sh_ee[w][j][l & 7] = ee;
            dpart += ee;
        }
        WAVE_SYNC();                        // ee visible wave-wide
        #pragma unroll 2
        for(int j=0;j<clen;j++){
            int s = __shfl(sreg, j);
            float2 xv = ((const float2*)(x + (size_t)s*128))[l];
            #pragma unroll
            for(int h=0;h<8;h++){
                float wt = sh_ee[w][j][h];
                acc0[h] += wt * xv.x;
                acc1[h] += wt * xv.y;
            }
        }
    }
    dpart += __shfl_xor(dpart, 8);
    dpart += __shfl_xor(dpart, 16);
    dpart += __shfl_xor(dpart, 32);         // lane l holds denom for head l&7
    #pragma unroll
    for(int h=0;h<8;h++){
        float dn = __shfl(dpart, h) + 1e-16f;
        float v0 = acc0[h]/dn, v1 = acc1[h]/dn;
        short h0 = f2bf(v0), h1 = f2bf(v1);
        short2 hi = { h0, h1 };
        short2 lo = { f2bf(v0 - bf2f(h0)), f2bf(v1 - bf2f(h1)) };
        size_t off = (size_t)node*F1 + h*128 + 2*l;
        *(short2*)(oh + off) = hi;
        *(short2*)(ol + off) = lo;
    }
}

// ---------------- agg2: softmax-agg of h2 fp32 [1024]; 1 wave/node, pipelined 2-edge groups ----------------
__global__ __launch_bounds__(256) void agg2_kernel(const float* __restrict__ hbuf,
                                                   const float* __restrict__ asrc,
                                                   const float* __restrict__ adst,
                                                   const int* __restrict__ rowp,
                                                   const int* __restrict__ colsrc,
                                                   const float* __restrict__ bias,
                                                   short* __restrict__ oh, short* __restrict__ ol){
    const int w = threadIdx.x >> 6, l = threadIdx.x & 63;
    const int node = blockIdx.x*4 + w;
    __shared__ float sh_ee[4][64][8];
    int beg = rowp[node], end = rowp[node+1];
    float rd = adst[node*8 + (l & 7)];
    float acc[16];
    #pragma unroll
    for(int k=0;k<16;k++) acc[k]=0.f;
    float dpart = 0.f;
    for(int base=beg; base<end; base+=64){
        int clen = min(64, end-base);
        WAVE_SYNC();                        // prior chunk's ee reads complete
        int sreg = (l < clen) ? colsrc[base + l] : 0;
        // ee for all 64 slots (zero-padded beyond clen)
        #pragma unroll 1
        for(int it=l; it<512; it+=64){
            int j = it >> 3;
            float ee = 0.f;
            if(j < clen){
                int s = colsrc[base + j];
                float e = asrc[s*8 + (l & 7)] + rd;
                e = (e > 0.f) ? e : 0.2f*e;
                ee = expf(e);
                dpart += ee;
            }
            sh_ee[w][j][l & 7] = ee;
        }
        WAVE_SYNC();                        // ee visible wave-wide
        int cpad = (clen + 1) & ~1;
        // software-pipelined gather: pair (A,B) in flight while FMA-ing previous pair
        int sA = __shfl(sreg, 0), sB = __shfl(sreg, 1);
        const float4* pA = (const float4*)(hbuf + (size_t)sA*F1);
        const float4* pB = (const float4*)(hbuf + (size_t)sB*F1);
        float4 vA0=pA[l], vA1=pA[l+64], vA2=pA[l+128], vA3=pA[l+192];
        float4 vB0=pB[l], vB1=pB[l+64], vB2=pB[l+128], vB3=pB[l+192];
        #pragma unroll 1
        for(int j0=0; j0<cpad; j0+=2){
            float4 nA0,nA1,nA2,nA3,nB0,nB1,nB2,nB3;
            const bool more = (j0+2 < cpad);
            if(more){
                int s2 = __shfl(sreg, j0+2), s3 = __shfl(sreg, j0+3);
                const float4* p2 = (const float4*)(hbuf + (size_t)s2*F1);
                const float4* p3 = (const float4*)(hbuf + (size_t)s3*F1);
                nA0=p2[l]; nA1=p2[l+64]; nA2=p2[l+128]; nA3=p2[l+192];
                nB0=p3[l]; nB1=p3[l+64]; nB2=p3[l+128]; nB3=p3[l+192];
            }
            const int hh0 = (l>>5);
            float wA0 = sh_ee[w][j0][hh0],   wA1 = sh_ee[w][j0][2+hh0];
            float wA2 = sh_ee[w][j0][4+hh0], wA3 = sh_ee[w][j0][6+hh0];
            float wB0 = sh_ee[w][j0+1][hh0],   wB1 = sh_ee[w][j0+1][2+hh0];
            float wB2 = sh_ee[w][j0+1][4+hh0], wB3 = sh_ee[w][j0+1][6+hh0];
            acc[ 0]+=wA0*vA0.x; acc[ 1]+=wA0*vA0.y; acc[ 2]+=wA0*vA0.z; acc[ 3]+=wA0*vA0.w;
            acc[ 4]+=wA1*vA1.x; acc[ 5]+=wA1*vA1.y; acc[ 6]+=wA1*vA1.z; acc[ 7]+=wA1*vA1.w;
            acc[ 8]+=wA2*vA2.x; acc[ 9]+=wA2*vA2.y; acc[10]+=wA2*vA2.z; acc[11]+=wA2*vA2.w;
            acc[12]+=wA3*vA3.x; acc[13]+=wA3*vA3.y; acc[14]+=wA3*vA3.z; acc[15]+=wA3*vA3.w;
            acc[ 0]+=wB0*vB0.x; acc[ 1]+=wB0*vB0.y; acc[ 2]+=wB0*vB0.z; acc[ 3]+=wB0*vB0.w;
            acc[ 4]+=wB1*vB1.x; acc[ 5]+=wB1*vB1.y; acc[ 6]+=wB1*vB1.z; acc[ 7]+=wB1*vB1.w;
            acc[ 8]+=wB2*vB2.x; acc[ 9]+=wB2*vB2.y; acc[10]+=wB2*vB2.z; acc[11]+=wB2*vB2.w;
            acc[12]+=wB3*vB3.x; acc[13]+=wB3*vB3.y; acc[14]+=wB3*vB3.z; acc[15]+=wB3*vB3.w;
            if(more){
                vA0=nA0; vA1=nA1; vA2=nA2; vA3=nA3;
                vB0=nB0; vB1=nB1; vB2=nB2; vB3=nB3;
            }
        }
    }
    dpart += __shfl_xor(dpart, 8);
    dpart += __shfl_xor(dpart, 16);
    dpart += __shfl_xor(dpart, 32);
    #pragma unroll
    for(int k=0;k<4;k++){
        float dn = __shfl(dpart, 2*k + (l>>5)) + 1e-16f;
        int f = 4*(l + 64*k);
        float4 bb = *(const float4*)(bias + f);
        float v0 = fmaxf(acc[4*k+0]/dn + bb.x, 0.f);
        float v1 = fmaxf(acc[4*k+1]/dn + bb.y, 0.f);
        float v2 = fmaxf(acc[4*k+2]/dn + bb.z, 0.f);
        float v3 = fmaxf(acc[4*k+3]/dn + bb.w, 0.f);
        short h0=f2bf(v0), h1=f2bf(v1), h2=f2bf(v2), h3=f2bf(v3);
        short4 hi = { h0, h1, h2, h3 };
        short4 lo = { f2bf(v0-bf2f(h0)), f2bf(v1-bf2f(h1)), f2bf(v2-bf2f(h2)), f2bf(v3-bf2f(h3)) };
        size_t off = (size_t)node*F1 + f;
        *(short4*)(oh + off) = hi;
        *(short4*)(ol + off) = lo;
    }
}

// ---------------- agg3: softmax-agg of h3 fp32 [512] H=1; 1 wave/node, pipelined 4-edge groups ----------------
__global__ __launch_bounds__(256) void agg3_kernel(const float* __restrict__ hbuf,
                                                   const float* __restrict__ asrc,
                                                   const float* __restrict__ adst,
                                                   const int* __restrict__ rowp,
                                                   const int* __restrict__ colsrc,
                                                   const float* __restrict__ bias,
                                                   short* __restrict__ oh, short* __restrict__ ol){
    const int w = threadIdx.x >> 6, l = threadIdx.x & 63;
    const int node = blockIdx.x*4 + w;
    int beg = rowp[node], end = rowp[node+1];
    float rd = adst[node];
    float acc[8];
    #pragma unroll
    for(int k=0;k<8;k++) acc[k]=0.f;
    float dpart = 0.f;
    for(int base=beg; base<end; base+=64){
        int clen = min(64, end-base);
        int sreg = 0; float eereg = 0.f;
        if(l < clen){
            sreg = colsrc[base + l];
            float e = asrc[sreg] + rd;
            e = (e > 0.f) ? e : 0.2f*e;
            eereg = expf(e);
            dpart += eereg;
        }
        int cpad = (clen + 3) & ~3;
        int sa=__shfl(sreg,0), sb=__shfl(sreg,1), sc=__shfl(sreg,2), sd=__shfl(sreg,3);
        float wa=__shfl(eereg,0), wb=__shfl(eereg,1), wc=__shfl(eereg,2), wd=__shfl(eereg,3);
        const float4* qa = (const float4*)(hbuf + (size_t)sa*INT_DIM);
        const float4* qb = (const float4*)(hbuf + (size_t)sb*INT_DIM);
        const float4* qc = (const float4*)(hbuf + (size_t)sc*INT_DIM);
        const float4* qd = (const float4*)(hbuf + (size_t)sd*INT_DIM);
        float4 va0=qa[l], va1=qa[l+64];
        float4 vb0=qb[l], vb1=qb[l+64];
        float4 vc0=qc[l], vc1=qc[l+64];
        float4 vd0=qd[l], vd1=qd[l+64];
        #pragma unroll 1
        for(int j0=0; j0<cpad; j0+=4){
            float4 na0,na1,nb0,nb1,nc0,nc1,nd0,nd1;
            float xa=0.f,xb=0.f,xc=0.f,xd=0.f;
            const bool more = (j0+4 < cpad);
            if(more){
                int t0=__shfl(sreg,j0+4), t1=__shfl(sreg,j0+5), t2=__shfl(sreg,j0+6), t3=__shfl(sreg,j0+7);
                xa=__shfl(eereg,j0+4); xb=__shfl(eereg,j0+5); xc=__shfl(eereg,j0+6); xd=__shfl(eereg,j0+7);
                const float4* r0 = (const float4*)(hbuf + (size_t)t0*INT_DIM);
                const float4* r1 = (const float4*)(hbuf + (size_t)t1*INT_DIM);
                const float4* r2 = (const float4*)(hbuf + (size_t)t2*INT_DIM);
                const float4* r3 = (const float4*)(hbuf + (size_t)t3*INT_DIM);
                na0=r0[l]; na1=r0[l+64];
                nb0=r1[l]; nb1=r1[l+64];
                nc0=r2[l]; nc1=r2[l+64];
                nd0=r3[l]; nd1=r3[l+64];
            }
            acc[0]+=wa*va0.x; acc[1]+=wa*va0.y; acc[2]+=wa*va0.z; acc[3]+=wa*va0.w;
            acc[4]+=wa*va1.x; acc[5]+=wa*va1.y; acc[6]+=wa*va1.z; acc[7]+=wa*va1.w;
            acc[0]+=wb*vb0.x; acc[1]+=wb*vb0.y; acc[2]+=wb*vb0.z; acc[3]+=wb*vb0.w;
            acc[4]+=wb*vb1.x; acc[5]+=wb*vb1.y; acc[6]+=wb*vb1.z; acc[7]+=wb*vb1.w;
            acc[0]+=wc*vc0.x; acc[1]+=wc*vc0.y; acc[2]+=wc*vc0.z; acc[3]+=wc*vc0.w;
            acc[4]+=wc*vc1.x; acc[5]+=wc*vc1.y; acc[6]+=wc*vc1.z; acc[7]+=wc*vc1.w;
            acc[0]+=wd*vd0.x; acc[1]+=wd*vd0.y; acc[2]+=wd*vd0.z; acc[3]+=wd*vd0.w;
            acc[4]+=wd*vd1.x; acc[5]+=wd*vd1.y; acc[6]+=wd*vd1.z; acc[7]+=wd*vd1.w;
            if(more){
                va0=na0; va1=na1; vb0=nb0; vb1=nb1;
                vc0=nc0; vc1=nc1; vd0=nd0; vd1=nd1;
                wa=xa; wb=xb; wc=xc; wd=xd;
            }
        }
    }
    #pragma unroll
    for(int off=1; off<64; off<<=1) dpart += __shfl_xor(dpart, off);
    float dn = dpart + 1e-16f;
    #pragma unroll
    for(int k=0;k<2;k++){
        int f = 4*(l + 64*k);
        float4 bb = *(const float4*)(bias + f);
        float v0 = fmaxf(acc[4*k+0]/dn + bb.x, 0.f);
        float v1 = fmaxf(acc[4*k+1]/dn + bb.y, 0.f);
        float v2 = fmaxf(acc[4*k+2]/dn + bb.z, 0.f);
        float v3 = fmaxf(acc[4*k+3]/dn + bb.w, 0.f);
        short h0=f2bf(v0), h1=f2bf(v1), h2=f2bf(v2), h3=f2bf(v3);
        short4 hi = { h0, h1, h2, h3 };
        short4 lo = { f2bf(v0-bf2f(h0)), f2bf(v1-bf2f(h1)), f2bf(v2-bf2f(h2)), f2bf(v3-bf2f(h3)) };
        size_t off = (size_t)node*INT_DIM + f;
        *(short4*)(oh + off) = hi;
        *(short4*)(ol + off) = lo;
    }
}

// ---------------- fused split-bf16 MFMA GEMM (generalized: lda/ldb/ldc, blockIdx.z offsets) ----------------
template<int FUSE, int SPLIT>
__global__ __launch_bounds__(256) void mfma_gemm_kernel(
    const short* __restrict__ Ah, const short* __restrict__ Al, int lda, int za,
    const short* __restrict__ Bh, const short* __restrict__ Bl, int ldb, int zb,
    const float* __restrict__ bias, float* __restrict__ C,
    short* __restrict__ Gh, short* __restrict__ Gl, int ldc, int zc,
    int K, int gx)
{
    __shared__ short lAh[128*32];   // 8 KB each
    __shared__ short lAl[128*32];
    __shared__ short lBh[128*32];
    __shared__ short lBl[128*32];
    const int tid  = threadIdx.x;
    const int lane = tid & 63;
    const int w    = tid >> 6;
    const int wm   = w >> 1, wn = w & 1;
    const int z    = blockIdx.z;

    // XCD-bijective swizzle
    const int nwg = gridDim.x;
    const int q = nwg >> 3, r = nwg & 7;
    const int xcd = blockIdx.x & 7, idx = blockIdx.x >> 3;
    const int wgid = (xcd < r ? xcd*(q+1) : r*(q+1) + (xcd-r)*q) + idx;
    const int row0 = (wgid / gx) * 128, col0 = (wgid % gx) * 128;

    f32x4 acc[4][4];
    #pragma unroll
    for(int i=0;i<4;i++)
        #pragma unroll
        for(int j=0;j<4;j++) acc[i][j] = (f32x4){0.f,0.f,0.f,0.f};

    const int r1 = tid >> 2,  s1 = (tid & 3) ^ (r1 & 3);
    const int r2 = r1 + 64,   s2 = (tid & 3) ^ (r2 & 3);
    const size_t aoff1 = (size_t)(row0 + r1) * lda + (size_t)z*za + s1 * 8;
    const size_t aoff2 = (size_t)(row0 + r2) * lda + (size_t)z*za + s2 * 8;
    const size_t boff1 = (size_t)(col0 + r1) * ldb + (size_t)z*zb + s1 * 8;
    const size_t boff2 = (size_t)(col0 + r2) * ldb + (size_t)z*zb + s2 * 8;

    typedef __attribute__((address_space(3))) char lds_char;
    lds_char* dAh1 = (lds_char*)(&lAh[0]) + w*1024;  lds_char* dAh2 = dAh1 + 4096;
    lds_char* dAl1 = (lds_char*)(&lAl[0]) + w*1024;  lds_char* dAl2 = dAl1 + 4096;
    lds_char* dBh1 = (lds_char*)(&lBh[0]) + w*1024;  lds_char* dBh2 = dBh1 + 4096;
    lds_char* dBl1 = (lds_char*)(&lBl[0]) + w*1024;  lds_char* dBl2 = dBl1 + 4096;

    int arow[4], brow[4];
    const int slotx = ((lane >> 4) ^ (lane & 3)) << 4;
    #pragma unroll
    for(int i=0;i<4;i++){
        arow[i] = (wm*64 + i*16 + (lane & 15)) * 64 + slotx;
        brow[i] = (wn*64 + i*16 + (lane & 15)) * 64 + slotx;
    }

    #pragma unroll 1
    for(int k0 = 0; k0 < K; k0 += 32){
        __syncthreads();
        #define GLDS(src, dst) __builtin_amdgcn_global_load_lds( \
            (__attribute__((address_space(1))) void*)(src), \
            (__attribute__((address_space(3))) void*)(dst), 16, 0, 0)
        GLDS(Ah + aoff1 + k0, dAh1);  GLDS(Ah + aoff2 + k0, dAh2);
        GLDS(Al + aoff1 + k0, dAl1);  GLDS(Al + aoff2 + k0, dAl2);
        GLDS(Bh + boff1 + k0, dBh1);  GLDS(Bh + boff2 + k0, dBh2);
        GLDS(Bl + boff1 + k0, dBl1);  GLDS(Bl + boff2 + k0, dBl2);
        #undef GLDS
        __syncthreads();
        bf16x8 afh[4], afl[4];
        #pragma unroll
        for(int i=0;i<4;i++){
            afh[i] = *(const bf16x8*)((const char*)lAh + arow[i]);
            afl[i] = *(const bf16x8*)((const char*)lAl + arow[i]);
        }
        #pragma unroll
        for(int j=0;j<4;j++){
            bf16x8 bh = *(const bf16x8*)((const char*)lBh + brow[j]);
            bf16x8 bl = *(const bf16x8*)((const char*)lBl + brow[j]);
            #pragma unroll
            for(int i=0;i<4;i++){
                acc[i][j] = __builtin_amdgcn_mfma_f32_16x16x32_bf16(afh[i], bh, acc[i][j], 0, 0, 0);
                acc[i][j] = __builtin_amdgcn_mfma_f32_16x16x32_bf16(afh[i], bl, acc[i][j], 0, 0, 0);
                acc[i][j] = __builtin_amdgcn_mfma_f32_16x16x32_bf16(afl[i], bh, acc[i][j], 0, 0, 0);
            }
        }
    }

    // epilogue: C/D layout col=lane&15, row=(lane>>4)*4+reg
    #pragma unroll
    for(int i=0;i<4;i++){
        const int rr = row0 + wm*64 + i*16 + ((lane >> 4) << 2);
        #pragma unroll
        for(int j=0;j<4;j++){
            const int gc = z*zc + col0 + wn*64 + j*16 + (lane & 15);
            float b = FUSE ? bias[gc] : 0.f;
            #pragma unroll
            for(int rg=0;rg<4;rg++){
                float v = acc[i][j][rg];
                if(FUSE) v = fmaxf(v + b, 0.f);
                if(SPLIT){
                    short hv = f2bf(v);
                    Gh[(size_t)(rr + rg) * ldc + gc] = hv;
                    Gl[(size_t)(rr + rg) * ldc + gc] = f2bf(v - bf2f(hv));
                } else {
                    C[(size_t)(rr + rg) * ldc + gc] = v;
                }
            }
        }
    }
}

// ---------------- alpha: per-node per-head dot(h[n,h,:], a[h,:])  (project-first layers) ----------------
template<int H, int C>
__global__ __launch_bounds__(128) void alpha_kernel(const float* __restrict__ hbuf,
                                                    const float* __restrict__ a_src,
                                                    const float* __restrict__ a_dst,
                                                    float* __restrict__ asrc, float* __restrict__ adst, int n){
    constexpr int F = H*C;
    int node = blockIdx.x;
    int t = threadIdx.x;          // 128 threads
    float ps[H], pd[H];
    #pragma unroll
    for(int h=0;h<H;h++){ ps[h]=0.f; pd[h]=0.f; }
    #pragma unroll
    for(int k=0;k<F/128;k++){
        int idx = t + k*128;
        int h = (k*128)/C;
        float v = hbuf[(size_t)node*F + idx];
        ps[h] += v * a_src[idx];
        pd[h] += v * a_dst[idx];
    }
    int lane = t & 63, wv = t >> 6;
    __shared__ float shs[2][H], shd[2][H];
    #pragma unroll
    for(int h=0;h<H;h++){
        float v = ps[h], w2 = pd[h];
        #pragma unroll
        for(int off=32; off; off>>=1){ v += __shfl_down(v, off); w2 += __shfl_down(w2, off); }
        if(lane==0){ shs[wv][h]=v; shd[wv][h]=w2; }
    }
    __syncthreads();
    if(t < H){
        asrc[(size_t)node*H + t] = shs[0][t] + shs[1][t];
        adst[(size_t)node*H + t] = shd[0][t] + shd[1][t];
    }
}

// ---------------- classifier: out[n,3] = h[n,:512] @ Wc + bc ----------------
__global__ __launch_bounds__(256) void cls_kernel(const float* __restrict__ h, const float* __restrict__ Wc,
                                                  const float* __restrict__ bc, float* __restrict__ out, int n){
    int node = blockIdx.x*4 + (threadIdx.x >> 6);
    int lane = threadIdx.x & 63;
    if(node >= n) return;
    float s0=0.f, s1=0.f, s2=0.f;
    const float* hr = h + (size_t)node*INT_DIM;
    for(int k=lane; k<INT_DIM; k+=64){
        float v = hr[k];
        s0 += v * Wc[k*3+0];
        s1 += v * Wc[k*3+1];
        s2 += v * Wc[k*3+2];
    }
    #pragma unroll
    for(int off=32; off; off>>=1){
        s0 += __shfl_down(s0, off);
        s1 += __shfl_down(s1, off);
        s2 += __shfl_down(s2, off);
    }
    if(lane==0){
        out[(size_t)node*3+0] = s0 + bc[0];
        out[(size_t)node*3+1] = s1 + bc[1];
        out[(size_t)node*3+2] = s2 + bc[2];
    }
}

extern "C" void kernel_launch(void* const* d_in, const int* in_sizes, int n_in,
                              void* d_out, int out_size, void* d_ws, size_t ws_size,
                              hipStream_t stream){
    const float* x      = (const float*)d_in[0];
    const int*   ei     = (const int*)d_in[1];
    const float* W1     = (const float*)d_in[2];
    const float* a_src1 = (const float*)d_in[3];
    const float* a_dst1 = (const float*)d_in[4];
    const float* b1     = (const float*)d_in[5];
    const float* W2     = (const float*)d_in[6];
    const float* a_src2 = (const float*)d_in[7];
    const float* a_dst2 = (const float*)d_in[8];
    const float* b2     = (const float*)d_in[9];
    const float* W3     = (const float*)d_in[10];
    const float* a_src3 = (const float*)d_in[11];
    const float* a_dst3 = (const float*)d_in[12];
    const float* b3     = (const float*)d_in[13];
    const float* Wl     = (const float*)d_in[14];
    const float* bl     = (const float*)d_in[15];
    const float* Wc     = (const float*)d_in[16];
    const float* bc     = (const float*)d_in[17];
    float* out = (float*)d_out;

    const int* src = ei;
    const int* dst = ei + EE;

    // workspace carve: two big regions (41.4 MB each) + weights + small
    char* p = (char*)d_ws;
    char* regA = p;  p += (size_t)MPAD*F1*4;            // pair {ph,pl} OR fp32 buffer
    char* regB = p;  p += (size_t)MPAD*F1*4;            // pair {qh,ql}
    short* wt_h = (short*)p;  p += (size_t)F1*F1*2;     // 2.1 MB
    short* wt_l = (short*)p;  p += (size_t)F1*F1*2;     // 2.1 MB
    float* aw1  = (float*)p;  p += 16*IN_DIM*4;
    float* asrc = (float*)p;  p += (size_t)NN*HEADS*4;
    float* adst = (float*)p;  p += (size_t)NN*HEADS*4;
    int* cnt    = (int*)p;    p += NN*4;
    int* rowp   = (int*)p;    p += (NN+1)*4;
    int* cursor = (int*)p;    p += NN*4;
    int* colsrc = (int*)p;    p += EE*4;

    short* ph = (short*)regA;  short* pl = ph + (size_t)MPAD*F1;
    float* Af = (float*)regA;
    short* qh = (short*)regB;  short* ql = qh + (size_t)MPAD*F1;

    // ---- CSR build (by dst) ----
    hipMemsetAsync(cnt, 0, NN*sizeof(int), stream);
    count_kernel<<<(EE+255)/256, 256, 0, stream>>>(dst, EE, cnt);
    scan_kernel<<<1, 256, 0, stream>>>(cnt, rowp, cursor, NN);
    fill_kernel<<<(EE+255)/256, 256, 0, stream>>>(src, dst, EE, cursor, colsrc);

    // ---- Layer 1 (agg-first via linearity) ----
    splitT_kernel<<<dim3(F1/32, IN_DIM/32), 256, 0, stream>>>(W1, wt_h, wt_l, IN_DIM, F1);
    aw1_kernel<<<8, 256, 0, stream>>>(W1, a_src1, a_dst1, aw1);
    alpha1_kernel<<<NN/16, 256, 0, stream>>>(x, aw1, asrc, adst);
    agg1_kernel<<<NN/4, 256, 0, stream>>>(x, asrc, adst, rowp, colsrc, ph, pl);
    // out1 = relu(xa @ W1 + b1), block-diagonal per head, split output -> regB
    mfma_gemm_kernel<1,1><<<dim3(MPAD/128, 1, HEADS), 256, 0, stream>>>(
        ph, pl, F1, 128,  wt_h, wt_l, IN_DIM, 128*IN_DIM,
        b1, nullptr, qh, ql, F1, 128,  IN_DIM, 1);

    // ---- Layer 2 (project-first) ----
    splitT_kernel<<<dim3(F1/32, F1/32), 256, 0, stream>>>(W2, wt_h, wt_l, F1, F1);
    mfma_gemm_kernel<0,0><<<dim3((F1/128)*(MPAD/128), 1, 1), 256, 0, stream>>>(
        qh, ql, F1, 0,  wt_h, wt_l, F1, 0,
        nullptr, Af, nullptr, nullptr, F1, 0,  F1, F1/128);
    alpha_kernel<HEADS, HID><<<NN, 128, 0, stream>>>(Af, a_src2, a_dst2, asrc, adst, NN);
    agg2_kernel<<<NN/4, 256, 0, stream>>>(Af, asrc, adst, rowp, colsrc, b2, qh, ql);

    // ---- Layer 3 (project-first, H=1) ----
    splitT_kernel<<<dim3(INT_DIM/32, F1/32), 256, 0, stream>>>(W3, wt_h, wt_l, F1, INT_DIM);
    mfma_gemm_kernel<0,0><<<dim3((INT_DIM/128)*(MPAD/128), 1, 1), 256, 0, stream>>>(
        qh, ql, F1, 0,  wt_h, wt_l, F1, 0,
        nullptr, Af, nullptr, nullptr, INT_DIM, 0,  F1, INT_DIM/128);
    alpha_kernel<1, INT_DIM><<<NN, 128, 0, stream>>>(Af, a_src3, a_dst3, asrc, adst, NN);
    agg3_kernel<<<NN/4, 256, 0, stream>>>(Af, asrc, adst, rowp, colsrc, b3, qh, ql);

    // ---- Linear: relu(out3 @ Wl + bl) -> Af fp32 [NN,512] ----
    splitT_kernel<<<dim3(INT_DIM/32, INT_DIM/32), 256, 0, stream>>>(Wl, wt_h, wt_l, INT_DIM, INT_DIM);
    mfma_gemm_kernel<1,0><<<dim3((INT_DIM/128)*(MPAD/128), 1, 1), 256, 0, stream>>>(
        qh, ql, INT_DIM, 0,  wt_h, wt_l, INT_DIM, 0,
        bl, Af, nullptr, nullptr, INT_DIM, 0,  INT_DIM, INT_DIM/128);

    // ---- Classifier ----
    cls_kernel<<<(NN+3)/4, 256, 0, stream>>>(Af, Wc, bc, out, NN);
}

// Round 8
// 412.633 us; speedup vs baseline: 1.1634x; 1.1512x over previous
//
#include <hip/hip_runtime.h>
#include <hip/hip_bf16.h>

// Problem constants
#define NN 10000
#define EE 160000
#define IN_DIM 128
#define HID 128
#define HEADS 8
#define F1 (HEADS*HID)   // 1024
#define INT_DIM 512
#define OUT_DIM 3
#define MPAD 10112       // 79 * 128

typedef __attribute__((ext_vector_type(8))) short bf16x8;
typedef __attribute__((ext_vector_type(4))) float f32x4;
typedef __attribute__((ext_vector_type(8))) _Float16 half8;
typedef __attribute__((ext_vector_type(4))) _Float16 half4;

// wave-local LDS fence: wait all this wave's DS ops, and pin program order
#define WAVE_SYNC() do { asm volatile("s_waitcnt lgkmcnt(0)" ::: "memory"); \
                         __builtin_amdgcn_sched_barrier(0); } while(0)

__device__ inline short f2bf(float v){
    union { __hip_bfloat16 b; short s; } u;
    u.b = __float2bfloat16(v);
    return u.s;
}
__device__ inline float bf2f(short s){
    union { short s; __hip_bfloat16 b; } u;
    u.s = s;
    return __bfloat162float(u.b);
}

// ---------------- CSR build ----------------
__global__ __launch_bounds__(256) void count_kernel(const int* __restrict__ dst, int E, int* __restrict__ cnt){
    int e = blockIdx.x*256 + threadIdx.x;
    if(e < E) atomicAdd(&cnt[dst[e]], 1);
}

__global__ __launch_bounds__(256) void scan_kernel(const int* __restrict__ cnt, int* __restrict__ rowp,
                                                   int* __restrict__ cursor, int n){
    __shared__ int sh[256];
    __shared__ int stotal;
    int t = threadIdx.x;
    if(t==0) stotal = 0;
    __syncthreads();
    for(int base=0; base<n; base+=256){
        int i = base + t;
        int v = (i<n) ? cnt[i] : 0;
        sh[t] = v;
        __syncthreads();
        #pragma unroll
        for(int off=1; off<256; off<<=1){
            int add = (t>=off) ? sh[t-off] : 0;
            __syncthreads();
            sh[t] += add;
            __syncthreads();
        }
        int excl = sh[t] - v;
        if(i<n){ rowp[i] = stotal + excl; cursor[i] = stotal + excl; }
        int chunk_total = sh[255];
        __syncthreads();
        if(t==0) stotal += chunk_total;
        __syncthreads();
    }
    if(t==0) rowp[n] = stotal;
}

__global__ __launch_bounds__(256) void fill_kernel(const int* __restrict__ src, const int* __restrict__ dst,
                                                   int E, int* __restrict__ cursor, int* __restrict__ colsrc){
    int e = blockIdx.x*256 + threadIdx.x;
    if(e < E){
        int d = dst[e];
        int pos = atomicAdd(&cursor[d], 1);
        colsrc[pos] = src[e];
    }
}

// ---------------- split + transpose weights: B[K,N] fp32 -> T_hi/T_lo [N,K] bf16 ----------------
__global__ __launch_bounds__(256) void splitT_kernel(const float* __restrict__ B, short* __restrict__ Th,
                                                     short* __restrict__ Tl, int K, int N){
    __shared__ float tile[32][33];
    const int tx = threadIdx.x & 31, ty = threadIdx.x >> 5;   // 32 x 8
    const int n0 = blockIdx.x * 32, k0 = blockIdx.y * 32;
    #pragma unroll
    for(int i = 0; i < 32; i += 8)
        tile[ty + i][tx] = B[(size_t)(k0 + ty + i) * N + n0 + tx];
    __syncthreads();
    #pragma unroll
    for(int i = 0; i < 32; i += 8){
        int n = ty + i;
        float v = tile[tx][n];             // = B[k0+tx][n0+n]
        short hv = f2bf(v);
        Th[(size_t)(n0 + n) * K + k0 + tx] = hv;
        Tl[(size_t)(n0 + n) * K + k0 + tx] = f2bf(v - bf2f(hv));
    }
}

// ---------------- aw1[j][k] = sum_c a[j][c] * W1[k, hj*128+c]  (j<8: a_src, j>=8: a_dst) ----------------
__global__ __launch_bounds__(256) void aw1_kernel(const float* __restrict__ W1,
                                                  const float* __restrict__ a_src,
                                                  const float* __restrict__ a_dst,
                                                  float* __restrict__ aw){
    int idx = blockIdx.x*256 + threadIdx.x;
    if(idx >= 16*IN_DIM) return;
    int j = idx >> 7, k = idx & 127;
    int hj = j & 7;
    const float* av = (j < 8 ? a_src : a_dst) + hj*HID;
    const float* wr = W1 + (size_t)k*F1 + hj*HID;
    float s = 0.f;
    #pragma unroll 4
    for(int c = 0; c < HID; c++) s += av[c] * wr[c];
    aw[idx] = s;
}

// ---------------- alpha1[n, j] = x[n,:] @ aw[j,:]  -> asrc/adst [NN,8] ----------------
__global__ __launch_bounds__(256) void alpha1_kernel(const float* __restrict__ x,
                                                     const float* __restrict__ aw,
                                                     float* __restrict__ asrc, float* __restrict__ adst){
    __shared__ float xs[16][128];
    __shared__ float aws[16][128];
    int t = threadIdx.x;
    int nb = blockIdx.x * 16;
    for(int i = t; i < 16*128; i += 256){
        xs[i >> 7][i & 127] = x[(size_t)nb*128 + i];
        aws[i >> 7][i & 127] = aw[i];
    }
    __syncthreads();
    int nl = t >> 4, j = t & 15;
    float s = 0.f;
    #pragma unroll 4
    for(int c = 0; c < 128; c++) s += xs[nl][c] * aws[j][c];
    int node = nb + nl;
    if(j < 8) asrc[node*8 + j] = s;
    else      adst[node*8 + (j-8)] = s;
}

// ---------------- agg1: per-head softmax-agg of RAW x; 4 nodes/block, 1 wave/node ----------------
__global__ __launch_bounds__(256) void agg1_kernel(const float* __restrict__ x,
                                                   const float* __restrict__ asrc,
                                                   const float* __restrict__ adst,
                                                   const int* __restrict__ rowp,
                                                   const int* __restrict__ colsrc,
                                                   short* __restrict__ oh, short* __restrict__ ol){
    const int w = threadIdx.x >> 6, l = threadIdx.x & 63;
    const int node = blockIdx.x*4 + w;
    __shared__ float sh_ee[4][64][8];
    int beg = rowp[node], end = rowp[node+1];
    float rd = adst[node*8 + (l & 7)];
    float acc0[8], acc1[8];
    #pragma unroll
    for(int h=0;h<8;h++){ acc0[h]=0.f; acc1[h]=0.f; }
    float dpart = 0.f;
    for(int base=beg; base<end; base+=64){
        int clen = min(64, end-base);
        WAVE_SYNC();                        // prior chunk's ee reads complete
        int sreg = (l < clen) ? colsrc[base + l] : 0;
        for(int it=l; it<clen*8; it+=64){
            int j = it >> 3;
            int s = colsrc[base + j];
            float e = asrc[s*8 + (l & 7)] + rd;
            e = (e > 0.f) ? e : 0.2f*e;
            float ee = expf(e);
            sh_ee[w][j][l & 7] = ee;
            dpart += ee;
        }
        WAVE_SYNC();                        // ee visible wave-wide
        #pragma unroll 2
        for(int j=0;j<clen;j++){
            int s = __shfl(sreg, j);
            float2 xv = ((const float2*)(x + (size_t)s*128))[l];
            #pragma unroll
            for(int h=0;h<8;h++){
                float wt = sh_ee[w][j][h];
                acc0[h] += wt * xv.x;
                acc1[h] += wt * xv.y;
            }
        }
    }
    dpart += __shfl_xor(dpart, 8);
    dpart += __shfl_xor(dpart, 16);
    dpart += __shfl_xor(dpart, 32);         // lane l holds denom for head l&7
    #pragma unroll
    for(int h=0;h<8;h++){
        float dn = __shfl(dpart, h) + 1e-16f;
        float v0 = acc0[h]/dn, v1 = acc1[h]/dn;
        short h0 = f2bf(v0), h1 = f2bf(v1);
        short2 hi = { h0, h1 };
        short2 lo = { f2bf(v0 - bf2f(h0)), f2bf(v1 - bf2f(h1)) };
        size_t off = (size_t)node*F1 + h*128 + 2*l;
        *(short2*)(oh + off) = hi;
        *(short2*)(ol + off) = lo;
    }
}

__device__ inline void fma8x2(float* acc, half8 v0, half8 v1, float w0, float w1){
    #pragma unroll
    for(int k=0;k<8;k++){
        acc[k]   += w0 * (float)v0[k];
        acc[8+k] += w1 * (float)v1[k];
    }
}
__device__ inline void fma8(float* acc, half8 v, float w){
    #pragma unroll
    for(int k=0;k<8;k++) acc[k] += w * (float)v[k];
}

// ---------------- agg2: softmax-agg of h2 fp16 [1024]; 1 wave/node, 4-edge pipelined groups ----------------
__global__ __launch_bounds__(256) void agg2_kernel(const _Float16* __restrict__ hbuf,
                                                   const float* __restrict__ asrc,
                                                   const float* __restrict__ adst,
                                                   const int* __restrict__ rowp,
                                                   const int* __restrict__ colsrc,
                                                   const float* __restrict__ bias,
                                                   short* __restrict__ oh, short* __restrict__ ol){
    const int w = threadIdx.x >> 6, l = threadIdx.x & 63;
    const int node = blockIdx.x*4 + w;
    __shared__ float sh_ee[4][64][8];
    int beg = rowp[node], end = rowp[node+1];
    float rd = adst[node*8 + (l & 7)];
    float acc[16];
    #pragma unroll
    for(int k=0;k<16;k++) acc[k]=0.f;
    float dpart = 0.f;
    for(int base=beg; base<end; base+=64){
        int clen = min(64, end-base);
        WAVE_SYNC();                        // prior chunk's ee reads complete
        int sreg = (l < clen) ? colsrc[base + l] : 0;
        // ee for all 64 slots (zero-padded beyond clen)
        #pragma unroll 1
        for(int it=l; it<512; it+=64){
            int j = it >> 3;
            float ee = 0.f;
            if(j < clen){
                int s = colsrc[base + j];
                float e = asrc[s*8 + (l & 7)] + rd;
                e = (e > 0.f) ? e : 0.2f*e;
                ee = expf(e);
                dpart += ee;
            }
            sh_ee[w][j][l & 7] = ee;
        }
        WAVE_SYNC();                        // ee visible wave-wide
        int cpad = (clen + 3) & ~3;
        // 4 edges in flight; each edge: 2 half8 chunks (features 8l.., 512+8l..)
        int sA=__shfl(sreg,0), sB=__shfl(sreg,1), sC=__shfl(sreg,2), sD=__shfl(sreg,3);
        const half8* pA=(const half8*)(hbuf+(size_t)sA*F1);
        const half8* pB=(const half8*)(hbuf+(size_t)sB*F1);
        const half8* pC=(const half8*)(hbuf+(size_t)sC*F1);
        const half8* pD=(const half8*)(hbuf+(size_t)sD*F1);
        half8 vA0=pA[l], vA1=pA[l+64];
        half8 vB0=pB[l], vB1=pB[l+64];
        half8 vC0=pC[l], vC1=pC[l+64];
        half8 vD0=pD[l], vD1=pD[l+64];
        const int h0 = l>>4, h1 = 4 + (l>>4);
        #pragma unroll 1
        for(int j0=0; j0<cpad; j0+=4){
            half8 nA0,nA1,nB0,nB1,nC0,nC1,nD0,nD1;
            const bool more = (j0+4 < cpad);
            if(more){
                int t0=__shfl(sreg,j0+4), t1=__shfl(sreg,j0+5), t2=__shfl(sreg,j0+6), t3=__shfl(sreg,j0+7);
                const half8* q0=(const half8*)(hbuf+(size_t)t0*F1);
                const half8* q1=(const half8*)(hbuf+(size_t)t1*F1);
                const half8* q2=(const half8*)(hbuf+(size_t)t2*F1);
                const half8* q3=(const half8*)(hbuf+(size_t)t3*F1);
                nA0=q0[l]; nA1=q0[l+64];
                nB0=q1[l]; nB1=q1[l+64];
                nC0=q2[l]; nC1=q2[l+64];
                nD0=q3[l]; nD1=q3[l+64];
            }
            fma8x2(acc, vA0, vA1, sh_ee[w][j0  ][h0], sh_ee[w][j0  ][h1]);
            fma8x2(acc, vB0, vB1, sh_ee[w][j0+1][h0], sh_ee[w][j0+1][h1]);
            fma8x2(acc, vC0, vC1, sh_ee[w][j0+2][h0], sh_ee[w][j0+2][h1]);
            fma8x2(acc, vD0, vD1, sh_ee[w][j0+3][h0], sh_ee[w][j0+3][h1]);
            if(more){
                vA0=nA0; vA1=nA1; vB0=nB0; vB1=nB1;
                vC0=nC0; vC1=nC1; vD0=nD0; vD1=nD1;
            }
        }
    }
    dpart += __shfl_xor(dpart, 8);
    dpart += __shfl_xor(dpart, 16);
    dpart += __shfl_xor(dpart, 32);
    float dn0 = __shfl(dpart, l>>4) + 1e-16f;
    float dn1 = __shfl(dpart, 4 + (l>>4)) + 1e-16f;
    const float4* bp = (const float4*)bias;
    float4 ba0 = bp[2*l],       ba1 = bp[2*l+1];       // bias[8l .. 8l+7]
    float4 bc0 = bp[128 + 2*l], bc1 = bp[128 + 2*l+1]; // bias[512+8l ..]
    float bb0[8] = {ba0.x,ba0.y,ba0.z,ba0.w, ba1.x,ba1.y,ba1.z,ba1.w};
    float bb1[8] = {bc0.x,bc0.y,bc0.z,bc0.w, bc1.x,bc1.y,bc1.z,bc1.w};
    bf16x8 hi0, lo0, hi1, lo1;
    #pragma unroll
    for(int k=0;k<8;k++){
        float v0 = fmaxf(acc[k]/dn0 + bb0[k], 0.f);
        float v1 = fmaxf(acc[8+k]/dn1 + bb1[k], 0.f);
        short h0v = f2bf(v0); hi0[k]=h0v; lo0[k]=f2bf(v0 - bf2f(h0v));
        short h1v = f2bf(v1); hi1[k]=h1v; lo1[k]=f2bf(v1 - bf2f(h1v));
    }
    size_t o0 = (size_t)node*F1 + 8*l;
    size_t o1 = o0 + 512;
    *(bf16x8*)(oh + o0) = hi0;  *(bf16x8*)(ol + o0) = lo0;
    *(bf16x8*)(oh + o1) = hi1;  *(bf16x8*)(ol + o1) = lo1;
}

// ---------------- agg3: softmax-agg of h3 fp16 [512] H=1; 1 wave/node, 8-edge pipelined groups ----------------
__global__ __launch_bounds__(256) void agg3_kernel(const _Float16* __restrict__ hbuf,
                                                   const float* __restrict__ asrc,
                                                   const float* __restrict__ adst,
                                                   const int* __restrict__ rowp,
                                                   const int* __restrict__ colsrc,
                                                   const float* __restrict__ bias,
                                                   short* __restrict__ oh, short* __restrict__ ol){
    const int w = threadIdx.x >> 6, l = threadIdx.x & 63;
    const int node = blockIdx.x*4 + w;
    int beg = rowp[node], end = rowp[node+1];
    float rd = adst[node];
    float acc[8];
    #pragma unroll
    for(int k=0;k<8;k++) acc[k]=0.f;
    float dpart = 0.f;
    for(int base=beg; base<end; base+=64){
        int clen = min(64, end-base);
        int sreg = 0; float eereg = 0.f;
        if(l < clen){
            sreg = colsrc[base + l];
            float e = asrc[sreg] + rd;
            e = (e > 0.f) ? e : 0.2f*e;
            eereg = expf(e);
            dpart += eereg;
        }
        int cpad = (clen + 7) & ~7;
        half8 v[8];
        float wt[8];
        #pragma unroll
        for(int k=0;k<8;k++){
            int s = __shfl(sreg, k);
            wt[k] = __shfl(eereg, k);
            v[k] = ((const half8*)(hbuf + (size_t)s*INT_DIM))[l];
        }
        #pragma unroll 1
        for(int j0=0; j0<cpad; j0+=8){
            half8 nv[8]; float nw[8];
            const bool more = (j0+8 < cpad);
            if(more){
                #pragma unroll
                for(int k=0;k<8;k++){
                    int s = __shfl(sreg, j0+8+k);
                    nw[k] = __shfl(eereg, j0+8+k);
                    nv[k] = ((const half8*)(hbuf + (size_t)s*INT_DIM))[l];
                }
            }
            #pragma unroll
            for(int k=0;k<8;k++) fma8(acc, v[k], wt[k]);
            if(more){
                #pragma unroll
                for(int k=0;k<8;k++){ v[k]=nv[k]; wt[k]=nw[k]; }
            }
        }
    }
    #pragma unroll
    for(int off=1; off<64; off<<=1) dpart += __shfl_xor(dpart, off);
    float dn = dpart + 1e-16f;
    const float4* bp = (const float4*)bias;
    float4 ba0 = bp[2*l], ba1 = bp[2*l+1];    // bias[8l .. 8l+7]
    float bb[8] = {ba0.x,ba0.y,ba0.z,ba0.w, ba1.x,ba1.y,ba1.z,ba1.w};
    bf16x8 hi, lo;
    #pragma unroll
    for(int k=0;k<8;k++){
        float vv = fmaxf(acc[k]/dn + bb[k], 0.f);
        short hv = f2bf(vv); hi[k]=hv; lo[k]=f2bf(vv - bf2f(hv));
    }
    size_t o = (size_t)node*INT_DIM + 8*l;
    *(bf16x8*)(oh + o) = hi;
    *(bf16x8*)(ol + o) = lo;
}

// ---------------- fused split-bf16 MFMA GEMM; OUT: 0=fp32, 1=split bf16 pair, 2=fp16 ----------------
template<int FUSE, int OUT>
__global__ __launch_bounds__(256) void mfma_gemm_kernel(
    const short* __restrict__ Ah, const short* __restrict__ Al, int lda, int za,
    const short* __restrict__ Bh, const short* __restrict__ Bl, int ldb, int zb,
    const float* __restrict__ bias, float* __restrict__ C,
    short* __restrict__ Gh, short* __restrict__ Gl, _Float16* __restrict__ Hf,
    int ldc, int zc, int K, int gx)
{
    __shared__ short lAh[128*32];   // 8 KB each
    __shared__ short lAl[128*32];
    __shared__ short lBh[128*32];
    __shared__ short lBl[128*32];
    const int tid  = threadIdx.x;
    const int lane = tid & 63;
    const int w    = tid >> 6;
    const int wm   = w >> 1, wn = w & 1;
    const int z    = blockIdx.z;

    // XCD-bijective swizzle
    const int nwg = gridDim.x;
    const int q = nwg >> 3, r = nwg & 7;
    const int xcd = blockIdx.x & 7, idx = blockIdx.x >> 3;
    const int wgid = (xcd < r ? xcd*(q+1) : r*(q+1) + (xcd-r)*q) + idx;
    const int row0 = (wgid / gx) * 128, col0 = (wgid % gx) * 128;

    f32x4 acc[4][4];
    #pragma unroll
    for(int i=0;i<4;i++)
        #pragma unroll
        for(int j=0;j<4;j++) acc[i][j] = (f32x4){0.f,0.f,0.f,0.f};

    const int r1 = tid >> 2,  s1 = (tid & 3) ^ (r1 & 3);
    const int r2 = r1 + 64,   s2 = (tid & 3) ^ (r2 & 3);
    const size_t aoff1 = (size_t)(row0 + r1) * lda + (size_t)z*za + s1 * 8;
    const size_t aoff2 = (size_t)(row0 + r2) * lda + (size_t)z*za + s2 * 8;
    const size_t boff1 = (size_t)(col0 + r1) * ldb + (size_t)z*zb + s1 * 8;
    const size_t boff2 = (size_t)(col0 + r2) * ldb + (size_t)z*zb + s2 * 8;

    typedef __attribute__((address_space(3))) char lds_char;
    lds_char* dAh1 = (lds_char*)(&lAh[0]) + w*1024;  lds_char* dAh2 = dAh1 + 4096;
    lds_char* dAl1 = (lds_char*)(&lAl[0]) + w*1024;  lds_char* dAl2 = dAl1 + 4096;
    lds_char* dBh1 = (lds_char*)(&lBh[0]) + w*1024;  lds_char* dBh2 = dBh1 + 4096;
    lds_char* dBl1 = (lds_char*)(&lBl[0]) + w*1024;  lds_char* dBl2 = dBl1 + 4096;

    int arow[4], brow[4];
    const int slotx = ((lane >> 4) ^ (lane & 3)) << 4;
    #pragma unroll
    for(int i=0;i<4;i++){
        arow[i] = (wm*64 + i*16 + (lane & 15)) * 64 + slotx;
        brow[i] = (wn*64 + i*16 + (lane & 15)) * 64 + slotx;
    }

    #pragma unroll 1
    for(int k0 = 0; k0 < K; k0 += 32){
        __syncthreads();
        #define GLDS(src, dst) __builtin_amdgcn_global_load_lds( \
            (__attribute__((address_space(1))) void*)(src), \
            (__attribute__((address_space(3))) void*)(dst), 16, 0, 0)
        GLDS(Ah + aoff1 + k0, dAh1);  GLDS(Ah + aoff2 + k0, dAh2);
        GLDS(Al + aoff1 + k0, dAl1);  GLDS(Al + aoff2 + k0, dAl2);
        GLDS(Bh + boff1 + k0, dBh1);  GLDS(Bh + boff2 + k0, dBh2);
        GLDS(Bl + boff1 + k0, dBl1);  GLDS(Bl + boff2 + k0, dBl2);
        #undef GLDS
        __syncthreads();
        bf16x8 afh[4], afl[4];
        #pragma unroll
        for(int i=0;i<4;i++){
            afh[i] = *(const bf16x8*)((const char*)lAh + arow[i]);
            afl[i] = *(const bf16x8*)((const char*)lAl + arow[i]);
        }
        #pragma unroll
        for(int j=0;j<4;j++){
            bf16x8 bh = *(const bf16x8*)((const char*)lBh + brow[j]);
            bf16x8 bl = *(const bf16x8*)((const char*)lBl + brow[j]);
            #pragma unroll
            for(int i=0;i<4;i++){
                acc[i][j] = __builtin_amdgcn_mfma_f32_16x16x32_bf16(afh[i], bh, acc[i][j], 0, 0, 0);
                acc[i][j] = __builtin_amdgcn_mfma_f32_16x16x32_bf16(afh[i], bl, acc[i][j], 0, 0, 0);
                acc[i][j] = __builtin_amdgcn_mfma_f32_16x16x32_bf16(afl[i], bh, acc[i][j], 0, 0, 0);
            }
        }
    }

    // epilogue: C/D layout col=lane&15, row=(lane>>4)*4+reg
    #pragma unroll
    for(int i=0;i<4;i++){
        const int rr = row0 + wm*64 + i*16 + ((lane >> 4) << 2);
        #pragma unroll
        for(int j=0;j<4;j++){
            const int gc = z*zc + col0 + wn*64 + j*16 + (lane & 15);
            float b = FUSE ? bias[gc] : 0.f;
            #pragma unroll
            for(int rg=0;rg<4;rg++){
                float v = acc[i][j][rg];
                if(FUSE) v = fmaxf(v + b, 0.f);
                if(OUT == 1){
                    short hv = f2bf(v);
                    Gh[(size_t)(rr + rg) * ldc + gc] = hv;
                    Gl[(size_t)(rr + rg) * ldc + gc] = f2bf(v - bf2f(hv));
                } else if(OUT == 2){
                    Hf[(size_t)(rr + rg) * ldc + gc] = (_Float16)v;
                } else {
                    C[(size_t)(rr + rg) * ldc + gc] = v;
                }
            }
        }
    }
}

// ---------------- alpha from fp16 h: H=8, C=128 (thread t -> head t>>4, 8 features) ----------------
__global__ __launch_bounds__(128) void alpha16_h8_kernel(const _Float16* __restrict__ hbuf,
                                                         const float* __restrict__ a_src,
                                                         const float* __restrict__ a_dst,
                                                         float* __restrict__ asrc, float* __restrict__ adst){
    int node = blockIdx.x;
    int t = threadIdx.x;          // 128 threads; features 8t..8t+7, head t>>4
    half8 v = ((const half8*)(hbuf + (size_t)node*F1))[t];
    const float4* ap = (const float4*)(a_src + 8*t);
    const float4* dp = (const float4*)(a_dst + 8*t);
    float4 a0 = ap[0], a1 = ap[1];
    float4 d0 = dp[0], d1 = dp[1];
    float av[8] = {a0.x,a0.y,a0.z,a0.w, a1.x,a1.y,a1.z,a1.w};
    float dv[8] = {d0.x,d0.y,d0.z,d0.w, d1.x,d1.y,d1.z,d1.w};
    float ps = 0.f, pd = 0.f;
    #pragma unroll
    for(int k=0;k<8;k++){
        float f = (float)v[k];
        ps += f * av[k];
        pd += f * dv[k];
    }
    #pragma unroll
    for(int off=8; off; off>>=1){ ps += __shfl_down(ps, off); pd += __shfl_down(pd, off); }
    if((t & 15) == 0){
        asrc[(size_t)node*8 + (t>>4)] = ps;
        adst[(size_t)node*8 + (t>>4)] = pd;
    }
}

// ---------------- alpha from fp16 h: H=1, C=512 ----------------
__global__ __launch_bounds__(128) void alpha16_h1_kernel(const _Float16* __restrict__ hbuf,
                                                         const float* __restrict__ a_src,
                                                         const float* __restrict__ a_dst,
                                                         float* __restrict__ asrc, float* __restrict__ adst){
    int node = blockIdx.x;
    int t = threadIdx.x;          // 128 threads; features 4t..4t+3
    half4 v = ((const half4*)(hbuf + (size_t)node*INT_DIM))[t];
    float4 a = ((const float4*)a_src)[t];
    float4 d = ((const float4*)a_dst)[t];
    float ps = (float)v[0]*a.x + (float)v[1]*a.y + (float)v[2]*a.z + (float)v[3]*a.w;
    float pd = (float)v[0]*d.x + (float)v[1]*d.y + (float)v[2]*d.z + (float)v[3]*d.w;
    #pragma unroll
    for(int off=32; off; off>>=1){ ps += __shfl_down(ps, off); pd += __shfl_down(pd, off); }
    __shared__ float shs[2], shd[2];
    int wv = t >> 6;
    if((t & 63) == 0){ shs[wv] = ps; shd[wv] = pd; }
    __syncthreads();
    if(t == 0){
        asrc[node] = shs[0] + shs[1];
        adst[node] = shd[0] + shd[1];
    }
}

// ---------------- classifier: out[n,3] = h[n,:512] @ Wc + bc ----------------
__global__ __launch_bounds__(256) void cls_kernel(const float* __restrict__ h, const float* __restrict__ Wc,
                                                  const float* __restrict__ bc, float* __restrict__ out, int n){
    int node = blockIdx.x*4 + (threadIdx.x >> 6);
    int lane = threadIdx.x & 63;
    if(node >= n) return;
    float s0=0.f, s1=0.f, s2=0.f;
    const float* hr = h + (size_t)node*INT_DIM;
    for(int k=lane; k<INT_DIM; k+=64){
        float v = hr[k];
        s0 += v * Wc[k*3+0];
        s1 += v * Wc[k*3+1];
        s2 += v * Wc[k*3+2];
    }
    #pragma unroll
    for(int off=32; off; off>>=1){
        s0 += __shfl_down(s0, off);
        s1 += __shfl_down(s1, off);
        s2 += __shfl_down(s2, off);
    }
    if(lane==0){
        out[(size_t)node*3+0] = s0 + bc[0];
        out[(size_t)node*3+1] = s1 + bc[1];
        out[(size_t)node*3+2] = s2 + bc[2];
    }
}

extern "C" void kernel_launch(void* const* d_in, const int* in_sizes, int n_in,
                              void* d_out, int out_size, void* d_ws, size_t ws_size,
                              hipStream_t stream){
    const float* x      = (const float*)d_in[0];
    const int*   ei     = (const int*)d_in[1];
    const float* W1     = (const float*)d_in[2];
    const float* a_src1 = (const float*)d_in[3];
    const float* a_dst1 = (const float*)d_in[4];
    const float* b1     = (const float*)d_in[5];
    const float* W2     = (const float*)d_in[6];
    const float* a_src2 = (const float*)d_in[7];
    const float* a_dst2 = (const float*)d_in[8];
    const float* b2     = (const float*)d_in[9];
    const float* W3     = (const float*)d_in[10];
    const float* a_src3 = (const float*)d_in[11];
    const float* a_dst3 = (const float*)d_in[12];
    const float* b3     = (const float*)d_in[13];
    const float* Wl     = (const float*)d_in[14];
    const float* bl     = (const float*)d_in[15];
    const float* Wc     = (const float*)d_in[16];
    const float* bc     = (const float*)d_in[17];
    float* out = (float*)d_out;

    const int* src = ei;
    const int* dst = ei + EE;

    // workspace carve: two big regions (41.4 MB each) + weights + small
    char* p = (char*)d_ws;
    char* regA = p;  p += (size_t)MPAD*F1*4;            // {ph,pl} OR fp16 h OR fp32 Af
    char* regB = p;  p += (size_t)MPAD*F1*4;            // pair {qh,ql}
    short* wt_h = (short*)p;  p += (size_t)F1*F1*2;     // 2.1 MB
    short* wt_l = (short*)p;  p += (size_t)F1*F1*2;     // 2.1 MB
    float* aw1  = (float*)p;  p += 16*IN_DIM*4;
    float* asrc = (float*)p;  p += (size_t)NN*HEADS*4;
    float* adst = (float*)p;  p += (size_t)NN*HEADS*4;
    int* cnt    = (int*)p;    p += NN*4;
    int* rowp   = (int*)p;    p += (NN+1)*4;
    int* cursor = (int*)p;    p += NN*4;
    int* colsrc = (int*)p;    p += EE*4;

    short* ph = (short*)regA;  short* pl = ph + (size_t)MPAD*F1;
    float* Af = (float*)regA;
    _Float16* H16 = (_Float16*)regA;
    short* qh = (short*)regB;  short* ql = qh + (size_t)MPAD*F1;

    // ---- CSR build (by dst) ----
    hipMemsetAsync(cnt, 0, NN*sizeof(int), stream);
    count_kernel<<<(EE+255)/256, 256, 0, stream>>>(dst, EE, cnt);
    scan_kernel<<<1, 256, 0, stream>>>(cnt, rowp, cursor, NN);
    fill_kernel<<<(EE+255)/256, 256, 0, stream>>>(src, dst, EE, cursor, colsrc);

    // ---- Layer 1 (agg-first via linearity) ----
    splitT_kernel<<<dim3(F1/32, IN_DIM/32), 256, 0, stream>>>(W1, wt_h, wt_l, IN_DIM, F1);
    aw1_kernel<<<8, 256, 0, stream>>>(W1, a_src1, a_dst1, aw1);
    alpha1_kernel<<<NN/16, 256, 0, stream>>>(x, aw1, asrc, adst);
    agg1_kernel<<<NN/4, 256, 0, stream>>>(x, asrc, adst, rowp, colsrc, ph, pl);
    // out1 = relu(xa @ W1 + b1), block-diagonal per head, split output -> regB
    mfma_gemm_kernel<1,1><<<dim3(MPAD/128, 1, HEADS), 256, 0, stream>>>(
        ph, pl, F1, 128,  wt_h, wt_l, IN_DIM, 128*IN_DIM,
        b1, nullptr, qh, ql, nullptr, F1, 128,  IN_DIM, 1);

    // ---- Layer 2 (project-first, fp16 h2) ----
    splitT_kernel<<<dim3(F1/32, F1/32), 256, 0, stream>>>(W2, wt_h, wt_l, F1, F1);
    mfma_gemm_kernel<0,2><<<dim3((F1/128)*(MPAD/128), 1, 1), 256, 0, stream>>>(
        qh, ql, F1, 0,  wt_h, wt_l, F1, 0,
        nullptr, nullptr, nullptr, nullptr, H16, F1, 0,  F1, F1/128);
    alpha16_h8_kernel<<<NN, 128, 0, stream>>>(H16, a_src2, a_dst2, asrc, adst);
    agg2_kernel<<<NN/4, 256, 0, stream>>>(H16, asrc, adst, rowp, colsrc, b2, qh, ql);

    // ---- Layer 3 (project-first, H=1, fp16 h3) ----
    splitT_kernel<<<dim3(INT_DIM/32, F1/32), 256, 0, stream>>>(W3, wt_h, wt_l, F1, INT_DIM);
    mfma_gemm_kernel<0,2><<<dim3((INT_DIM/128)*(MPAD/128), 1, 1), 256, 0, stream>>>(
        qh, ql, F1, 0,  wt_h, wt_l, F1, 0,
        nullptr, nullptr, nullptr, nullptr, H16, INT_DIM, 0,  F1, INT_DIM/128);
    alpha16_h1_kernel<<<NN, 128, 0, stream>>>(H16, a_src3, a_dst3, asrc, adst);
    agg3_kernel<<<NN/4, 256, 0, stream>>>(H16, asrc, adst, rowp, colsrc, b3, qh, ql);

    // ---- Linear: relu(out3 @ Wl + bl) -> Af fp32 [NN,512] ----
    splitT_kernel<<<dim3(INT_DIM/32, INT_DIM/32), 256, 0, stream>>>(Wl, wt_h, wt_l, INT_DIM, INT_DIM);
    mfma_gemm_kernel<1,0><<<dim3((INT_DIM/128)*(MPAD/128), 1, 1), 256, 0, stream>>>(
        qh, ql, INT_DIM, 0,  wt_h, wt_l, INT_DIM, 0,
        bl, Af, nullptr, nullptr, nullptr, INT_DIM, 0,  INT_DIM, INT_DIM/128);

    // ---- Classifier ----
    cls_kernel<<<(NN+3)/4, 256, 0, stream>>>(Af, Wc, bc, out, NN);
}

// Round 9
// 404.419 us; speedup vs baseline: 1.1870x; 1.0203x over previous
//
#include <hip/hip_runtime.h>
#include <hip/hip_bf16.h>

// Problem constants
#define NN 10000
#define EE 160000
#define IN_DIM 128
#define HID 128
#define HEADS 8
#define F1 (HEADS*HID)   // 1024
#define INT_DIM 512
#define OUT_DIM 3
#define MPAD 10112       // 79 * 128

typedef __attribute__((ext_vector_type(8))) short bf16x8;
typedef __attribute__((ext_vector_type(4))) float f32x4;
typedef __attribute__((ext_vector_type(8))) _Float16 half8;
typedef __attribute__((ext_vector_type(4))) _Float16 half4;

// wave-local LDS fence: wait all this wave's DS ops, and pin program order
#define WAVE_SYNC() do { asm volatile("s_waitcnt lgkmcnt(0)" ::: "memory"); \
                         __builtin_amdgcn_sched_barrier(0); } while(0)

__device__ inline short f2bf(float v){
    union { __hip_bfloat16 b; short s; } u;
    u.b = __float2bfloat16(v);
    return u.s;
}
__device__ inline float bf2f(short s){
    union { short s; __hip_bfloat16 b; } u;
    u.s = s;
    return __bfloat162float(u.b);
}

// ---------------- CSR build ----------------
__global__ __launch_bounds__(256) void count_kernel(const int* __restrict__ dst, int E, int* __restrict__ cnt){
    int e = blockIdx.x*256 + threadIdx.x;
    if(e < E) atomicAdd(&cnt[dst[e]], 1);
}

__global__ __launch_bounds__(256) void scan_kernel(const int* __restrict__ cnt, int* __restrict__ rowp,
                                                   int* __restrict__ cursor, int n){
    __shared__ int sh[256];
    __shared__ int stotal;
    int t = threadIdx.x;
    if(t==0) stotal = 0;
    __syncthreads();
    for(int base=0; base<n; base+=256){
        int i = base + t;
        int v = (i<n) ? cnt[i] : 0;
        sh[t] = v;
        __syncthreads();
        #pragma unroll
        for(int off=1; off<256; off<<=1){
            int add = (t>=off) ? sh[t-off] : 0;
            __syncthreads();
            sh[t] += add;
            __syncthreads();
        }
        int excl = sh[t] - v;
        if(i<n){ rowp[i] = stotal + excl; cursor[i] = stotal + excl; }
        int chunk_total = sh[255];
        __syncthreads();
        if(t==0) stotal += chunk_total;
        __syncthreads();
    }
    if(t==0) rowp[n] = stotal;
}

__global__ __launch_bounds__(256) void fill_kernel(const int* __restrict__ src, const int* __restrict__ dst,
                                                   int E, int* __restrict__ cursor, int* __restrict__ colsrc){
    int e = blockIdx.x*256 + threadIdx.x;
    if(e < E){
        int d = dst[e];
        int pos = atomicAdd(&cursor[d], 1);
        colsrc[pos] = src[e];
    }
}

// ---------------- split + transpose weights: B[K,N] fp32 -> T_hi/T_lo [N,K] bf16 ----------------
__global__ __launch_bounds__(256) void splitT_kernel(const float* __restrict__ B, short* __restrict__ Th,
                                                     short* __restrict__ Tl, int K, int N){
    __shared__ float tile[32][33];
    const int tx = threadIdx.x & 31, ty = threadIdx.x >> 5;   // 32 x 8
    const int n0 = blockIdx.x * 32, k0 = blockIdx.y * 32;
    #pragma unroll
    for(int i = 0; i < 32; i += 8)
        tile[ty + i][tx] = B[(size_t)(k0 + ty + i) * N + n0 + tx];
    __syncthreads();
    #pragma unroll
    for(int i = 0; i < 32; i += 8){
        int n = ty + i;
        float v = tile[tx][n];             // = B[k0+tx][n0+n]
        short hv = f2bf(v);
        Th[(size_t)(n0 + n) * K + k0 + tx] = hv;
        Tl[(size_t)(n0 + n) * K + k0 + tx] = f2bf(v - bf2f(hv));
    }
}

// ---------------- aw1[j][k] = sum_c a[j][c] * W1[k, hj*128+c]  (j<8: a_src, j>=8: a_dst) ----------------
__global__ __launch_bounds__(256) void aw1_kernel(const float* __restrict__ W1,
                                                  const float* __restrict__ a_src,
                                                  const float* __restrict__ a_dst,
                                                  float* __restrict__ aw){
    int idx = blockIdx.x*256 + threadIdx.x;
    if(idx >= 16*IN_DIM) return;
    int j = idx >> 7, k = idx & 127;
    int hj = j & 7;
    const float* av = (j < 8 ? a_src : a_dst) + hj*HID;
    const float* wr = W1 + (size_t)k*F1 + hj*HID;
    float s = 0.f;
    #pragma unroll 4
    for(int c = 0; c < HID; c++) s += av[c] * wr[c];
    aw[idx] = s;
}

// ---------------- alpha1[n, j] = x[n,:] @ aw[j,:]  -> asrc/adst [NN,8] ----------------
__global__ __launch_bounds__(256) void alpha1_kernel(const float* __restrict__ x,
                                                     const float* __restrict__ aw,
                                                     float* __restrict__ asrc, float* __restrict__ adst){
    __shared__ float xs[16][128];
    __shared__ float aws[16][128];
    int t = threadIdx.x;
    int nb = blockIdx.x * 16;
    for(int i = t; i < 16*128; i += 256){
        xs[i >> 7][i & 127] = x[(size_t)nb*128 + i];
        aws[i >> 7][i & 127] = aw[i];
    }
    __syncthreads();
    int nl = t >> 4, j = t & 15;
    float s = 0.f;
    #pragma unroll 4
    for(int c = 0; c < 128; c++) s += xs[nl][c] * aws[j][c];
    int node = nb + nl;
    if(j < 8) asrc[node*8 + j] = s;
    else      adst[node*8 + (j-8)] = s;
}

// ---------------- agg1: per-head softmax-agg of RAW x; 4 nodes/block, 1 wave/node ----------------
__global__ __launch_bounds__(256) void agg1_kernel(const float* __restrict__ x,
                                                   const float* __restrict__ asrc,
                                                   const float* __restrict__ adst,
                                                   const int* __restrict__ rowp,
                                                   const int* __restrict__ colsrc,
                                                   short* __restrict__ oh, short* __restrict__ ol){
    const int w = threadIdx.x >> 6, l = threadIdx.x & 63;
    const int node = blockIdx.x*4 + w;
    __shared__ float sh_ee[4][64][8];
    int beg = rowp[node], end = rowp[node+1];
    float rd = adst[node*8 + (l & 7)];
    float acc0[8], acc1[8];
    #pragma unroll
    for(int h=0;h<8;h++){ acc0[h]=0.f; acc1[h]=0.f; }
    float dpart = 0.f;
    for(int base=beg; base<end; base+=64){
        int clen = min(64, end-base);
        WAVE_SYNC();                        // prior chunk's ee reads complete
        int sreg = (l < clen) ? colsrc[base + l] : 0;
        for(int it=l; it<clen*8; it+=64){
            int j = it >> 3;
            int s = colsrc[base + j];
            float e = asrc[s*8 + (l & 7)] + rd;
            e = (e > 0.f) ? e : 0.2f*e;
            float ee = expf(e);
            sh_ee[w][j][l & 7] = ee;
            dpart += ee;
        }
        WAVE_SYNC();                        // ee visible wave-wide
        #pragma unroll 2
        for(int j=0;j<clen;j++){
            int s = __shfl(sreg, j);
            float2 xv = ((const float2*)(x + (size_t)s*128))[l];
            #pragma unroll
            for(int h=0;h<8;h++){
                float wt = sh_ee[w][j][h];
                acc0[h] += wt * xv.x;
                acc1[h] += wt * xv.y;
            }
        }
    }
    dpart += __shfl_xor(dpart, 8);
    dpart += __shfl_xor(dpart, 16);
    dpart += __shfl_xor(dpart, 32);         // lane l holds denom for head l&7
    #pragma unroll
    for(int h=0;h<8;h++){
        float dn = __shfl(dpart, h) + 1e-16f;
        float v0 = acc0[h]/dn, v1 = acc1[h]/dn;
        short h0 = f2bf(v0), h1 = f2bf(v1);
        short2 hi = { h0, h1 };
        short2 lo = { f2bf(v0 - bf2f(h0)), f2bf(v1 - bf2f(h1)) };
        size_t off = (size_t)node*F1 + h*128 + 2*l;
        *(short2*)(oh + off) = hi;
        *(short2*)(ol + off) = lo;
    }
}

__device__ inline void fma8x2(float* acc, half8 v0, half8 v1, float w0, float w1){
    #pragma unroll
    for(int k=0;k<8;k++){
        acc[k]   += w0 * (float)v0[k];
        acc[8+k] += w1 * (float)v1[k];
    }
}
__device__ inline void fma8(float* acc, half8 v, float w){
    #pragma unroll
    for(int k=0;k<8;k++) acc[k] += w * (float)v[k];
}

// ---------------- agg2: softmax-agg of h2 fp16 [1024]; 1 wave/node, 4-edge pipelined groups ----------------
__global__ __launch_bounds__(256) void agg2_kernel(const _Float16* __restrict__ hbuf,
                                                   const float* __restrict__ asrc,
                                                   const float* __restrict__ adst,
                                                   const int* __restrict__ rowp,
                                                   const int* __restrict__ colsrc,
                                                   const float* __restrict__ bias,
                                                   short* __restrict__ oh, short* __restrict__ ol){
    const int w = threadIdx.x >> 6, l = threadIdx.x & 63;
    const int node = blockIdx.x*4 + w;
    __shared__ float sh_ee[4][64][8];
    int beg = rowp[node], end = rowp[node+1];
    float rd = adst[node*8 + (l & 7)];
    float acc[16];
    #pragma unroll
    for(int k=0;k<16;k++) acc[k]=0.f;
    float dpart = 0.f;
    for(int base=beg; base<end; base+=64){
        int clen = min(64, end-base);
        WAVE_SYNC();                        // prior chunk's ee reads complete
        int sreg = (l < clen) ? colsrc[base + l] : 0;
        // ee for all 64 slots (zero-padded beyond clen)
        #pragma unroll 1
        for(int it=l; it<512; it+=64){
            int j = it >> 3;
            float ee = 0.f;
            if(j < clen){
                int s = colsrc[base + j];
                float e = asrc[s*8 + (l & 7)] + rd;
                e = (e > 0.f) ? e : 0.2f*e;
                ee = expf(e);
                dpart += ee;
            }
            sh_ee[w][j][l & 7] = ee;
        }
        WAVE_SYNC();                        // ee visible wave-wide
        int cpad = (clen + 3) & ~3;
        // 4 edges in flight; each edge: 2 half8 chunks (features 8l.., 512+8l..)
        int sA=__shfl(sreg,0), sB=__shfl(sreg,1), sC=__shfl(sreg,2), sD=__shfl(sreg,3);
        const half8* pA=(const half8*)(hbuf+(size_t)sA*F1);
        const half8* pB=(const half8*)(hbuf+(size_t)sB*F1);
        const half8* pC=(const half8*)(hbuf+(size_t)sC*F1);
        const half8* pD=(const half8*)(hbuf+(size_t)sD*F1);
        half8 vA0=pA[l], vA1=pA[l+64];
        half8 vB0=pB[l], vB1=pB[l+64];
        half8 vC0=pC[l], vC1=pC[l+64];
        half8 vD0=pD[l], vD1=pD[l+64];
        const int h0 = l>>4, h1 = 4 + (l>>4);
        #pragma unroll 1
        for(int j0=0; j0<cpad; j0+=4){
            half8 nA0,nA1,nB0,nB1,nC0,nC1,nD0,nD1;
            const bool more = (j0+4 < cpad);
            if(more){
                int t0=__shfl(sreg,j0+4), t1=__shfl(sreg,j0+5), t2=__shfl(sreg,j0+6), t3=__shfl(sreg,j0+7);
                const half8* q0=(const half8*)(hbuf+(size_t)t0*F1);
                const half8* q1=(const half8*)(hbuf+(size_t)t1*F1);
                const half8* q2=(const half8*)(hbuf+(size_t)t2*F1);
                const half8* q3=(const half8*)(hbuf+(size_t)t3*F1);
                nA0=q0[l]; nA1=q0[l+64];
                nB0=q1[l]; nB1=q1[l+64];
                nC0=q2[l]; nC1=q2[l+64];
                nD0=q3[l]; nD1=q3[l+64];
            }
            fma8x2(acc, vA0, vA1, sh_ee[w][j0  ][h0], sh_ee[w][j0  ][h1]);
            fma8x2(acc, vB0, vB1, sh_ee[w][j0+1][h0], sh_ee[w][j0+1][h1]);
            fma8x2(acc, vC0, vC1, sh_ee[w][j0+2][h0], sh_ee[w][j0+2][h1]);
            fma8x2(acc, vD0, vD1, sh_ee[w][j0+3][h0], sh_ee[w][j0+3][h1]);
            if(more){
                vA0=nA0; vA1=nA1; vB0=nB0; vB1=nB1;
                vC0=nC0; vC1=nC1; vD0=nD0; vD1=nD1;
            }
        }
    }
    dpart += __shfl_xor(dpart, 8);
    dpart += __shfl_xor(dpart, 16);
    dpart += __shfl_xor(dpart, 32);
    float dn0 = __shfl(dpart, l>>4) + 1e-16f;
    float dn1 = __shfl(dpart, 4 + (l>>4)) + 1e-16f;
    const float4* bp = (const float4*)bias;
    float4 ba0 = bp[2*l],       ba1 = bp[2*l+1];       // bias[8l .. 8l+7]
    float4 bc0 = bp[128 + 2*l], bc1 = bp[128 + 2*l+1]; // bias[512+8l ..]
    float bb0[8] = {ba0.x,ba0.y,ba0.z,ba0.w, ba1.x,ba1.y,ba1.z,ba1.w};
    float bb1[8] = {bc0.x,bc0.y,bc0.z,bc0.w, bc1.x,bc1.y,bc1.z,bc1.w};
    bf16x8 hi0, lo0, hi1, lo1;
    #pragma unroll
    for(int k=0;k<8;k++){
        float v0 = fmaxf(acc[k]/dn0 + bb0[k], 0.f);
        float v1 = fmaxf(acc[8+k]/dn1 + bb1[k], 0.f);
        short h0v = f2bf(v0); hi0[k]=h0v; lo0[k]=f2bf(v0 - bf2f(h0v));
        short h1v = f2bf(v1); hi1[k]=h1v; lo1[k]=f2bf(v1 - bf2f(h1v));
    }
    size_t o0 = (size_t)node*F1 + 8*l;
    size_t o1 = o0 + 512;
    *(bf16x8*)(oh + o0) = hi0;  *(bf16x8*)(ol + o0) = lo0;
    *(bf16x8*)(oh + o1) = hi1;  *(bf16x8*)(ol + o1) = lo1;
}

// ---------------- agg3: softmax-agg of h3 fp16 [512] H=1; 1 wave/node, 8-edge pipelined groups ----------------
__global__ __launch_bounds__(256) void agg3_kernel(const _Float16* __restrict__ hbuf,
                                                   const float* __restrict__ asrc,
                                                   const float* __restrict__ adst,
                                                   const int* __restrict__ rowp,
                                                   const int* __restrict__ colsrc,
                                                   const float* __restrict__ bias,
                                                   short* __restrict__ oh, short* __restrict__ ol){
    const int w = threadIdx.x >> 6, l = threadIdx.x & 63;
    const int node = blockIdx.x*4 + w;
    int beg = rowp[node], end = rowp[node+1];
    float rd = adst[node];
    float acc[8];
    #pragma unroll
    for(int k=0;k<8;k++) acc[k]=0.f;
    float dpart = 0.f;
    for(int base=beg; base<end; base+=64){
        int clen = min(64, end-base);
        int sreg = 0; float eereg = 0.f;
        if(l < clen){
            sreg = colsrc[base + l];
            float e = asrc[sreg] + rd;
            e = (e > 0.f) ? e : 0.2f*e;
            eereg = expf(e);
            dpart += eereg;
        }
        int cpad = (clen + 7) & ~7;
        half8 v[8];
        float wt[8];
        #pragma unroll
        for(int k=0;k<8;k++){
            int s = __shfl(sreg, k);
            wt[k] = __shfl(eereg, k);
            v[k] = ((const half8*)(hbuf + (size_t)s*INT_DIM))[l];
        }
        #pragma unroll 1
        for(int j0=0; j0<cpad; j0+=8){
            half8 nv[8]; float nw[8];
            const bool more = (j0+8 < cpad);
            if(more){
                #pragma unroll
                for(int k=0;k<8;k++){
                    int s = __shfl(sreg, j0+8+k);
                    nw[k] = __shfl(eereg, j0+8+k);
                    nv[k] = ((const half8*)(hbuf + (size_t)s*INT_DIM))[l];
                }
            }
            #pragma unroll
            for(int k=0;k<8;k++) fma8(acc, v[k], wt[k]);
            if(more){
                #pragma unroll
                for(int k=0;k<8;k++){ v[k]=nv[k]; wt[k]=nw[k]; }
            }
        }
    }
    #pragma unroll
    for(int off=1; off<64; off<<=1) dpart += __shfl_xor(dpart, off);
    float dn = dpart + 1e-16f;
    const float4* bp = (const float4*)bias;
    float4 ba0 = bp[2*l], ba1 = bp[2*l+1];    // bias[8l .. 8l+7]
    float bb[8] = {ba0.x,ba0.y,ba0.z,ba0.w, ba1.x,ba1.y,ba1.z,ba1.w};
    bf16x8 hi, lo;
    #pragma unroll
    for(int k=0;k<8;k++){
        float vv = fmaxf(acc[k]/dn + bb[k], 0.f);
        short hv = f2bf(vv); hi[k]=hv; lo[k]=f2bf(vv - bf2f(hv));
    }
    size_t o = (size_t)node*INT_DIM + 8*l;
    *(bf16x8*)(oh + o) = hi;
    *(bf16x8*)(ol + o) = lo;
}

// ---------------- fused split-bf16 MFMA GEMM, 8 waves (2x4), 128x128 tile ----------------
// OUT: 0=fp32, 1=split bf16 pair, 2=fp16
template<int FUSE, int OUT>
__global__ __launch_bounds__(512, 4) void mfma_gemm_kernel(
    const short* __restrict__ Ah, const short* __restrict__ Al, int lda, int za,
    const short* __restrict__ Bh, const short* __restrict__ Bl, int ldb, int zb,
    const float* __restrict__ bias, float* __restrict__ C,
    short* __restrict__ Gh, short* __restrict__ Gl, _Float16* __restrict__ Hf,
    int ldc, int zc, int K, int gx)
{
    __shared__ short lAh[128*32];   // 8 KB each
    __shared__ short lAl[128*32];
    __shared__ short lBh[128*32];
    __shared__ short lBl[128*32];
    const int tid  = threadIdx.x;
    const int lane = tid & 63;
    const int w    = tid >> 6;      // 0..7
    const int wm   = w >> 2;        // 0..1 (row half)
    const int wn   = w & 3;         // 0..3 (col quarter)
    const int z    = blockIdx.z;

    // XCD-bijective swizzle
    const int nwg = gridDim.x;
    const int q = nwg >> 3, r = nwg & 7;
    const int xcd = blockIdx.x & 7, idx = blockIdx.x >> 3;
    const int wgid = (xcd < r ? xcd*(q+1) : r*(q+1) + (xcd-r)*q) + idx;
    const int row0 = (wgid / gx) * 128, col0 = (wgid % gx) * 128;

    f32x4 acc[4][2];
    #pragma unroll
    for(int i=0;i<4;i++)
        #pragma unroll
        for(int j=0;j<2;j++) acc[i][j] = (f32x4){0.f,0.f,0.f,0.f};

    // single staging chunk: 512 lanes cover 128 rows x 4 slots of 16B
    const int rr1 = tid >> 2;                 // 0..127
    const int ss1 = (tid & 3) ^ (rr1 & 3);    // XOR-swizzled source slot
    const size_t aoff = (size_t)(row0 + rr1) * lda + (size_t)z*za + ss1 * 8;
    const size_t boff = (size_t)(col0 + rr1) * ldb + (size_t)z*zb + ss1 * 8;

    typedef __attribute__((address_space(3))) char lds_char;
    lds_char* dAh = (lds_char*)(&lAh[0]) + w*1024;
    lds_char* dAl = (lds_char*)(&lAl[0]) + w*1024;
    lds_char* dBh = (lds_char*)(&lBh[0]) + w*1024;
    lds_char* dBl = (lds_char*)(&lBl[0]) + w*1024;

    int arow[4], brow[2];
    const int slotx = ((lane >> 4) ^ (lane & 3)) << 4;
    #pragma unroll
    for(int i=0;i<4;i++)
        arow[i] = (wm*64 + i*16 + (lane & 15)) * 64 + slotx;
    #pragma unroll
    for(int j=0;j<2;j++)
        brow[j] = (wn*32 + j*16 + (lane & 15)) * 64 + slotx;

    #pragma unroll 1
    for(int k0 = 0; k0 < K; k0 += 32){
        __syncthreads();
        #define GLDS(src, dst) __builtin_amdgcn_global_load_lds( \
            (__attribute__((address_space(1))) void*)(src), \
            (__attribute__((address_space(3))) void*)(dst), 16, 0, 0)
        GLDS(Ah + aoff + k0, dAh);
        GLDS(Al + aoff + k0, dAl);
        GLDS(Bh + boff + k0, dBh);
        GLDS(Bl + boff + k0, dBl);
        #undef GLDS
        __syncthreads();
        bf16x8 afh[4], afl[4];
        #pragma unroll
        for(int i=0;i<4;i++){
            afh[i] = *(const bf16x8*)((const char*)lAh + arow[i]);
            afl[i] = *(const bf16x8*)((const char*)lAl + arow[i]);
        }
        #pragma unroll
        for(int j=0;j<2;j++){
            bf16x8 bh = *(const bf16x8*)((const char*)lBh + brow[j]);
            bf16x8 bl = *(const bf16x8*)((const char*)lBl + brow[j]);
            #pragma unroll
            for(int i=0;i<4;i++){
                acc[i][j] = __builtin_amdgcn_mfma_f32_16x16x32_bf16(afh[i], bh, acc[i][j], 0, 0, 0);
                acc[i][j] = __builtin_amdgcn_mfma_f32_16x16x32_bf16(afh[i], bl, acc[i][j], 0, 0, 0);
                acc[i][j] = __builtin_amdgcn_mfma_f32_16x16x32_bf16(afl[i], bh, acc[i][j], 0, 0, 0);
            }
        }
    }

    // epilogue: C/D layout col=lane&15, row=(lane>>4)*4+reg
    #pragma unroll
    for(int i=0;i<4;i++){
        const int rr = row0 + wm*64 + i*16 + ((lane >> 4) << 2);
        #pragma unroll
        for(int j=0;j<2;j++){
            const int gc = z*zc + col0 + wn*32 + j*16 + (lane & 15);
            float b = FUSE ? bias[gc] : 0.f;
            #pragma unroll
            for(int rg=0;rg<4;rg++){
                float v = acc[i][j][rg];
                if(FUSE) v = fmaxf(v + b, 0.f);
                if(OUT == 1){
                    short hv = f2bf(v);
                    Gh[(size_t)(rr + rg) * ldc + gc] = hv;
                    Gl[(size_t)(rr + rg) * ldc + gc] = f2bf(v - bf2f(hv));
                } else if(OUT == 2){
                    Hf[(size_t)(rr + rg) * ldc + gc] = (_Float16)v;
                } else {
                    C[(size_t)(rr + rg) * ldc + gc] = v;
                }
            }
        }
    }
}

// ---------------- alpha from fp16 h: H=8, C=128 (thread t -> head t>>4, 8 features) ----------------
__global__ __launch_bounds__(128) void alpha16_h8_kernel(const _Float16* __restrict__ hbuf,
                                                         const float* __restrict__ a_src,
                                                         const float* __restrict__ a_dst,
                                                         float* __restrict__ asrc, float* __restrict__ adst){
    int node = blockIdx.x;
    int t = threadIdx.x;          // 128 threads; features 8t..8t+7, head t>>4
    half8 v = ((const half8*)(hbuf + (size_t)node*F1))[t];
    const float4* ap = (const float4*)(a_src + 8*t);
    const float4* dp = (const float4*)(a_dst + 8*t);
    float4 a0 = ap[0], a1 = ap[1];
    float4 d0 = dp[0], d1 = dp[1];
    float av[8] = {a0.x,a0.y,a0.z,a0.w, a1.x,a1.y,a1.z,a1.w};
    float dv[8] = {d0.x,d0.y,d0.z,d0.w, d1.x,d1.y,d1.z,d1.w};
    float ps = 0.f, pd = 0.f;
    #pragma unroll
    for(int k=0;k<8;k++){
        float f = (float)v[k];
        ps += f * av[k];
        pd += f * dv[k];
    }
    #pragma unroll
    for(int off=8; off; off>>=1){ ps += __shfl_down(ps, off); pd += __shfl_down(pd, off); }
    if((t & 15) == 0){
        asrc[(size_t)node*8 + (t>>4)] = ps;
        adst[(size_t)node*8 + (t>>4)] = pd;
    }
}

// ---------------- alpha from fp16 h: H=1, C=512 ----------------
__global__ __launch_bounds__(128) void alpha16_h1_kernel(const _Float16* __restrict__ hbuf,
                                                         const float* __restrict__ a_src,
                                                         const float* __restrict__ a_dst,
                                                         float* __restrict__ asrc, float* __restrict__ adst){
    int node = blockIdx.x;
    int t = threadIdx.x;          // 128 threads; features 4t..4t+3
    half4 v = ((const half4*)(hbuf + (size_t)node*INT_DIM))[t];
    float4 a = ((const float4*)a_src)[t];
    float4 d = ((const float4*)a_dst)[t];
    float ps = (float)v[0]*a.x + (float)v[1]*a.y + (float)v[2]*a.z + (float)v[3]*a.w;
    float pd = (float)v[0]*d.x + (float)v[1]*d.y + (float)v[2]*d.z + (float)v[3]*d.w;
    #pragma unroll
    for(int off=32; off; off>>=1){ ps += __shfl_down(ps, off); pd += __shfl_down(pd, off); }
    __shared__ float shs[2], shd[2];
    int wv = t >> 6;
    if((t & 63) == 0){ shs[wv] = ps; shd[wv] = pd; }
    __syncthreads();
    if(t == 0){
        asrc[node] = shs[0] + shs[1];
        adst[node] = shd[0] + shd[1];
    }
}

// ---------------- classifier: out[n,3] = h[n,:512] @ Wc + bc ----------------
__global__ __launch_bounds__(256) void cls_kernel(const float* __restrict__ h, const float* __restrict__ Wc,
                                                  const float* __restrict__ bc, float* __restrict__ out, int n){
    int node = blockIdx.x*4 + (threadIdx.x >> 6);
    int lane = threadIdx.x & 63;
    if(node >= n) return;
    float s0=0.f, s1=0.f, s2=0.f;
    const float* hr = h + (size_t)node*INT_DIM;
    for(int k=lane; k<INT_DIM; k+=64){
        float v = hr[k];
        s0 += v * Wc[k*3+0];
        s1 += v * Wc[k*3+1];
        s2 += v * Wc[k*3+2];
    }
    #pragma unroll
    for(int off=32; off; off>>=1){
        s0 += __shfl_down(s0, off);
        s1 += __shfl_down(s1, off);
        s2 += __shfl_down(s2, off);
    }
    if(lane==0){
        out[(size_t)node*3+0] = s0 + bc[0];
        out[(size_t)node*3+1] = s1 + bc[1];
        out[(size_t)node*3+2] = s2 + bc[2];
    }
}

extern "C" void kernel_launch(void* const* d_in, const int* in_sizes, int n_in,
                              void* d_out, int out_size, void* d_ws, size_t ws_size,
                              hipStream_t stream){
    const float* x      = (const float*)d_in[0];
    const int*   ei     = (const int*)d_in[1];
    const float* W1     = (const float*)d_in[2];
    const float* a_src1 = (const float*)d_in[3];
    const float* a_dst1 = (const float*)d_in[4];
    const float* b1     = (const float*)d_in[5];
    const float* W2     = (const float*)d_in[6];
    const float* a_src2 = (const float*)d_in[7];
    const float* a_dst2 = (const float*)d_in[8];
    const float* b2     = (const float*)d_in[9];
    const float* W3     = (const float*)d_in[10];
    const float* a_src3 = (const float*)d_in[11];
    const float* a_dst3 = (const float*)d_in[12];
    const float* b3     = (const float*)d_in[13];
    const float* Wl     = (const float*)d_in[14];
    const float* bl     = (const float*)d_in[15];
    const float* Wc     = (const float*)d_in[16];
    const float* bc     = (const float*)d_in[17];
    float* out = (float*)d_out;

    const int* src = ei;
    const int* dst = ei + EE;

    // workspace carve: two big regions (41.4 MB each) + weights + small
    char* p = (char*)d_ws;
    char* regA = p;  p += (size_t)MPAD*F1*4;            // {ph,pl} OR fp16 h OR fp32 Af
    char* regB = p;  p += (size_t)MPAD*F1*4;            // pair {qh,ql}
    short* wt_h = (short*)p;  p += (size_t)F1*F1*2;     // 2.1 MB
    short* wt_l = (short*)p;  p += (size_t)F1*F1*2;     // 2.1 MB
    float* aw1  = (float*)p;  p += 16*IN_DIM*4;
    float* asrc = (float*)p;  p += (size_t)NN*HEADS*4;
    float* adst = (float*)p;  p += (size_t)NN*HEADS*4;
    int* cnt    = (int*)p;    p += NN*4;
    int* rowp   = (int*)p;    p += (NN+1)*4;
    int* cursor = (int*)p;    p += NN*4;
    int* colsrc = (int*)p;    p += EE*4;

    short* ph = (short*)regA;  short* pl = ph + (size_t)MPAD*F1;
    float* Af = (float*)regA;
    _Float16* H16 = (_Float16*)regA;
    short* qh = (short*)regB;  short* ql = qh + (size_t)MPAD*F1;

    // ---- CSR build (by dst) ----
    hipMemsetAsync(cnt, 0, NN*sizeof(int), stream);
    count_kernel<<<(EE+255)/256, 256, 0, stream>>>(dst, EE, cnt);
    scan_kernel<<<1, 256, 0, stream>>>(cnt, rowp, cursor, NN);
    fill_kernel<<<(EE+255)/256, 256, 0, stream>>>(src, dst, EE, cursor, colsrc);

    // ---- Layer 1 (agg-first via linearity) ----
    splitT_kernel<<<dim3(F1/32, IN_DIM/32), 256, 0, stream>>>(W1, wt_h, wt_l, IN_DIM, F1);
    aw1_kernel<<<8, 256, 0, stream>>>(W1, a_src1, a_dst1, aw1);
    alpha1_kernel<<<NN/16, 256, 0, stream>>>(x, aw1, asrc, adst);
    agg1_kernel<<<NN/4, 256, 0, stream>>>(x, asrc, adst, rowp, colsrc, ph, pl);
    // out1 = relu(xa @ W1 + b1), block-diagonal per head, split output -> regB
    mfma_gemm_kernel<1,1><<<dim3(MPAD/128, 1, HEADS), 512, 0, stream>>>(
        ph, pl, F1, 128,  wt_h, wt_l, IN_DIM, 128*IN_DIM,
        b1, nullptr, qh, ql, nullptr, F1, 128,  IN_DIM, 1);

    // ---- Layer 2 (project-first, fp16 h2) ----
    splitT_kernel<<<dim3(F1/32, F1/32), 256, 0, stream>>>(W2, wt_h, wt_l, F1, F1);
    mfma_gemm_kernel<0,2><<<dim3((F1/128)*(MPAD/128), 1, 1), 512, 0, stream>>>(
        qh, ql, F1, 0,  wt_h, wt_l, F1, 0,
        nullptr, nullptr, nullptr, nullptr, H16, F1, 0,  F1, F1/128);
    alpha16_h8_kernel<<<NN, 128, 0, stream>>>(H16, a_src2, a_dst2, asrc, adst);
    agg2_kernel<<<NN/4, 256, 0, stream>>>(H16, asrc, adst, rowp, colsrc, b2, qh, ql);

    // ---- Layer 3 (project-first, H=1, fp16 h3) ----
    splitT_kernel<<<dim3(INT_DIM/32, F1/32), 256, 0, stream>>>(W3, wt_h, wt_l, F1, INT_DIM);
    mfma_gemm_kernel<0,2><<<dim3((INT_DIM/128)*(MPAD/128), 1, 1), 512, 0, stream>>>(
        qh, ql, F1, 0,  wt_h, wt_l, F1, 0,
        nullptr, nullptr, nullptr, nullptr, H16, INT_DIM, 0,  F1, INT_DIM/128);
    alpha16_h1_kernel<<<NN, 128, 0, stream>>>(H16, a_src3, a_dst3, asrc, adst);
    agg3_kernel<<<NN/4, 256, 0, stream>>>(H16, asrc, adst, rowp, colsrc, b3, qh, ql);

    // ---- Linear: relu(out3 @ Wl + bl) -> Af fp32 [NN,512] ----
    splitT_kernel<<<dim3(INT_DIM/32, INT_DIM/32), 256, 0, stream>>>(Wl, wt_h, wt_l, INT_DIM, INT_DIM);
    mfma_gemm_kernel<1,0><<<dim3((INT_DIM/128)*(MPAD/128), 1, 1), 512, 0, stream>>>(
        qh, ql, INT_DIM, 0,  wt_h, wt_l, INT_DIM, 0,
        bl, Af, nullptr, nullptr, nullptr, INT_DIM, 0,  INT_DIM, INT_DIM/128);

    // ---- Classifier ----
    cls_kernel<<<(NN+3)/4, 256, 0, stream>>>(Af, Wc, bc, out, NN);
}

// Round 10
// 390.453 us; speedup vs baseline: 1.2295x; 1.0358x over previous
//
#include <hip/hip_runtime.h>
#include <hip/hip_bf16.h>

// Problem constants
#define NN 10000
#define EE 160000
#define IN_DIM 128
#define HID 128
#define HEADS 8
#define F1 (HEADS*HID)   // 1024
#define INT_DIM 512
#define OUT_DIM 3
#define MPAD 10112       // 79 * 128

typedef __attribute__((ext_vector_type(8))) short bf16x8;
typedef __attribute__((ext_vector_type(4))) float f32x4;
typedef __attribute__((ext_vector_type(8))) _Float16 half8;
typedef __attribute__((ext_vector_type(4))) _Float16 half4;

// wave-local LDS fence: wait all this wave's DS ops, and pin program order
#define WAVE_SYNC() do { asm volatile("s_waitcnt lgkmcnt(0)" ::: "memory"); \
                         __builtin_amdgcn_sched_barrier(0); } while(0)

__device__ inline short f2bf(float v){
    union { __hip_bfloat16 b; short s; } u;
    u.b = __float2bfloat16(v);
    return u.s;
}
__device__ inline float bf2f(short s){
    union { short s; __hip_bfloat16 b; } u;
    u.s = s;
    return __bfloat162float(u.b);
}

// ---------------- CSR build ----------------
__global__ __launch_bounds__(256) void count_kernel(const int* __restrict__ dst, int E, int* __restrict__ cnt){
    int e = blockIdx.x*256 + threadIdx.x;
    if(e < E) atomicAdd(&cnt[dst[e]], 1);
}

__global__ __launch_bounds__(256) void scan_kernel(const int* __restrict__ cnt, int* __restrict__ rowp,
                                                   int* __restrict__ cursor, int n){
    __shared__ int sh[256];
    __shared__ int stotal;
    int t = threadIdx.x;
    if(t==0) stotal = 0;
    __syncthreads();
    for(int base=0; base<n; base+=256){
        int i = base + t;
        int v = (i<n) ? cnt[i] : 0;
        sh[t] = v;
        __syncthreads();
        #pragma unroll
        for(int off=1; off<256; off<<=1){
            int add = (t>=off) ? sh[t-off] : 0;
            __syncthreads();
            sh[t] += add;
            __syncthreads();
        }
        int excl = sh[t] - v;
        if(i<n){ rowp[i] = stotal + excl; cursor[i] = stotal + excl; }
        int chunk_total = sh[255];
        __syncthreads();
        if(t==0) stotal += chunk_total;
        __syncthreads();
    }
    if(t==0) rowp[n] = stotal;
}

__global__ __launch_bounds__(256) void fill_kernel(const int* __restrict__ src, const int* __restrict__ dst,
                                                   int E, int* __restrict__ cursor, int* __restrict__ colsrc){
    int e = blockIdx.x*256 + threadIdx.x;
    if(e < E){
        int d = dst[e];
        int pos = atomicAdd(&cursor[d], 1);
        colsrc[pos] = src[e];
    }
}

// ---------------- split + transpose weights: B[K,N] fp32 -> T_hi/T_lo [N,K] bf16 ----------------
__global__ __launch_bounds__(256) void splitT_kernel(const float* __restrict__ B, short* __restrict__ Th,
                                                     short* __restrict__ Tl, int K, int N){
    __shared__ float tile[32][33];
    const int tx = threadIdx.x & 31, ty = threadIdx.x >> 5;   // 32 x 8
    const int n0 = blockIdx.x * 32, k0 = blockIdx.y * 32;
    #pragma unroll
    for(int i = 0; i < 32; i += 8)
        tile[ty + i][tx] = B[(size_t)(k0 + ty + i) * N + n0 + tx];
    __syncthreads();
    #pragma unroll
    for(int i = 0; i < 32; i += 8){
        int n = ty + i;
        float v = tile[tx][n];             // = B[k0+tx][n0+n]
        short hv = f2bf(v);
        Th[(size_t)(n0 + n) * K + k0 + tx] = hv;
        Tl[(size_t)(n0 + n) * K + k0 + tx] = f2bf(v - bf2f(hv));
    }
}

// ---------------- aw1[j][k] = sum_c a[j][c] * W1[k, hj*128+c]  (j<8: a_src, j>=8: a_dst) ----------------
__global__ __launch_bounds__(256) void aw1_kernel(const float* __restrict__ W1,
                                                  const float* __restrict__ a_src,
                                                  const float* __restrict__ a_dst,
                                                  float* __restrict__ aw){
    int idx = blockIdx.x*256 + threadIdx.x;
    if(idx >= 16*IN_DIM) return;
    int j = idx >> 7, k = idx & 127;
    int hj = j & 7;
    const float* av = (j < 8 ? a_src : a_dst) + hj*HID;
    const float* wr = W1 + (size_t)k*F1 + hj*HID;
    float s = 0.f;
    #pragma unroll 4
    for(int c = 0; c < HID; c++) s += av[c] * wr[c];
    aw[idx] = s;
}

// ---------------- alpha1[n, j] = x[n,:] @ aw[j,:]  -> asrc/adst [NN,8] ----------------
__global__ __launch_bounds__(256) void alpha1_kernel(const float* __restrict__ x,
                                                     const float* __restrict__ aw,
                                                     float* __restrict__ asrc, float* __restrict__ adst){
    __shared__ float xs[16][128];
    __shared__ float aws[16][128];
    int t = threadIdx.x;
    int nb = blockIdx.x * 16;
    for(int i = t; i < 16*128; i += 256){
        xs[i >> 7][i & 127] = x[(size_t)nb*128 + i];
        aws[i >> 7][i & 127] = aw[i];
    }
    __syncthreads();
    int nl = t >> 4, j = t & 15;
    float s = 0.f;
    #pragma unroll 4
    for(int c = 0; c < 128; c++) s += xs[nl][c] * aws[j][c];
    int node = nb + nl;
    if(j < 8) asrc[node*8 + j] = s;
    else      adst[node*8 + (j-8)] = s;
}

// ---------------- agg1: per-head softmax-agg of RAW x; 4 nodes/block, 1 wave/node ----------------
__global__ __launch_bounds__(256) void agg1_kernel(const float* __restrict__ x,
                                                   const float* __restrict__ asrc,
                                                   const float* __restrict__ adst,
                                                   const int* __restrict__ rowp,
                                                   const int* __restrict__ colsrc,
                                                   short* __restrict__ oh, short* __restrict__ ol){
    const int w = threadIdx.x >> 6, l = threadIdx.x & 63;
    const int node = blockIdx.x*4 + w;
    __shared__ float sh_ee[4][64][8];
    int beg = rowp[node], end = rowp[node+1];
    float rd = adst[node*8 + (l & 7)];
    float acc0[8], acc1[8];
    #pragma unroll
    for(int h=0;h<8;h++){ acc0[h]=0.f; acc1[h]=0.f; }
    float dpart = 0.f;
    for(int base=beg; base<end; base+=64){
        int clen = min(64, end-base);
        WAVE_SYNC();                        // prior chunk's ee reads complete
        int sreg = (l < clen) ? colsrc[base + l] : 0;
        for(int it=l; it<clen*8; it+=64){
            int j = it >> 3;
            int s = colsrc[base + j];
            float e = asrc[s*8 + (l & 7)] + rd;
            e = (e > 0.f) ? e : 0.2f*e;
            float ee = expf(e);
            sh_ee[w][j][l & 7] = ee;
            dpart += ee;
        }
        WAVE_SYNC();                        // ee visible wave-wide
        #pragma unroll 2
        for(int j=0;j<clen;j++){
            int s = __shfl(sreg, j);
            float2 xv = ((const float2*)(x + (size_t)s*128))[l];
            #pragma unroll
            for(int h=0;h<8;h++){
                float wt = sh_ee[w][j][h];
                acc0[h] += wt * xv.x;
                acc1[h] += wt * xv.y;
            }
        }
    }
    dpart += __shfl_xor(dpart, 8);
    dpart += __shfl_xor(dpart, 16);
    dpart += __shfl_xor(dpart, 32);         // lane l holds denom for head l&7
    #pragma unroll
    for(int h=0;h<8;h++){
        float dn = __shfl(dpart, h) + 1e-16f;
        float v0 = acc0[h]/dn, v1 = acc1[h]/dn;
        short h0 = f2bf(v0), h1 = f2bf(v1);
        short2 hi = { h0, h1 };
        short2 lo = { f2bf(v0 - bf2f(h0)), f2bf(v1 - bf2f(h1)) };
        size_t off = (size_t)node*F1 + h*128 + 2*l;
        *(short2*)(oh + off) = hi;
        *(short2*)(ol + off) = lo;
    }
}

__device__ inline void fma8x2(float* acc, half8 v0, half8 v1, float w0, float w1){
    #pragma unroll
    for(int k=0;k<8;k++){
        acc[k]   += w0 * (float)v0[k];
        acc[8+k] += w1 * (float)v1[k];
    }
}
__device__ inline void fma8(float* acc, half8 v, float w){
    #pragma unroll
    for(int k=0;k<8;k++) acc[k] += w * (float)v[k];
}

// ---------------- agg2: softmax-agg of h2 fp16 [1024]; 1 wave/node, 4-edge pipelined groups ----------------
__global__ __launch_bounds__(256) void agg2_kernel(const _Float16* __restrict__ hbuf,
                                                   const float* __restrict__ asrc,
                                                   const float* __restrict__ adst,
                                                   const int* __restrict__ rowp,
                                                   const int* __restrict__ colsrc,
                                                   const float* __restrict__ bias,
                                                   short* __restrict__ oh, short* __restrict__ ol){
    const int w = threadIdx.x >> 6, l = threadIdx.x & 63;
    const int node = blockIdx.x*4 + w;
    __shared__ float sh_ee[4][64][8];
    int beg = rowp[node], end = rowp[node+1];
    float rd = adst[node*8 + (l & 7)];
    float acc[16];
    #pragma unroll
    for(int k=0;k<16;k++) acc[k]=0.f;
    float dpart = 0.f;
    for(int base=beg; base<end; base+=64){
        int clen = min(64, end-base);
        WAVE_SYNC();                        // prior chunk's ee reads complete
        int sreg = (l < clen) ? colsrc[base + l] : 0;
        // ee for all 64 slots (zero-padded beyond clen)
        #pragma unroll 1
        for(int it=l; it<512; it+=64){
            int j = it >> 3;
            float ee = 0.f;
            if(j < clen){
                int s = colsrc[base + j];
                float e = asrc[s*8 + (l & 7)] + rd;
                e = (e > 0.f) ? e : 0.2f*e;
                ee = expf(e);
                dpart += ee;
            }
            sh_ee[w][j][l & 7] = ee;
        }
        WAVE_SYNC();                        // ee visible wave-wide
        int cpad = (clen + 3) & ~3;
        // 4 edges in flight; each edge: 2 half8 chunks (features 8l.., 512+8l..)
        int sA=__shfl(sreg,0), sB=__shfl(sreg,1), sC=__shfl(sreg,2), sD=__shfl(sreg,3);
        const half8* pA=(const half8*)(hbuf+(size_t)sA*F1);
        const half8* pB=(const half8*)(hbuf+(size_t)sB*F1);
        const half8* pC=(const half8*)(hbuf+(size_t)sC*F1);
        const half8* pD=(const half8*)(hbuf+(size_t)sD*F1);
        half8 vA0=pA[l], vA1=pA[l+64];
        half8 vB0=pB[l], vB1=pB[l+64];
        half8 vC0=pC[l], vC1=pC[l+64];
        half8 vD0=pD[l], vD1=pD[l+64];
        const int h0 = l>>4, h1 = 4 + (l>>4);
        #pragma unroll 1
        for(int j0=0; j0<cpad; j0+=4){
            half8 nA0,nA1,nB0,nB1,nC0,nC1,nD0,nD1;
            const bool more = (j0+4 < cpad);
            if(more){
                int t0=__shfl(sreg,j0+4), t1=__shfl(sreg,j0+5), t2=__shfl(sreg,j0+6), t3=__shfl(sreg,j0+7);
                const half8* q0=(const half8*)(hbuf+(size_t)t0*F1);
                const half8* q1=(const half8*)(hbuf+(size_t)t1*F1);
                const half8* q2=(const half8*)(hbuf+(size_t)t2*F1);
                const half8* q3=(const half8*)(hbuf+(size_t)t3*F1);
                nA0=q0[l]; nA1=q0[l+64];
                nB0=q1[l]; nB1=q1[l+64];
                nC0=q2[l]; nC1=q2[l+64];
                nD0=q3[l]; nD1=q3[l+64];
            }
            fma8x2(acc, vA0, vA1, sh_ee[w][j0  ][h0], sh_ee[w][j0  ][h1]);
            fma8x2(acc, vB0, vB1, sh_ee[w][j0+1][h0], sh_ee[w][j0+1][h1]);
            fma8x2(acc, vC0, vC1, sh_ee[w][j0+2][h0], sh_ee[w][j0+2][h1]);
            fma8x2(acc, vD0, vD1, sh_ee[w][j0+3][h0], sh_ee[w][j0+3][h1]);
            if(more){
                vA0=nA0; vA1=nA1; vB0=nB0; vB1=nB1;
                vC0=nC0; vC1=nC1; vD0=nD0; vD1=nD1;
            }
        }
    }
    dpart += __shfl_xor(dpart, 8);
    dpart += __shfl_xor(dpart, 16);
    dpart += __shfl_xor(dpart, 32);
    float dn0 = __shfl(dpart, l>>4) + 1e-16f;
    float dn1 = __shfl(dpart, 4 + (l>>4)) + 1e-16f;
    const float4* bp = (const float4*)bias;
    float4 ba0 = bp[2*l],       ba1 = bp[2*l+1];       // bias[8l .. 8l+7]
    float4 bc0 = bp[128 + 2*l], bc1 = bp[128 + 2*l+1]; // bias[512+8l ..]
    float bb0[8] = {ba0.x,ba0.y,ba0.z,ba0.w, ba1.x,ba1.y,ba1.z,ba1.w};
    float bb1[8] = {bc0.x,bc0.y,bc0.z,bc0.w, bc1.x,bc1.y,bc1.z,bc1.w};
    bf16x8 hi0, lo0, hi1, lo1;
    #pragma unroll
    for(int k=0;k<8;k++){
        float v0 = fmaxf(acc[k]/dn0 + bb0[k], 0.f);
        float v1 = fmaxf(acc[8+k]/dn1 + bb1[k], 0.f);
        short h0v = f2bf(v0); hi0[k]=h0v; lo0[k]=f2bf(v0 - bf2f(h0v));
        short h1v = f2bf(v1); hi1[k]=h1v; lo1[k]=f2bf(v1 - bf2f(h1v));
    }
    size_t o0 = (size_t)node*F1 + 8*l;
    size_t o1 = o0 + 512;
    *(bf16x8*)(oh + o0) = hi0;  *(bf16x8*)(ol + o0) = lo0;
    *(bf16x8*)(oh + o1) = hi1;  *(bf16x8*)(ol + o1) = lo1;
}

// ---------------- agg3: softmax-agg of h3 fp16 [512] H=1; 1 wave/node, 8-edge pipelined groups ----------------
__global__ __launch_bounds__(256) void agg3_kernel(const _Float16* __restrict__ hbuf,
                                                   const float* __restrict__ asrc,
                                                   const float* __restrict__ adst,
                                                   const int* __restrict__ rowp,
                                                   const int* __restrict__ colsrc,
                                                   const float* __restrict__ bias,
                                                   short* __restrict__ oh, short* __restrict__ ol){
    const int w = threadIdx.x >> 6, l = threadIdx.x & 63;
    const int node = blockIdx.x*4 + w;
    int beg = rowp[node], end = rowp[node+1];
    float rd = adst[node];
    float acc[8];
    #pragma unroll
    for(int k=0;k<8;k++) acc[k]=0.f;
    float dpart = 0.f;
    for(int base=beg; base<end; base+=64){
        int clen = min(64, end-base);
        int sreg = 0; float eereg = 0.f;
        if(l < clen){
            sreg = colsrc[base + l];
            float e = asrc[sreg] + rd;
            e = (e > 0.f) ? e : 0.2f*e;
            eereg = expf(e);
            dpart += eereg;
        }
        int cpad = (clen + 7) & ~7;
        half8 v[8];
        float wt[8];
        #pragma unroll
        for(int k=0;k<8;k++){
            int s = __shfl(sreg, k);
            wt[k] = __shfl(eereg, k);
            v[k] = ((const half8*)(hbuf + (size_t)s*INT_DIM))[l];
        }
        #pragma unroll 1
        for(int j0=0; j0<cpad; j0+=8){
            half8 nv[8]; float nw[8];
            const bool more = (j0+8 < cpad);
            if(more){
                #pragma unroll
                for(int k=0;k<8;k++){
                    int s = __shfl(sreg, j0+8+k);
                    nw[k] = __shfl(eereg, j0+8+k);
                    nv[k] = ((const half8*)(hbuf + (size_t)s*INT_DIM))[l];
                }
            }
            #pragma unroll
            for(int k=0;k<8;k++) fma8(acc, v[k], wt[k]);
            if(more){
                #pragma unroll
                for(int k=0;k<8;k++){ v[k]=nv[k]; wt[k]=nw[k]; }
            }
        }
    }
    #pragma unroll
    for(int off=1; off<64; off<<=1) dpart += __shfl_xor(dpart, off);
    float dn = dpart + 1e-16f;
    const float4* bp = (const float4*)bias;
    float4 ba0 = bp[2*l], ba1 = bp[2*l+1];    // bias[8l .. 8l+7]
    float bb[8] = {ba0.x,ba0.y,ba0.z,ba0.w, ba1.x,ba1.y,ba1.z,ba1.w};
    bf16x8 hi, lo;
    #pragma unroll
    for(int k=0;k<8;k++){
        float vv = fmaxf(acc[k]/dn + bb[k], 0.f);
        short hv = f2bf(vv); hi[k]=hv; lo[k]=f2bf(vv - bf2f(hv));
    }
    size_t o = (size_t)node*INT_DIM + 8*l;
    *(bf16x8*)(oh + o) = hi;
    *(bf16x8*)(ol + o) = lo;
}

// ---------------- fused split-bf16 MFMA GEMM, 8 waves (2x4), 128x128 tile ----------------
// 2-phase double-buffered K-loop: stage(next) -> compute(cur) -> single __syncthreads.
// Swizzle involution (both sides): slot ^= (row>>1)&3  -> bank-quad bijective on 8 rows.
// OUT: 0=fp32, 1=split bf16 pair, 2=fp16
template<int FUSE, int OUT>
__global__ __launch_bounds__(512, 4) void mfma_gemm_kernel(
    const short* __restrict__ Ah, const short* __restrict__ Al, int lda, int za,
    const short* __restrict__ Bh, const short* __restrict__ Bl, int ldb, int zb,
    const float* __restrict__ bias, float* __restrict__ C,
    short* __restrict__ Gh, short* __restrict__ Gl, _Float16* __restrict__ Hf,
    int ldc, int zc, int K, int gx)
{
    __shared__ short lAh[2][128*32];   // 16 KB each (double-buffered)
    __shared__ short lAl[2][128*32];
    __shared__ short lBh[2][128*32];
    __shared__ short lBl[2][128*32];
    const int tid  = threadIdx.x;
    const int lane = tid & 63;
    const int w    = tid >> 6;      // 0..7
    const int wm   = w >> 2;        // 0..1 (row half)
    const int wn   = w & 3;         // 0..3 (col quarter)
    const int z    = blockIdx.z;

    // XCD-bijective swizzle
    const int nwg = gridDim.x;
    const int q = nwg >> 3, r = nwg & 7;
    const int xcd = blockIdx.x & 7, idx = blockIdx.x >> 3;
    const int wgid = (xcd < r ? xcd*(q+1) : r*(q+1) + (xcd-r)*q) + idx;
    const int row0 = (wgid / gx) * 128, col0 = (wgid % gx) * 128;

    f32x4 acc[4][2];
    #pragma unroll
    for(int i=0;i<4;i++)
        #pragma unroll
        for(int j=0;j<2;j++) acc[i][j] = (f32x4){0.f,0.f,0.f,0.f};

    // staging: 512 lanes cover 128 rows x 4 slots of 16B; LDS slot written = tid&3
    const int rr1 = tid >> 2;                        // 0..127
    const int ss1 = (tid & 3) ^ ((rr1 >> 1) & 3);    // swizzled global slot
    const size_t aoff = (size_t)(row0 + rr1) * lda + (size_t)z*za + ss1 * 8;
    const size_t boff = (size_t)(col0 + rr1) * ldb + (size_t)z*zb + ss1 * 8;

    typedef __attribute__((address_space(3))) char lds_char;
    lds_char* dAh = (lds_char*)(&lAh[0][0]) + w*1024;
    lds_char* dAl = (lds_char*)(&lAl[0][0]) + w*1024;
    lds_char* dBh = (lds_char*)(&lBh[0][0]) + w*1024;
    lds_char* dBl = (lds_char*)(&lBl[0][0]) + w*1024;

    // fragment read byte-offsets: row's global slot g = lane>>4, LDS slot = g ^ ((row>>1)&3);
    // row & 15 == lane & 15 for all fragments (16-aligned row bases)
    int arow[4], brow[2];
    const int slotx = ((lane >> 4) ^ ((lane >> 1) & 3)) << 4;
    #pragma unroll
    for(int i=0;i<4;i++)
        arow[i] = (wm*64 + i*16 + (lane & 15)) * 64 + slotx;
    #pragma unroll
    for(int j=0;j<2;j++)
        brow[j] = (wn*32 + j*16 + (lane & 15)) * 64 + slotx;

    #define GLDS(src, dst) __builtin_amdgcn_global_load_lds( \
        (__attribute__((address_space(1))) void*)(src), \
        (__attribute__((address_space(3))) void*)(dst), 16, 0, 0)
    // prologue: stage tile 0 into buffer 0
    GLDS(Ah + aoff, dAh);
    GLDS(Al + aoff, dAl);
    GLDS(Bh + boff, dBh);
    GLDS(Bl + boff, dBl);
    __syncthreads();

    #pragma unroll 1
    for(int k0 = 0, kb = 0; k0 < K; k0 += 32, kb ^= 1){
        // stage NEXT tile into the other buffer (overlaps with compute below)
        if(k0 + 32 < K){
            const int nb = kb ^ 1;
            GLDS(Ah + aoff + k0 + 32, dAh + nb*8192);
            GLDS(Al + aoff + k0 + 32, dAl + nb*8192);
            GLDS(Bh + boff + k0 + 32, dBh + nb*8192);
            GLDS(Bl + boff + k0 + 32, dBl + nb*8192);
        }
        // compute CURRENT buffer
        const char* pAh = (const char*)(&lAh[0][0]) + kb*8192;
        const char* pAl = (const char*)(&lAl[0][0]) + kb*8192;
        const char* pBh = (const char*)(&lBh[0][0]) + kb*8192;
        const char* pBl = (const char*)(&lBl[0][0]) + kb*8192;
        bf16x8 afh[4], afl[4];
        #pragma unroll
        for(int i=0;i<4;i++){
            afh[i] = *(const bf16x8*)(pAh + arow[i]);
            afl[i] = *(const bf16x8*)(pAl + arow[i]);
        }
        #pragma unroll
        for(int j=0;j<2;j++){
            bf16x8 bh = *(const bf16x8*)(pBh + brow[j]);
            bf16x8 bl = *(const bf16x8*)(pBl + brow[j]);
            #pragma unroll
            for(int i=0;i<4;i++){
                acc[i][j] = __builtin_amdgcn_mfma_f32_16x16x32_bf16(afh[i], bh, acc[i][j], 0, 0, 0);
                acc[i][j] = __builtin_amdgcn_mfma_f32_16x16x32_bf16(afh[i], bl, acc[i][j], 0, 0, 0);
                acc[i][j] = __builtin_amdgcn_mfma_f32_16x16x32_bf16(afl[i], bh, acc[i][j], 0, 0, 0);
            }
        }
        // single barrier: drains this wave's staged loads (vmcnt0) and guards buffer reuse
        __syncthreads();
    }
    #undef GLDS

    // epilogue: C/D layout col=lane&15, row=(lane>>4)*4+reg
    #pragma unroll
    for(int i=0;i<4;i++){
        const int rr = row0 + wm*64 + i*16 + ((lane >> 4) << 2);
        #pragma unroll
        for(int j=0;j<2;j++){
            const int gc = z*zc + col0 + wn*32 + j*16 + (lane & 15);
            float b = FUSE ? bias[gc] : 0.f;
            #pragma unroll
            for(int rg=0;rg<4;rg++){
                float v = acc[i][j][rg];
                if(FUSE) v = fmaxf(v + b, 0.f);
                if(OUT == 1){
                    short hv = f2bf(v);
                    Gh[(size_t)(rr + rg) * ldc + gc] = hv;
                    Gl[(size_t)(rr + rg) * ldc + gc] = f2bf(v - bf2f(hv));
                } else if(OUT == 2){
                    Hf[(size_t)(rr + rg) * ldc + gc] = (_Float16)v;
                } else {
                    C[(size_t)(rr + rg) * ldc + gc] = v;
                }
            }
        }
    }
}

// ---------------- alpha from fp16 h: H=8, C=128 (thread t -> head t>>4, 8 features) ----------------
__global__ __launch_bounds__(128) void alpha16_h8_kernel(const _Float16* __restrict__ hbuf,
                                                         const float* __restrict__ a_src,
                                                         const float* __restrict__ a_dst,
                                                         float* __restrict__ asrc, float* __restrict__ adst){
    int node = blockIdx.x;
    int t = threadIdx.x;          // 128 threads; features 8t..8t+7, head t>>4
    half8 v = ((const half8*)(hbuf + (size_t)node*F1))[t];
    const float4* ap = (const float4*)(a_src + 8*t);
    const float4* dp = (const float4*)(a_dst + 8*t);
    float4 a0 = ap[0], a1 = ap[1];
    float4 d0 = dp[0], d1 = dp[1];
    float av[8] = {a0.x,a0.y,a0.z,a0.w, a1.x,a1.y,a1.z,a1.w};
    float dv[8] = {d0.x,d0.y,d0.z,d0.w, d1.x,d1.y,d1.z,d1.w};
    float ps = 0.f, pd = 0.f;
    #pragma unroll
    for(int k=0;k<8;k++){
        float f = (float)v[k];
        ps += f * av[k];
        pd += f * dv[k];
    }
    #pragma unroll
    for(int off=8; off; off>>=1){ ps += __shfl_down(ps, off); pd += __shfl_down(pd, off); }
    if((t & 15) == 0){
        asrc[(size_t)node*8 + (t>>4)] = ps;
        adst[(size_t)node*8 + (t>>4)] = pd;
    }
}

// ---------------- alpha from fp16 h: H=1, C=512 ----------------
__global__ __launch_bounds__(128) void alpha16_h1_kernel(const _Float16* __restrict__ hbuf,
                                                         const float* __restrict__ a_src,
                                                         const float* __restrict__ a_dst,
                                                         float* __restrict__ asrc, float* __restrict__ adst){
    int node = blockIdx.x;
    int t = threadIdx.x;          // 128 threads; features 4t..4t+3
    half4 v = ((const half4*)(hbuf + (size_t)node*INT_DIM))[t];
    float4 a = ((const float4*)a_src)[t];
    float4 d = ((const float4*)a_dst)[t];
    float ps = (float)v[0]*a.x + (float)v[1]*a.y + (float)v[2]*a.z + (float)v[3]*a.w;
    float pd = (float)v[0]*d.x + (float)v[1]*d.y + (float)v[2]*d.z + (float)v[3]*d.w;
    #pragma unroll
    for(int off=32; off; off>>=1){ ps += __shfl_down(ps, off); pd += __shfl_down(pd, off); }
    __shared__ float shs[2], shd[2];
    int wv = t >> 6;
    if((t & 63) == 0){ shs[wv] = ps; shd[wv] = pd; }
    __syncthreads();
    if(t == 0){
        asrc[node] = shs[0] + shs[1];
        adst[node] = shd[0] + shd[1];
    }
}

// ---------------- classifier: out[n,3] = h[n,:512] @ Wc + bc ----------------
__global__ __launch_bounds__(256) void cls_kernel(const float* __restrict__ h, const float* __restrict__ Wc,
                                                  const float* __restrict__ bc, float* __restrict__ out, int n){
    int node = blockIdx.x*4 + (threadIdx.x >> 6);
    int lane = threadIdx.x & 63;
    if(node >= n) return;
    float s0=0.f, s1=0.f, s2=0.f;
    const float* hr = h + (size_t)node*INT_DIM;
    for(int k=lane; k<INT_DIM; k+=64){
        float v = hr[k];
        s0 += v * Wc[k*3+0];
        s1 += v * Wc[k*3+1];
        s2 += v * Wc[k*3+2];
    }
    #pragma unroll
    for(int off=32; off; off>>=1){
        s0 += __shfl_down(s0, off);
        s1 += __shfl_down(s1, off);
        s2 += __shfl_down(s2, off);
    }
    if(lane==0){
        out[(size_t)node*3+0] = s0 + bc[0];
        out[(size_t)node*3+1] = s1 + bc[1];
        out[(size_t)node*3+2] = s2 + bc[2];
    }
}

extern "C" void kernel_launch(void* const* d_in, const int* in_sizes, int n_in,
                              void* d_out, int out_size, void* d_ws, size_t ws_size,
                              hipStream_t stream){
    const float* x      = (const float*)d_in[0];
    const int*   ei     = (const int*)d_in[1];
    const float* W1     = (const float*)d_in[2];
    const float* a_src1 = (const float*)d_in[3];
    const float* a_dst1 = (const float*)d_in[4];
    const float* b1     = (const float*)d_in[5];
    const float* W2     = (const float*)d_in[6];
    const float* a_src2 = (const float*)d_in[7];
    const float* a_dst2 = (const float*)d_in[8];
    const float* b2     = (const float*)d_in[9];
    const float* W3     = (const float*)d_in[10];
    const float* a_src3 = (const float*)d_in[11];
    const float* a_dst3 = (const float*)d_in[12];
    const float* b3     = (const float*)d_in[13];
    const float* Wl     = (const float*)d_in[14];
    const float* bl     = (const float*)d_in[15];
    const float* Wc     = (const float*)d_in[16];
    const float* bc     = (const float*)d_in[17];
    float* out = (float*)d_out;

    const int* src = ei;
    const int* dst = ei + EE;

    // workspace carve: two big regions (41.4 MB each) + weights + small
    char* p = (char*)d_ws;
    char* regA = p;  p += (size_t)MPAD*F1*4;            // {ph,pl} OR fp16 h OR fp32 Af
    char* regB = p;  p += (size_t)MPAD*F1*4;            // pair {qh,ql}
    short* wt_h = (short*)p;  p += (size_t)F1*F1*2;     // 2.1 MB
    short* wt_l = (short*)p;  p += (size_t)F1*F1*2;     // 2.1 MB
    float* aw1  = (float*)p;  p += 16*IN_DIM*4;
    float* asrc = (float*)p;  p += (size_t)NN*HEADS*4;
    float* adst = (float*)p;  p += (size_t)NN*HEADS*4;
    int* cnt    = (int*)p;    p += NN*4;
    int* rowp   = (int*)p;    p += (NN+1)*4;
    int* cursor = (int*)p;    p += NN*4;
    int* colsrc = (int*)p;    p += EE*4;

    short* ph = (short*)regA;  short* pl = ph + (size_t)MPAD*F1;
    float* Af = (float*)regA;
    _Float16* H16 = (_Float16*)regA;
    short* qh = (short*)regB;  short* ql = qh + (size_t)MPAD*F1;

    // ---- CSR build (by dst) ----
    hipMemsetAsync(cnt, 0, NN*sizeof(int), stream);
    count_kernel<<<(EE+255)/256, 256, 0, stream>>>(dst, EE, cnt);
    scan_kernel<<<1, 256, 0, stream>>>(cnt, rowp, cursor, NN);
    fill_kernel<<<(EE+255)/256, 256, 0, stream>>>(src, dst, EE, cursor, colsrc);

    // ---- Layer 1 (agg-first via linearity) ----
    splitT_kernel<<<dim3(F1/32, IN_DIM/32), 256, 0, stream>>>(W1, wt_h, wt_l, IN_DIM, F1);
    aw1_kernel<<<8, 256, 0, stream>>>(W1, a_src1, a_dst1, aw1);
    alpha1_kernel<<<NN/16, 256, 0, stream>>>(x, aw1, asrc, adst);
    agg1_kernel<<<NN/4, 256, 0, stream>>>(x, asrc, adst, rowp, colsrc, ph, pl);
    // out1 = relu(xa @ W1 + b1), block-diagonal per head, split output -> regB
    mfma_gemm_kernel<1,1><<<dim3(MPAD/128, 1, HEADS), 512, 0, stream>>>(
        ph, pl, F1, 128,  wt_h, wt_l, IN_DIM, 128*IN_DIM,
        b1, nullptr, qh, ql, nullptr, F1, 128,  IN_DIM, 1);

    // ---- Layer 2 (project-first, fp16 h2) ----
    splitT_kernel<<<dim3(F1/32, F1/32), 256, 0, stream>>>(W2, wt_h, wt_l, F1, F1);
    mfma_gemm_kernel<0,2><<<dim3((F1/128)*(MPAD/128), 1, 1), 512, 0, stream>>>(
        qh, ql, F1, 0,  wt_h, wt_l, F1, 0,
        nullptr, nullptr, nullptr, nullptr, H16, F1, 0,  F1, F1/128);
    alpha16_h8_kernel<<<NN, 128, 0, stream>>>(H16, a_src2, a_dst2, asrc, adst);
    agg2_kernel<<<NN/4, 256, 0, stream>>>(H16, asrc, adst, rowp, colsrc, b2, qh, ql);

    // ---- Layer 3 (project-first, H=1, fp16 h3) ----
    splitT_kernel<<<dim3(INT_DIM/32, F1/32), 256, 0, stream>>>(W3, wt_h, wt_l, F1, INT_DIM);
    mfma_gemm_kernel<0,2><<<dim3((INT_DIM/128)*(MPAD/128), 1, 1), 512, 0, stream>>>(
        qh, ql, F1, 0,  wt_h, wt_l, F1, 0,
        nullptr, nullptr, nullptr, nullptr, H16, INT_DIM, 0,  F1, INT_DIM/128);
    alpha16_h1_kernel<<<NN, 128, 0, stream>>>(H16, a_src3, a_dst3, asrc, adst);
    agg3_kernel<<<NN/4, 256, 0, stream>>>(H16, asrc, adst, rowp, colsrc, b3, qh, ql);

    // ---- Linear: relu(out3 @ Wl + bl) -> Af fp32 [NN,512] ----
    splitT_kernel<<<dim3(INT_DIM/32, INT_DIM/32), 256, 0, stream>>>(Wl, wt_h, wt_l, INT_DIM, INT_DIM);
    mfma_gemm_kernel<1,0><<<dim3((INT_DIM/128)*(MPAD/128), 1, 1), 512, 0, stream>>>(
        qh, ql, INT_DIM, 0,  wt_h, wt_l, INT_DIM, 0,
        bl, Af, nullptr, nullptr, nullptr, INT_DIM, 0,  INT_DIM, INT_DIM/128);

    // ---- Classifier ----
    cls_kernel<<<(NN+3)/4, 256, 0, stream>>>(Af, Wc, bc, out, NN);
}

// Round 11
// 306.513 us; speedup vs baseline: 1.5662x; 1.2739x over previous
//
#include <hip/hip_runtime.h>
#include <hip/hip_bf16.h>

// Problem constants
#define NN 10000
#define EE 160000
#define IN_DIM 128
#define HID 128
#define HEADS 8
#define F1 (HEADS*HID)   // 1024
#define INT_DIM 512
#define OUT_DIM 3
#define MPAD 10112       // 79 * 128

typedef __attribute__((ext_vector_type(8))) short bf16x8;
typedef __attribute__((ext_vector_type(4))) float f32x4;
typedef __attribute__((ext_vector_type(8))) _Float16 half8;
typedef __attribute__((ext_vector_type(4))) _Float16 half4;
typedef __attribute__((ext_vector_type(2))) _Float16 half2v;

// wave-local LDS fence: wait all this wave's DS ops, and pin program order
#define WAVE_SYNC() do { asm volatile("s_waitcnt lgkmcnt(0)" ::: "memory"); \
                         __builtin_amdgcn_sched_barrier(0); } while(0)

__device__ inline short f2bf(float v){
    union { __hip_bfloat16 b; short s; } u;
    u.b = __float2bfloat16(v);
    return u.s;
}
__device__ inline float bf2f(short s){
    union { short s; __hip_bfloat16 b; } u;
    u.s = s;
    return __bfloat162float(u.b);
}

// ---------------- CSR build ----------------
__global__ __launch_bounds__(256) void count_kernel(const int* __restrict__ dst, int E, int* __restrict__ cnt){
    int e = blockIdx.x*256 + threadIdx.x;
    if(e < E) atomicAdd(&cnt[dst[e]], 1);
}

__global__ __launch_bounds__(256) void scan_kernel(const int* __restrict__ cnt, int* __restrict__ rowp,
                                                   int* __restrict__ cursor, int n){
    __shared__ int sh[256];
    __shared__ int stotal;
    int t = threadIdx.x;
    if(t==0) stotal = 0;
    __syncthreads();
    for(int base=0; base<n; base+=256){
        int i = base + t;
        int v = (i<n) ? cnt[i] : 0;
        sh[t] = v;
        __syncthreads();
        #pragma unroll
        for(int off=1; off<256; off<<=1){
            int add = (t>=off) ? sh[t-off] : 0;
            __syncthreads();
            sh[t] += add;
            __syncthreads();
        }
        int excl = sh[t] - v;
        if(i<n){ rowp[i] = stotal + excl; cursor[i] = stotal + excl; }
        int chunk_total = sh[255];
        __syncthreads();
        if(t==0) stotal += chunk_total;
        __syncthreads();
    }
    if(t==0) rowp[n] = stotal;
}

__global__ __launch_bounds__(256) void fill_kernel(const int* __restrict__ src, const int* __restrict__ dst,
                                                   int E, int* __restrict__ cursor, int* __restrict__ colsrc){
    int e = blockIdx.x*256 + threadIdx.x;
    if(e < E){
        int d = dst[e];
        int pos = atomicAdd(&cursor[d], 1);
        colsrc[pos] = src[e];
    }
}

// ---------------- split + transpose weights: B[K,N] fp32 -> T_hi/T_lo [N,K] bf16 ----------------
__global__ __launch_bounds__(256) void splitT_kernel(const float* __restrict__ B, short* __restrict__ Th,
                                                     short* __restrict__ Tl, int K, int N){
    __shared__ float tile[32][33];
    const int tx = threadIdx.x & 31, ty = threadIdx.x >> 5;   // 32 x 8
    const int n0 = blockIdx.x * 32, k0 = blockIdx.y * 32;
    #pragma unroll
    for(int i = 0; i < 32; i += 8)
        tile[ty + i][tx] = B[(size_t)(k0 + ty + i) * N + n0 + tx];
    __syncthreads();
    #pragma unroll
    for(int i = 0; i < 32; i += 8){
        int n = ty + i;
        float v = tile[tx][n];             // = B[k0+tx][n0+n]
        short hv = f2bf(v);
        Th[(size_t)(n0 + n) * K + k0 + tx] = hv;
        Tl[(size_t)(n0 + n) * K + k0 + tx] = f2bf(v - bf2f(hv));
    }
}

// ---------------- transpose weights to fp16: B[K,N] fp32 -> T [N,K] fp16 ----------------
__global__ __launch_bounds__(256) void splitT16_kernel(const float* __restrict__ B, _Float16* __restrict__ T,
                                                       int K, int N){
    __shared__ float tile[32][33];
    const int tx = threadIdx.x & 31, ty = threadIdx.x >> 5;   // 32 x 8
    const int n0 = blockIdx.x * 32, k0 = blockIdx.y * 32;
    #pragma unroll
    for(int i = 0; i < 32; i += 8)
        tile[ty + i][tx] = B[(size_t)(k0 + ty + i) * N + n0 + tx];
    __syncthreads();
    #pragma unroll
    for(int i = 0; i < 32; i += 8){
        int n = ty + i;
        T[(size_t)(n0 + n) * K + k0 + tx] = (_Float16)tile[tx][n];
    }
}

// ---------------- aw1[j][k] = sum_c a[j][c] * W1[k, hj*128+c]  (j<8: a_src, j>=8: a_dst) ----------------
__global__ __launch_bounds__(256) void aw1_kernel(const float* __restrict__ W1,
                                                  const float* __restrict__ a_src,
                                                  const float* __restrict__ a_dst,
                                                  float* __restrict__ aw){
    int idx = blockIdx.x*256 + threadIdx.x;
    if(idx >= 16*IN_DIM) return;
    int j = idx >> 7, k = idx & 127;
    int hj = j & 7;
    const float* av = (j < 8 ? a_src : a_dst) + hj*HID;
    const float* wr = W1 + (size_t)k*F1 + hj*HID;
    float s = 0.f;
    #pragma unroll 4
    for(int c = 0; c < HID; c++) s += av[c] * wr[c];
    aw[idx] = s;
}

// ---------------- alpha1[n, j] = x[n,:] @ aw[j,:]  -> asrc/adst [NN,8] ----------------
__global__ __launch_bounds__(256) void alpha1_kernel(const float* __restrict__ x,
                                                     const float* __restrict__ aw,
                                                     float* __restrict__ asrc, float* __restrict__ adst){
    __shared__ float xs[16][128];
    __shared__ float aws[16][128];
    int t = threadIdx.x;
    int nb = blockIdx.x * 16;
    for(int i = t; i < 16*128; i += 256){
        xs[i >> 7][i & 127] = x[(size_t)nb*128 + i];
        aws[i >> 7][i & 127] = aw[i];
    }
    __syncthreads();
    int nl = t >> 4, j = t & 15;
    float s = 0.f;
    #pragma unroll 4
    for(int c = 0; c < 128; c++) s += xs[nl][c] * aws[j][c];
    int node = nb + nl;
    if(j < 8) asrc[node*8 + j] = s;
    else      adst[node*8 + (j-8)] = s;
}

// ---------------- agg1: per-head softmax-agg of RAW x; 4 nodes/block, 1 wave/node; emits fp16 ----------------
__global__ __launch_bounds__(256) void agg1_kernel(const float* __restrict__ x,
                                                   const float* __restrict__ asrc,
                                                   const float* __restrict__ adst,
                                                   const int* __restrict__ rowp,
                                                   const int* __restrict__ colsrc,
                                                   _Float16* __restrict__ oa){
    const int w = threadIdx.x >> 6, l = threadIdx.x & 63;
    const int node = blockIdx.x*4 + w;
    __shared__ float sh_ee[4][64][8];
    int beg = rowp[node], end = rowp[node+1];
    float rd = adst[node*8 + (l & 7)];
    float acc0[8], acc1[8];
    #pragma unroll
    for(int h=0;h<8;h++){ acc0[h]=0.f; acc1[h]=0.f; }
    float dpart = 0.f;
    for(int base=beg; base<end; base+=64){
        int clen = min(64, end-base);
        WAVE_SYNC();                        // prior chunk's ee reads complete
        int sreg = (l < clen) ? colsrc[base + l] : 0;
        for(int it=l; it<clen*8; it+=64){
            int j = it >> 3;
            int s = colsrc[base + j];
            float e = asrc[s*8 + (l & 7)] + rd;
            e = (e > 0.f) ? e : 0.2f*e;
            float ee = expf(e);
            sh_ee[w][j][l & 7] = ee;
            dpart += ee;
        }
        WAVE_SYNC();                        // ee visible wave-wide
        #pragma unroll 2
        for(int j=0;j<clen;j++){
            int s = __shfl(sreg, j);
            float2 xv = ((const float2*)(x + (size_t)s*128))[l];
            #pragma unroll
            for(int h=0;h<8;h++){
                float wt = sh_ee[w][j][h];
                acc0[h] += wt * xv.x;
                acc1[h] += wt * xv.y;
            }
        }
    }
    dpart += __shfl_xor(dpart, 8);
    dpart += __shfl_xor(dpart, 16);
    dpart += __shfl_xor(dpart, 32);         // lane l holds denom for head l&7
    #pragma unroll
    for(int h=0;h<8;h++){
        float dn = __shfl(dpart, h) + 1e-16f;
        half2v o = { (_Float16)(acc0[h]/dn), (_Float16)(acc1[h]/dn) };
        *(half2v*)(oa + (size_t)node*F1 + h*128 + 2*l) = o;
    }
}

__device__ inline void fma8x2(float* acc, half8 v0, half8 v1, float w0, float w1){
    #pragma unroll
    for(int k=0;k<8;k++){
        acc[k]   += w0 * (float)v0[k];
        acc[8+k] += w1 * (float)v1[k];
    }
}
__device__ inline void fma8(float* acc, half8 v, float w){
    #pragma unroll
    for(int k=0;k<8;k++) acc[k] += w * (float)v[k];
}

// ---------------- agg2: softmax-agg of h2 fp16 [1024]; 1 wave/node, 4-edge pipelined; emits fp16 ----------------
__global__ __launch_bounds__(256) void agg2_kernel(const _Float16* __restrict__ hbuf,
                                                   const float* __restrict__ asrc,
                                                   const float* __restrict__ adst,
                                                   const int* __restrict__ rowp,
                                                   const int* __restrict__ colsrc,
                                                   const float* __restrict__ bias,
                                                   _Float16* __restrict__ oa){
    const int w = threadIdx.x >> 6, l = threadIdx.x & 63;
    const int node = blockIdx.x*4 + w;
    __shared__ float sh_ee[4][64][8];
    int beg = rowp[node], end = rowp[node+1];
    float rd = adst[node*8 + (l & 7)];
    float acc[16];
    #pragma unroll
    for(int k=0;k<16;k++) acc[k]=0.f;
    float dpart = 0.f;
    for(int base=beg; base<end; base+=64){
        int clen = min(64, end-base);
        WAVE_SYNC();                        // prior chunk's ee reads complete
        int sreg = (l < clen) ? colsrc[base + l] : 0;
        // ee for all 64 slots (zero-padded beyond clen)
        #pragma unroll 1
        for(int it=l; it<512; it+=64){
            int j = it >> 3;
            float ee = 0.f;
            if(j < clen){
                int s = colsrc[base + j];
                float e = asrc[s*8 + (l & 7)] + rd;
                e = (e > 0.f) ? e : 0.2f*e;
                ee = expf(e);
                dpart += ee;
            }
            sh_ee[w][j][l & 7] = ee;
        }
        WAVE_SYNC();                        // ee visible wave-wide
        int cpad = (clen + 3) & ~3;
        // 4 edges in flight; each edge: 2 half8 chunks (features 8l.., 512+8l..)
        int sA=__shfl(sreg,0), sB=__shfl(sreg,1), sC=__shfl(sreg,2), sD=__shfl(sreg,3);
        const half8* pA=(const half8*)(hbuf+(size_t)sA*F1);
        const half8* pB=(const half8*)(hbuf+(size_t)sB*F1);
        const half8* pC=(const half8*)(hbuf+(size_t)sC*F1);
        const half8* pD=(const half8*)(hbuf+(size_t)sD*F1);
        half8 vA0=pA[l], vA1=pA[l+64];
        half8 vB0=pB[l], vB1=pB[l+64];
        half8 vC0=pC[l], vC1=pC[l+64];
        half8 vD0=pD[l], vD1=pD[l+64];
        const int h0 = l>>4, h1 = 4 + (l>>4);
        #pragma unroll 1
        for(int j0=0; j0<cpad; j0+=4){
            half8 nA0,nA1,nB0,nB1,nC0,nC1,nD0,nD1;
            const bool more = (j0+4 < cpad);
            if(more){
                int t0=__shfl(sreg,j0+4), t1=__shfl(sreg,j0+5), t2=__shfl(sreg,j0+6), t3=__shfl(sreg,j0+7);
                const half8* q0=(const half8*)(hbuf+(size_t)t0*F1);
                const half8* q1=(const half8*)(hbuf+(size_t)t1*F1);
                const half8* q2=(const half8*)(hbuf+(size_t)t2*F1);
                const half8* q3=(const half8*)(hbuf+(size_t)t3*F1);
                nA0=q0[l]; nA1=q0[l+64];
                nB0=q1[l]; nB1=q1[l+64];
                nC0=q2[l]; nC1=q2[l+64];
                nD0=q3[l]; nD1=q3[l+64];
            }
            fma8x2(acc, vA0, vA1, sh_ee[w][j0  ][h0], sh_ee[w][j0  ][h1]);
            fma8x2(acc, vB0, vB1, sh_ee[w][j0+1][h0], sh_ee[w][j0+1][h1]);
            fma8x2(acc, vC0, vC1, sh_ee[w][j0+2][h0], sh_ee[w][j0+2][h1]);
            fma8x2(acc, vD0, vD1, sh_ee[w][j0+3][h0], sh_ee[w][j0+3][h1]);
            if(more){
                vA0=nA0; vA1=nA1; vB0=nB0; vB1=nB1;
                vC0=nC0; vC1=nC1; vD0=nD0; vD1=nD1;
            }
        }
    }
    dpart += __shfl_xor(dpart, 8);
    dpart += __shfl_xor(dpart, 16);
    dpart += __shfl_xor(dpart, 32);
    float dn0 = __shfl(dpart, l>>4) + 1e-16f;
    float dn1 = __shfl(dpart, 4 + (l>>4)) + 1e-16f;
    const float4* bp = (const float4*)bias;
    float4 ba0 = bp[2*l],       ba1 = bp[2*l+1];       // bias[8l .. 8l+7]
    float4 bc0 = bp[128 + 2*l], bc1 = bp[128 + 2*l+1]; // bias[512+8l ..]
    float bb0[8] = {ba0.x,ba0.y,ba0.z,ba0.w, ba1.x,ba1.y,ba1.z,ba1.w};
    float bb1[8] = {bc0.x,bc0.y,bc0.z,bc0.w, bc1.x,bc1.y,bc1.z,bc1.w};
    half8 o0, o1;
    #pragma unroll
    for(int k=0;k<8;k++){
        o0[k] = (_Float16)fmaxf(acc[k]/dn0 + bb0[k], 0.f);
        o1[k] = (_Float16)fmaxf(acc[8+k]/dn1 + bb1[k], 0.f);
    }
    size_t off0 = (size_t)node*F1 + 8*l;
    *(half8*)(oa + off0) = o0;
    *(half8*)(oa + off0 + 512) = o1;
}

// ---------------- agg3: softmax-agg of h3 fp16 [512] H=1; emits split bf16 (for Wl 3-pass) ----------------
__global__ __launch_bounds__(256) void agg3_kernel(const _Float16* __restrict__ hbuf,
                                                   const float* __restrict__ asrc,
                                                   const float* __restrict__ adst,
                                                   const int* __restrict__ rowp,
                                                   const int* __restrict__ colsrc,
                                                   const float* __restrict__ bias,
                                                   short* __restrict__ oh, short* __restrict__ ol){
    const int w = threadIdx.x >> 6, l = threadIdx.x & 63;
    const int node = blockIdx.x*4 + w;
    int beg = rowp[node], end = rowp[node+1];
    float rd = adst[node];
    float acc[8];
    #pragma unroll
    for(int k=0;k<8;k++) acc[k]=0.f;
    float dpart = 0.f;
    for(int base=beg; base<end; base+=64){
        int clen = min(64, end-base);
        int sreg = 0; float eereg = 0.f;
        if(l < clen){
            sreg = colsrc[base + l];
            float e = asrc[sreg] + rd;
            e = (e > 0.f) ? e : 0.2f*e;
            eereg = expf(e);
            dpart += eereg;
        }
        int cpad = (clen + 7) & ~7;
        half8 v[8];
        float wt[8];
        #pragma unroll
        for(int k=0;k<8;k++){
            int s = __shfl(sreg, k);
            wt[k] = __shfl(eereg, k);
            v[k] = ((const half8*)(hbuf + (size_t)s*INT_DIM))[l];
        }
        #pragma unroll 1
        for(int j0=0; j0<cpad; j0+=8){
            half8 nv[8]; float nw[8];
            const bool more = (j0+8 < cpad);
            if(more){
                #pragma unroll
                for(int k=0;k<8;k++){
                    int s = __shfl(sreg, j0+8+k);
                    nw[k] = __shfl(eereg, j0+8+k);
                    nv[k] = ((const half8*)(hbuf + (size_t)s*INT_DIM))[l];
                }
            }
            #pragma unroll
            for(int k=0;k<8;k++) fma8(acc, v[k], wt[k]);
            if(more){
                #pragma unroll
                for(int k=0;k<8;k++){ v[k]=nv[k]; wt[k]=nw[k]; }
            }
        }
    }
    #pragma unroll
    for(int off=1; off<64; off<<=1) dpart += __shfl_xor(dpart, off);
    float dn = dpart + 1e-16f;
    const float4* bp = (const float4*)bias;
    float4 ba0 = bp[2*l], ba1 = bp[2*l+1];    // bias[8l .. 8l+7]
    float bb[8] = {ba0.x,ba0.y,ba0.z,ba0.w, ba1.x,ba1.y,ba1.z,ba1.w};
    bf16x8 hi, lo;
    #pragma unroll
    for(int k=0;k<8;k++){
        float vv = fmaxf(acc[k]/dn + bb[k], 0.f);
        short hv = f2bf(vv); hi[k]=hv; lo[k]=f2bf(vv - bf2f(hv));
    }
    size_t o = (size_t)node*INT_DIM + 8*l;
    *(bf16x8*)(oh + o) = hi;
    *(bf16x8*)(ol + o) = lo;
}

// ---------------- single-pass fp16 MFMA GEMM, 8 waves (2x4), 128x128 tile, dbuf 2-phase ----------------
template<int FUSE>
__global__ __launch_bounds__(512, 4) void mfma16_gemm_kernel(
    const _Float16* __restrict__ A, int lda, int za,
    const _Float16* __restrict__ B, int ldb, int zb,
    const float* __restrict__ bias, _Float16* __restrict__ O,
    int ldc, int zc, int K, int gx)
{
    __shared__ _Float16 lA[2][128*32];   // 8 KB per buffer
    __shared__ _Float16 lB[2][128*32];
    const int tid  = threadIdx.x;
    const int lane = tid & 63;
    const int w    = tid >> 6;      // 0..7
    const int wm   = w >> 2;        // 0..1 (row half)
    const int wn   = w & 3;         // 0..3 (col quarter)
    const int z    = blockIdx.z;

    // XCD-bijective swizzle
    const int nwg = gridDim.x;
    const int q = nwg >> 3, r = nwg & 7;
    const int xcd = blockIdx.x & 7, idx = blockIdx.x >> 3;
    const int wgid = (xcd < r ? xcd*(q+1) : r*(q+1) + (xcd-r)*q) + idx;
    const int row0 = (wgid / gx) * 128, col0 = (wgid % gx) * 128;

    f32x4 acc[4][2];
    #pragma unroll
    for(int i=0;i<4;i++)
        #pragma unroll
        for(int j=0;j<2;j++) acc[i][j] = (f32x4){0.f,0.f,0.f,0.f};

    // staging: 512 lanes cover 128 rows x 4 slots of 16B; LDS slot written = tid&3
    const int rr1 = tid >> 2;                        // 0..127
    const int ss1 = (tid & 3) ^ ((rr1 >> 1) & 3);    // swizzled global slot
    const size_t aoff = (size_t)(row0 + rr1) * lda + (size_t)z*za + ss1 * 8;
    const size_t boff = (size_t)(col0 + rr1) * ldb + (size_t)z*zb + ss1 * 8;

    typedef __attribute__((address_space(3))) char lds_char;
    lds_char* dA = (lds_char*)(&lA[0][0]) + w*1024;
    lds_char* dB = (lds_char*)(&lB[0][0]) + w*1024;

    int arow[4], brow[2];
    const int slotx = ((lane >> 4) ^ ((lane >> 1) & 3)) << 4;
    #pragma unroll
    for(int i=0;i<4;i++)
        arow[i] = (wm*64 + i*16 + (lane & 15)) * 64 + slotx;
    #pragma unroll
    for(int j=0;j<2;j++)
        brow[j] = (wn*32 + j*16 + (lane & 15)) * 64 + slotx;

    #define GLDS(src, dst) __builtin_amdgcn_global_load_lds( \
        (__attribute__((address_space(1))) void*)(src), \
        (__attribute__((address_space(3))) void*)(dst), 16, 0, 0)
    GLDS(A + aoff, dA);
    GLDS(B + boff, dB);
    __syncthreads();

    #pragma unroll 1
    for(int k0 = 0, kb = 0; k0 < K; k0 += 32, kb ^= 1){
        if(k0 + 32 < K){
            const int nb = kb ^ 1;
            GLDS(A + aoff + k0 + 32, dA + nb*8192);
            GLDS(B + boff + k0 + 32, dB + nb*8192);
        }
        const char* pA = (const char*)(&lA[0][0]) + kb*8192;
        const char* pB = (const char*)(&lB[0][0]) + kb*8192;
        half8 af[4];
        #pragma unroll
        for(int i=0;i<4;i++) af[i] = *(const half8*)(pA + arow[i]);
        #pragma unroll
        for(int j=0;j<2;j++){
            half8 bf = *(const half8*)(pB + brow[j]);
            #pragma unroll
            for(int i=0;i<4;i++)
                acc[i][j] = __builtin_amdgcn_mfma_f32_16x16x32_f16(af[i], bf, acc[i][j], 0, 0, 0);
        }
        __syncthreads();
    }
    #undef GLDS

    // epilogue: C/D layout col=lane&15, row=(lane>>4)*4+reg
    #pragma unroll
    for(int i=0;i<4;i++){
        const int rr = row0 + wm*64 + i*16 + ((lane >> 4) << 2);
        #pragma unroll
        for(int j=0;j<2;j++){
            const int gc = z*zc + col0 + wn*32 + j*16 + (lane & 15);
            float b = FUSE ? bias[gc] : 0.f;
            #pragma unroll
            for(int rg=0;rg<4;rg++){
                float v = acc[i][j][rg];
                if(FUSE) v = fmaxf(v + b, 0.f);
                O[(size_t)(rr + rg) * ldc + gc] = (_Float16)v;
            }
        }
    }
}

// ---------------- fused split-bf16 MFMA GEMM (Wl path), 8 waves, dbuf 2-phase, fp32 out ----------------
__global__ __launch_bounds__(512, 4) void mfma_gemm_kernel(
    const short* __restrict__ Ah, const short* __restrict__ Al, int lda,
    const short* __restrict__ Bh, const short* __restrict__ Bl, int ldb,
    const float* __restrict__ bias, float* __restrict__ C,
    int ldc, int K, int gx)
{
    __shared__ short lAh[2][128*32];
    __shared__ short lAl[2][128*32];
    __shared__ short lBh[2][128*32];
    __shared__ short lBl[2][128*32];
    const int tid  = threadIdx.x;
    const int lane = tid & 63;
    const int w    = tid >> 6;
    const int wm   = w >> 2;
    const int wn   = w & 3;

    const int nwg = gridDim.x;
    const int q = nwg >> 3, r = nwg & 7;
    const int xcd = blockIdx.x & 7, idx = blockIdx.x >> 3;
    const int wgid = (xcd < r ? xcd*(q+1) : r*(q+1) + (xcd-r)*q) + idx;
    const int row0 = (wgid / gx) * 128, col0 = (wgid % gx) * 128;

    f32x4 acc[4][2];
    #pragma unroll
    for(int i=0;i<4;i++)
        #pragma unroll
        for(int j=0;j<2;j++) acc[i][j] = (f32x4){0.f,0.f,0.f,0.f};

    const int rr1 = tid >> 2;
    const int ss1 = (tid & 3) ^ ((rr1 >> 1) & 3);
    const size_t aoff = (size_t)(row0 + rr1) * lda + ss1 * 8;
    const size_t boff = (size_t)(col0 + rr1) * ldb + ss1 * 8;

    typedef __attribute__((address_space(3))) char lds_char;
    lds_char* dAh = (lds_char*)(&lAh[0][0]) + w*1024;
    lds_char* dAl = (lds_char*)(&lAl[0][0]) + w*1024;
    lds_char* dBh = (lds_char*)(&lBh[0][0]) + w*1024;
    lds_char* dBl = (lds_char*)(&lBl[0][0]) + w*1024;

    int arow[4], brow[2];
    const int slotx = ((lane >> 4) ^ ((lane >> 1) & 3)) << 4;
    #pragma unroll
    for(int i=0;i<4;i++)
        arow[i] = (wm*64 + i*16 + (lane & 15)) * 64 + slotx;
    #pragma unroll
    for(int j=0;j<2;j++)
        brow[j] = (wn*32 + j*16 + (lane & 15)) * 64 + slotx;

    #define GLDS(src, dst) __builtin_amdgcn_global_load_lds( \
        (__attribute__((address_space(1))) void*)(src), \
        (__attribute__((address_space(3))) void*)(dst), 16, 0, 0)
    GLDS(Ah + aoff, dAh);
    GLDS(Al + aoff, dAl);
    GLDS(Bh + boff, dBh);
    GLDS(Bl + boff, dBl);
    __syncthreads();

    #pragma unroll 1
    for(int k0 = 0, kb = 0; k0 < K; k0 += 32, kb ^= 1){
        if(k0 + 32 < K){
            const int nb = kb ^ 1;
            GLDS(Ah + aoff + k0 + 32, dAh + nb*8192);
            GLDS(Al + aoff + k0 + 32, dAl + nb*8192);
            GLDS(Bh + boff + k0 + 32, dBh + nb*8192);
            GLDS(Bl + boff + k0 + 32, dBl + nb*8192);
        }
        const char* pAh = (const char*)(&lAh[0][0]) + kb*8192;
        const char* pAl = (const char*)(&lAl[0][0]) + kb*8192;
        const char* pBh = (const char*)(&lBh[0][0]) + kb*8192;
        const char* pBl = (const char*)(&lBl[0][0]) + kb*8192;
        bf16x8 afh[4], afl[4];
        #pragma unroll
        for(int i=0;i<4;i++){
            afh[i] = *(const bf16x8*)(pAh + arow[i]);
            afl[i] = *(const bf16x8*)(pAl + arow[i]);
        }
        #pragma unroll
        for(int j=0;j<2;j++){
            bf16x8 bh = *(const bf16x8*)(pBh + brow[j]);
            bf16x8 bl = *(const bf16x8*)(pBl + brow[j]);
            #pragma unroll
            for(int i=0;i<4;i++){
                acc[i][j] = __builtin_amdgcn_mfma_f32_16x16x32_bf16(afh[i], bh, acc[i][j], 0, 0, 0);
                acc[i][j] = __builtin_amdgcn_mfma_f32_16x16x32_bf16(afh[i], bl, acc[i][j], 0, 0, 0);
                acc[i][j] = __builtin_amdgcn_mfma_f32_16x16x32_bf16(afl[i], bh, acc[i][j], 0, 0, 0);
            }
        }
        __syncthreads();
    }
    #undef GLDS

    #pragma unroll
    for(int i=0;i<4;i++){
        const int rr = row0 + wm*64 + i*16 + ((lane >> 4) << 2);
        #pragma unroll
        for(int j=0;j<2;j++){
            const int gc = col0 + wn*32 + j*16 + (lane & 15);
            float b = bias[gc];
            #pragma unroll
            for(int rg=0;rg<4;rg++){
                float v = fmaxf(acc[i][j][rg] + b, 0.f);
                C[(size_t)(rr + rg) * ldc + gc] = v;
            }
        }
    }
}

// ---------------- alpha from fp16 h: H=8, C=128 ----------------
__global__ __launch_bounds__(128) void alpha16_h8_kernel(const _Float16* __restrict__ hbuf,
                                                         const float* __restrict__ a_src,
                                                         const float* __restrict__ a_dst,
                                                         float* __restrict__ asrc, float* __restrict__ adst){
    int node = blockIdx.x;
    int t = threadIdx.x;          // 128 threads; features 8t..8t+7, head t>>4
    half8 v = ((const half8*)(hbuf + (size_t)node*F1))[t];
    const float4* ap = (const float4*)(a_src + 8*t);
    const float4* dp = (const float4*)(a_dst + 8*t);
    float4 a0 = ap[0], a1 = ap[1];
    float4 d0 = dp[0], d1 = dp[1];
    float av[8] = {a0.x,a0.y,a0.z,a0.w, a1.x,a1.y,a1.z,a1.w};
    float dv[8] = {d0.x,d0.y,d0.z,d0.w, d1.x,d1.y,d1.z,d1.w};
    float ps = 0.f, pd = 0.f;
    #pragma unroll
    for(int k=0;k<8;k++){
        float f = (float)v[k];
        ps += f * av[k];
        pd += f * dv[k];
    }
    #pragma unroll
    for(int off=8; off; off>>=1){ ps += __shfl_down(ps, off); pd += __shfl_down(pd, off); }
    if((t & 15) == 0){
        asrc[(size_t)node*8 + (t>>4)] = ps;
        adst[(size_t)node*8 + (t>>4)] = pd;
    }
}

// ---------------- alpha from fp16 h: H=1, C=512 ----------------
__global__ __launch_bounds__(128) void alpha16_h1_kernel(const _Float16* __restrict__ hbuf,
                                                         const float* __restrict__ a_src,
                                                         const float* __restrict__ a_dst,
                                                         float* __restrict__ asrc, float* __restrict__ adst){
    int node = blockIdx.x;
    int t = threadIdx.x;          // 128 threads; features 4t..4t+3
    half4 v = ((const half4*)(hbuf + (size_t)node*INT_DIM))[t];
    float4 a = ((const float4*)a_src)[t];
    float4 d = ((const float4*)a_dst)[t];
    float ps = (float)v[0]*a.x + (float)v[1]*a.y + (float)v[2]*a.z + (float)v[3]*a.w;
    float pd = (float)v[0]*d.x + (float)v[1]*d.y + (float)v[2]*d.z + (float)v[3]*d.w;
    #pragma unroll
    for(int off=32; off; off>>=1){ ps += __shfl_down(ps, off); pd += __shfl_down(pd, off); }
    __shared__ float shs[2], shd[2];
    int wv = t >> 6;
    if((t & 63) == 0){ shs[wv] = ps; shd[wv] = pd; }
    __syncthreads();
    if(t == 0){
        asrc[node] = shs[0] + shs[1];
        adst[node] = shd[0] + shd[1];
    }
}

// ---------------- classifier: out[n,3] = h[n,:512] @ Wc + bc ----------------
__global__ __launch_bounds__(256) void cls_kernel(const float* __restrict__ h, const float* __restrict__ Wc,
                                                  const float* __restrict__ bc, float* __restrict__ out, int n){
    int node = blockIdx.x*4 + (threadIdx.x >> 6);
    int lane = threadIdx.x & 63;
    if(node >= n) return;
    float s0=0.f, s1=0.f, s2=0.f;
    const float* hr = h + (size_t)node*INT_DIM;
    for(int k=lane; k<INT_DIM; k+=64){
        float v = hr[k];
        s0 += v * Wc[k*3+0];
        s1 += v * Wc[k*3+1];
        s2 += v * Wc[k*3+2];
    }
    #pragma unroll
    for(int off=32; off; off>>=1){
        s0 += __shfl_down(s0, off);
        s1 += __shfl_down(s1, off);
        s2 += __shfl_down(s2, off);
    }
    if(lane==0){
        out[(size_t)node*3+0] = s0 + bc[0];
        out[(size_t)node*3+1] = s1 + bc[1];
        out[(size_t)node*3+2] = s2 + bc[2];
    }
}

extern "C" void kernel_launch(void* const* d_in, const int* in_sizes, int n_in,
                              void* d_out, int out_size, void* d_ws, size_t ws_size,
                              hipStream_t stream){
    const float* x      = (const float*)d_in[0];
    const int*   ei     = (const int*)d_in[1];
    const float* W1     = (const float*)d_in[2];
    const float* a_src1 = (const float*)d_in[3];
    const float* a_dst1 = (const float*)d_in[4];
    const float* b1     = (const float*)d_in[5];
    const float* W2     = (const float*)d_in[6];
    const float* a_src2 = (const float*)d_in[7];
    const float* a_dst2 = (const float*)d_in[8];
    const float* b2     = (const float*)d_in[9];
    const float* W3     = (const float*)d_in[10];
    const float* a_src3 = (const float*)d_in[11];
    const float* a_dst3 = (const float*)d_in[12];
    const float* b3     = (const float*)d_in[13];
    const float* Wl     = (const float*)d_in[14];
    const float* bl     = (const float*)d_in[15];
    const float* Wc     = (const float*)d_in[16];
    const float* bc     = (const float*)d_in[17];
    float* out = (float*)d_out;

    const int* src = ei;
    const int* dst = ei + EE;

    // workspace carve: two big regions (41.4 MB each) + weights + small
    char* p = (char*)d_ws;
    char* regA = p;  p += (size_t)MPAD*F1*4;            // fp16 arrays / fp32 Af
    char* regB = p;  p += (size_t)MPAD*F1*4;            // fp16 arrays / split pair {qh,ql}
    short* wt_h = (short*)p;  p += (size_t)F1*F1*2;     // 2.1 MB (also wt16 region)
    short* wt_l = (short*)p;  p += (size_t)F1*F1*2;     // 2.1 MB
    float* aw1  = (float*)p;  p += 16*IN_DIM*4;
    float* asrc = (float*)p;  p += (size_t)NN*HEADS*4;
    float* adst = (float*)p;  p += (size_t)NN*HEADS*4;
    int* cnt    = (int*)p;    p += NN*4;
    int* rowp   = (int*)p;    p += (NN+1)*4;
    int* cursor = (int*)p;    p += NN*4;
    int* colsrc = (int*)p;    p += EE*4;

    _Float16* hA = (_Float16*)regA;      // xa -> h2 -> h3
    _Float16* hB = (_Float16*)regB;      // out1 -> out2
    float* Af = (float*)regA;            // Wl output (fp32)
    short* qh = (short*)regB;  short* ql = qh + (size_t)MPAD*INT_DIM;   // agg3 split out
    _Float16* wt16 = (_Float16*)wt_h;    // fp16 transposed weights (W1/W2/W3)

    // ---- CSR build (by dst) ----
    hipMemsetAsync(cnt, 0, NN*sizeof(int), stream);
    count_kernel<<<(EE+255)/256, 256, 0, stream>>>(dst, EE, cnt);
    scan_kernel<<<1, 256, 0, stream>>>(cnt, rowp, cursor, NN);
    fill_kernel<<<(EE+255)/256, 256, 0, stream>>>(src, dst, EE, cursor, colsrc);

    // ---- Layer 1 (agg-first via linearity) ----
    splitT16_kernel<<<dim3(F1/32, IN_DIM/32), 256, 0, stream>>>(W1, wt16, IN_DIM, F1);
    aw1_kernel<<<8, 256, 0, stream>>>(W1, a_src1, a_dst1, aw1);
    alpha1_kernel<<<NN/16, 256, 0, stream>>>(x, aw1, asrc, adst);
    agg1_kernel<<<NN/4, 256, 0, stream>>>(x, asrc, adst, rowp, colsrc, hA);
    // out1 = relu(xa @ W1 + b1), block-diagonal per head -> hB (fp16)
    mfma16_gemm_kernel<1><<<dim3(MPAD/128, 1, HEADS), 512, 0, stream>>>(
        hA, F1, 128,  wt16, IN_DIM, 128*IN_DIM,
        b1, hB, F1, 128,  IN_DIM, 1);

    // ---- Layer 2 (project-first, fp16) ----
    splitT16_kernel<<<dim3(F1/32, F1/32), 256, 0, stream>>>(W2, wt16, F1, F1);
    mfma16_gemm_kernel<0><<<dim3((F1/128)*(MPAD/128), 1, 1), 512, 0, stream>>>(
        hB, F1, 0,  wt16, F1, 0,
        nullptr, hA, F1, 0,  F1, F1/128);
    alpha16_h8_kernel<<<NN, 128, 0, stream>>>(hA, a_src2, a_dst2, asrc, adst);
    agg2_kernel<<<NN/4, 256, 0, stream>>>(hA, asrc, adst, rowp, colsrc, b2, hB);

    // ---- Layer 3 (project-first, H=1, fp16) ----
    splitT16_kernel<<<dim3(INT_DIM/32, F1/32), 256, 0, stream>>>(W3, wt16, F1, INT_DIM);
    mfma16_gemm_kernel<0><<<dim3((INT_DIM/128)*(MPAD/128), 1, 1), 512, 0, stream>>>(
        hB, F1, 0,  wt16, F1, 0,
        nullptr, hA, INT_DIM, 0,  F1, INT_DIM/128);
    alpha16_h1_kernel<<<NN, 128, 0, stream>>>(hA, a_src3, a_dst3, asrc, adst);
    agg3_kernel<<<NN/4, 256, 0, stream>>>(hA, asrc, adst, rowp, colsrc, b3, qh, ql);

    // ---- Linear: relu(out3 @ Wl + bl) -> Af fp32 [NN,512] (split-bf16 3-pass for accuracy) ----
    splitT_kernel<<<dim3(INT_DIM/32, INT_DIM/32), 256, 0, stream>>>(Wl, wt_h, wt_l, INT_DIM, INT_DIM);
    mfma_gemm_kernel<<<dim3((INT_DIM/128)*(MPAD/128), 1, 1), 512, 0, stream>>>(
        qh, ql, INT_DIM,  wt_h, wt_l, INT_DIM,
        bl, Af, INT_DIM,  INT_DIM, INT_DIM/128);

    // ---- Classifier ----
    cls_kernel<<<(NN+3)/4, 256, 0, stream>>>(Af, Wc, bc, out, NN);
}

// Round 12
// 297.516 us; speedup vs baseline: 1.6135x; 1.0302x over previous
//
#include <hip/hip_runtime.h>
#include <hip/hip_bf16.h>

// Problem constants
#define NN 10000
#define EE 160000
#define IN_DIM 128
#define HID 128
#define HEADS 8
#define F1 (HEADS*HID)   // 1024
#define INT_DIM 512
#define OUT_DIM 3
#define MPAD 10112       // 79 * 128

typedef __attribute__((ext_vector_type(4))) float f32x4;
typedef __attribute__((ext_vector_type(8))) _Float16 half8;
typedef __attribute__((ext_vector_type(4))) _Float16 half4;
typedef __attribute__((ext_vector_type(2))) _Float16 half2v;

// wave-local LDS fence: wait all this wave's DS ops, and pin program order
#define WAVE_SYNC() do { asm volatile("s_waitcnt lgkmcnt(0)" ::: "memory"); \
                         __builtin_amdgcn_sched_barrier(0); } while(0)

// ---------------- CSR build ----------------
__global__ __launch_bounds__(256) void count_kernel(const int* __restrict__ dst, int E, int* __restrict__ cnt){
    int e = blockIdx.x*256 + threadIdx.x;
    if(e < E) atomicAdd(&cnt[dst[e]], 1);
}

__global__ __launch_bounds__(256) void scan_kernel(const int* __restrict__ cnt, int* __restrict__ rowp,
                                                   int* __restrict__ cursor, int n){
    __shared__ int sh[256];
    __shared__ int stotal;
    int t = threadIdx.x;
    if(t==0) stotal = 0;
    __syncthreads();
    for(int base=0; base<n; base+=256){
        int i = base + t;
        int v = (i<n) ? cnt[i] : 0;
        sh[t] = v;
        __syncthreads();
        #pragma unroll
        for(int off=1; off<256; off<<=1){
            int add = (t>=off) ? sh[t-off] : 0;
            __syncthreads();
            sh[t] += add;
            __syncthreads();
        }
        int excl = sh[t] - v;
        if(i<n){ rowp[i] = stotal + excl; cursor[i] = stotal + excl; }
        int chunk_total = sh[255];
        __syncthreads();
        if(t==0) stotal += chunk_total;
        __syncthreads();
    }
    if(t==0) rowp[n] = stotal;
}

__global__ __launch_bounds__(256) void fill_kernel(const int* __restrict__ src, const int* __restrict__ dst,
                                                   int E, int* __restrict__ cursor, int* __restrict__ colsrc){
    int e = blockIdx.x*256 + threadIdx.x;
    if(e < E){
        int d = dst[e];
        int pos = atomicAdd(&cursor[d], 1);
        colsrc[pos] = src[e];
    }
}

// ---------------- transpose weights to fp16: B[K,N] fp32 -> T [N,K] fp16 ----------------
__global__ __launch_bounds__(256) void splitT16_kernel(const float* __restrict__ B, _Float16* __restrict__ T,
                                                       int K, int N){
    __shared__ float tile[32][33];
    const int tx = threadIdx.x & 31, ty = threadIdx.x >> 5;   // 32 x 8
    const int n0 = blockIdx.x * 32, k0 = blockIdx.y * 32;
    #pragma unroll
    for(int i = 0; i < 32; i += 8)
        tile[ty + i][tx] = B[(size_t)(k0 + ty + i) * N + n0 + tx];
    __syncthreads();
    #pragma unroll
    for(int i = 0; i < 32; i += 8){
        int n = ty + i;
        T[(size_t)(n0 + n) * K + k0 + tx] = (_Float16)tile[tx][n];
    }
}

// ---------------- x fp32 -> fp16 ----------------
__global__ __launch_bounds__(256) void x16_kernel(const float* __restrict__ x, _Float16* __restrict__ x16, int n4){
    int i = blockIdx.x*256 + threadIdx.x;
    if(i >= n4) return;
    float4 v = ((const float4*)x)[i];
    half4 o = { (_Float16)v.x, (_Float16)v.y, (_Float16)v.z, (_Float16)v.w };
    ((half4*)x16)[i] = o;
}

// ---------------- aw1[j][k] = sum_c a[j][c] * W1[k, hj*128+c]  (j<8: a_src, j>=8: a_dst) ----------------
__global__ __launch_bounds__(256) void aw1_kernel(const float* __restrict__ W1,
                                                  const float* __restrict__ a_src,
                                                  const float* __restrict__ a_dst,
                                                  float* __restrict__ aw){
    int idx = blockIdx.x*256 + threadIdx.x;
    if(idx >= 16*IN_DIM) return;
    int j = idx >> 7, k = idx & 127;
    int hj = j & 7;
    const float* av = (j < 8 ? a_src : a_dst) + hj*HID;
    const float* wr = W1 + (size_t)k*F1 + hj*HID;
    float s = 0.f;
    #pragma unroll 4
    for(int c = 0; c < HID; c++) s += av[c] * wr[c];
    aw[idx] = s;
}

// ---------------- alpha1[n, j] = x[n,:] @ aw[j,:]  -> asrc/adst [NN,8] ----------------
__global__ __launch_bounds__(256) void alpha1_kernel(const float* __restrict__ x,
                                                     const float* __restrict__ aw,
                                                     float* __restrict__ asrc, float* __restrict__ adst){
    __shared__ float xs[16][128];
    __shared__ float aws[16][128];
    int t = threadIdx.x;
    int nb = blockIdx.x * 16;
    for(int i = t; i < 16*128; i += 256){
        xs[i >> 7][i & 127] = x[(size_t)nb*128 + i];
        aws[i >> 7][i & 127] = aw[i];
    }
    __syncthreads();
    int nl = t >> 4, j = t & 15;
    float s = 0.f;
    #pragma unroll 4
    for(int c = 0; c < 128; c++) s += xs[nl][c] * aws[j][c];
    int node = nb + nl;
    if(j < 8) asrc[node*8 + j] = s;
    else      adst[node*8 + (j-8)] = s;
}

// ---------------- agg1: per-head softmax-agg of fp16 x; 4 nodes/block, 1 wave/node; emits fp16 ----------------
__global__ __launch_bounds__(256) void agg1_kernel(const _Float16* __restrict__ x16,
                                                   const float* __restrict__ asrc,
                                                   const float* __restrict__ adst,
                                                   const int* __restrict__ rowp,
                                                   const int* __restrict__ colsrc,
                                                   _Float16* __restrict__ oa){
    const int w = threadIdx.x >> 6, l = threadIdx.x & 63;
    const int node = blockIdx.x*4 + w;
    __shared__ float sh_ee[4][64][8];
    int beg = rowp[node], end = rowp[node+1];
    float rd = adst[node*8 + (l & 7)];
    float acc0[8], acc1[8];
    #pragma unroll
    for(int h=0;h<8;h++){ acc0[h]=0.f; acc1[h]=0.f; }
    float dpart = 0.f;
    for(int base=beg; base<end; base+=64){
        int clen = min(64, end-base);
        WAVE_SYNC();                        // prior chunk's ee reads complete
        int sreg = (l < clen) ? colsrc[base + l] : 0;
        for(int it=l; it<clen*8; it+=64){
            int j = it >> 3;
            int s = colsrc[base + j];
            float e = asrc[s*8 + (l & 7)] + rd;
            e = (e > 0.f) ? e : 0.2f*e;
            float ee = expf(e);
            sh_ee[w][j][l & 7] = ee;
            dpart += ee;
        }
        WAVE_SYNC();                        // ee visible wave-wide
        #pragma unroll 2
        for(int j=0;j<clen;j++){
            int s = __shfl(sreg, j);
            half2v xv = ((const half2v*)(x16 + (size_t)s*128))[l];
            float x0 = (float)xv[0], x1 = (float)xv[1];
            #pragma unroll
            for(int h=0;h<8;h++){
                float wt = sh_ee[w][j][h];
                acc0[h] += wt * x0;
                acc1[h] += wt * x1;
            }
        }
    }
    dpart += __shfl_xor(dpart, 8);
    dpart += __shfl_xor(dpart, 16);
    dpart += __shfl_xor(dpart, 32);         // lane l holds denom for head l&7
    #pragma unroll
    for(int h=0;h<8;h++){
        float dn = __shfl(dpart, h) + 1e-16f;
        half2v o = { (_Float16)(acc0[h]/dn), (_Float16)(acc1[h]/dn) };
        *(half2v*)(oa + (size_t)node*F1 + h*128 + 2*l) = o;
    }
}

__device__ inline void fma8x2(float* acc, half8 v0, half8 v1, float w0, float w1){
    #pragma unroll
    for(int k=0;k<8;k++){
        acc[k]   += w0 * (float)v0[k];
        acc[8+k] += w1 * (float)v1[k];
    }
}
__device__ inline void fma8(float* acc, half8 v, float w){
    #pragma unroll
    for(int k=0;k<8;k++) acc[k] += w * (float)v[k];
}

// ---------------- agg2: softmax-agg of h2 fp16 [1024]; 1 wave/node, 4-edge pipelined; emits fp16 ----------------
__global__ __launch_bounds__(256) void agg2_kernel(const _Float16* __restrict__ hbuf,
                                                   const float* __restrict__ asrc,
                                                   const float* __restrict__ adst,
                                                   const int* __restrict__ rowp,
                                                   const int* __restrict__ colsrc,
                                                   const float* __restrict__ bias,
                                                   _Float16* __restrict__ oa){
    const int w = threadIdx.x >> 6, l = threadIdx.x & 63;
    const int node = blockIdx.x*4 + w;
    __shared__ float sh_ee[4][64][8];
    int beg = rowp[node], end = rowp[node+1];
    float rd = adst[node*8 + (l & 7)];
    float acc[16];
    #pragma unroll
    for(int k=0;k<16;k++) acc[k]=0.f;
    float dpart = 0.f;
    for(int base=beg; base<end; base+=64){
        int clen = min(64, end-base);
        int cpad = (clen + 3) & ~3;
        WAVE_SYNC();                        // prior chunk's ee reads complete
        int sreg = (l < clen) ? colsrc[base + l] : 0;
        // ee for rows [0, cpad) (zero-padded beyond clen)
        #pragma unroll 1
        for(int it=l; it<cpad*8; it+=64){
            int j = it >> 3;
            float ee = 0.f;
            if(j < clen){
                int s = colsrc[base + j];
                float e = asrc[s*8 + (l & 7)] + rd;
                e = (e > 0.f) ? e : 0.2f*e;
                ee = expf(e);
                dpart += ee;
            }
            sh_ee[w][j][l & 7] = ee;
        }
        WAVE_SYNC();                        // ee visible wave-wide
        // 4 edges in flight; each edge: 2 half8 chunks (features 8l.., 512+8l..)
        int sA=__shfl(sreg,0), sB=__shfl(sreg,1), sC=__shfl(sreg,2), sD=__shfl(sreg,3);
        const half8* pA=(const half8*)(hbuf+(size_t)sA*F1);
        const half8* pB=(const half8*)(hbuf+(size_t)sB*F1);
        const half8* pC=(const half8*)(hbuf+(size_t)sC*F1);
        const half8* pD=(const half8*)(hbuf+(size_t)sD*F1);
        half8 vA0=pA[l], vA1=pA[l+64];
        half8 vB0=pB[l], vB1=pB[l+64];
        half8 vC0=pC[l], vC1=pC[l+64];
        half8 vD0=pD[l], vD1=pD[l+64];
        const int h0 = l>>4, h1 = 4 + (l>>4);
        #pragma unroll 1
        for(int j0=0; j0<cpad; j0+=4){
            half8 nA0,nA1,nB0,nB1,nC0,nC1,nD0,nD1;
            const bool more = (j0+4 < cpad);
            if(more){
                int t0=__shfl(sreg,j0+4), t1=__shfl(sreg,j0+5), t2=__shfl(sreg,j0+6), t3=__shfl(sreg,j0+7);
                const half8* q0=(const half8*)(hbuf+(size_t)t0*F1);
                const half8* q1=(const half8*)(hbuf+(size_t)t1*F1);
                const half8* q2=(const half8*)(hbuf+(size_t)t2*F1);
                const half8* q3=(const half8*)(hbuf+(size_t)t3*F1);
                nA0=q0[l]; nA1=q0[l+64];
                nB0=q1[l]; nB1=q1[l+64];
                nC0=q2[l]; nC1=q2[l+64];
                nD0=q3[l]; nD1=q3[l+64];
            }
            fma8x2(acc, vA0, vA1, sh_ee[w][j0  ][h0], sh_ee[w][j0  ][h1]);
            fma8x2(acc, vB0, vB1, sh_ee[w][j0+1][h0], sh_ee[w][j0+1][h1]);
            fma8x2(acc, vC0, vC1, sh_ee[w][j0+2][h0], sh_ee[w][j0+2][h1]);
            fma8x2(acc, vD0, vD1, sh_ee[w][j0+3][h0], sh_ee[w][j0+3][h1]);
            if(more){
                vA0=nA0; vA1=nA1; vB0=nB0; vB1=nB1;
                vC0=nC0; vC1=nC1; vD0=nD0; vD1=nD1;
            }
        }
    }
    dpart += __shfl_xor(dpart, 8);
    dpart += __shfl_xor(dpart, 16);
    dpart += __shfl_xor(dpart, 32);
    float dn0 = __shfl(dpart, l>>4) + 1e-16f;
    float dn1 = __shfl(dpart, 4 + (l>>4)) + 1e-16f;
    const float4* bp = (const float4*)bias;
    float4 ba0 = bp[2*l],       ba1 = bp[2*l+1];       // bias[8l .. 8l+7]
    float4 bc0 = bp[128 + 2*l], bc1 = bp[128 + 2*l+1]; // bias[512+8l ..]
    float bb0[8] = {ba0.x,ba0.y,ba0.z,ba0.w, ba1.x,ba1.y,ba1.z,ba1.w};
    float bb1[8] = {bc0.x,bc0.y,bc0.z,bc0.w, bc1.x,bc1.y,bc1.z,bc1.w};
    half8 o0, o1;
    #pragma unroll
    for(int k=0;k<8;k++){
        o0[k] = (_Float16)fmaxf(acc[k]/dn0 + bb0[k], 0.f);
        o1[k] = (_Float16)fmaxf(acc[8+k]/dn1 + bb1[k], 0.f);
    }
    size_t off0 = (size_t)node*F1 + 8*l;
    *(half8*)(oa + off0) = o0;
    *(half8*)(oa + off0 + 512) = o1;
}

// ---------------- agg3: softmax-agg of h3 fp16 [512] H=1; emits fp16 ----------------
__global__ __launch_bounds__(256) void agg3_kernel(const _Float16* __restrict__ hbuf,
                                                   const float* __restrict__ asrc,
                                                   const float* __restrict__ adst,
                                                   const int* __restrict__ rowp,
                                                   const int* __restrict__ colsrc,
                                                   const float* __restrict__ bias,
                                                   _Float16* __restrict__ oa){
    const int w = threadIdx.x >> 6, l = threadIdx.x & 63;
    const int node = blockIdx.x*4 + w;
    int beg = rowp[node], end = rowp[node+1];
    float rd = adst[node];
    float acc[8];
    #pragma unroll
    for(int k=0;k<8;k++) acc[k]=0.f;
    float dpart = 0.f;
    for(int base=beg; base<end; base+=64){
        int clen = min(64, end-base);
        int sreg = 0; float eereg = 0.f;
        if(l < clen){
            sreg = colsrc[base + l];
            float e = asrc[sreg] + rd;
            e = (e > 0.f) ? e : 0.2f*e;
            eereg = expf(e);
            dpart += eereg;
        }
        int cpad = (clen + 7) & ~7;
        half8 v[8];
        float wt[8];
        #pragma unroll
        for(int k=0;k<8;k++){
            int s = __shfl(sreg, k);
            wt[k] = __shfl(eereg, k);
            v[k] = ((const half8*)(hbuf + (size_t)s*INT_DIM))[l];
        }
        #pragma unroll 1
        for(int j0=0; j0<cpad; j0+=8){
            half8 nv[8]; float nw[8];
            const bool more = (j0+8 < cpad);
            if(more){
                #pragma unroll
                for(int k=0;k<8;k++){
                    int s = __shfl(sreg, j0+8+k);
                    nw[k] = __shfl(eereg, j0+8+k);
                    nv[k] = ((const half8*)(hbuf + (size_t)s*INT_DIM))[l];
                }
            }
            #pragma unroll
            for(int k=0;k<8;k++) fma8(acc, v[k], wt[k]);
            if(more){
                #pragma unroll
                for(int k=0;k<8;k++){ v[k]=nv[k]; wt[k]=nw[k]; }
            }
        }
    }
    #pragma unroll
    for(int off=1; off<64; off<<=1) dpart += __shfl_xor(dpart, off);
    float dn = dpart + 1e-16f;
    const float4* bp = (const float4*)bias;
    float4 ba0 = bp[2*l], ba1 = bp[2*l+1];    // bias[8l .. 8l+7]
    float bb[8] = {ba0.x,ba0.y,ba0.z,ba0.w, ba1.x,ba1.y,ba1.z,ba1.w};
    half8 o;
    #pragma unroll
    for(int k=0;k<8;k++)
        o[k] = (_Float16)fmaxf(acc[k]/dn + bb[k], 0.f);
    *(half8*)(oa + (size_t)node*INT_DIM + 8*l) = o;
}

// ---------------- single-pass fp16 MFMA GEMM, 8 waves (2x4), 128x128 tile, dbuf 2-phase ----------------
template<int FUSE>
__global__ __launch_bounds__(512, 4) void mfma16_gemm_kernel(
    const _Float16* __restrict__ A, int lda, int za,
    const _Float16* __restrict__ B, int ldb, int zb,
    const float* __restrict__ bias, _Float16* __restrict__ O,
    int ldc, int zc, int K, int gx)
{
    __shared__ _Float16 lA[2][128*32];   // 8 KB per buffer
    __shared__ _Float16 lB[2][128*32];
    const int tid  = threadIdx.x;
    const int lane = tid & 63;
    const int w    = tid >> 6;      // 0..7
    const int wm   = w >> 2;        // 0..1 (row half)
    const int wn   = w & 3;         // 0..3 (col quarter)
    const int z    = blockIdx.z;

    // XCD-bijective swizzle
    const int nwg = gridDim.x;
    const int q = nwg >> 3, r = nwg & 7;
    const int xcd = blockIdx.x & 7, idx = blockIdx.x >> 3;
    const int wgid = (xcd < r ? xcd*(q+1) : r*(q+1) + (xcd-r)*q) + idx;
    const int row0 = (wgid / gx) * 128, col0 = (wgid % gx) * 128;

    f32x4 acc[4][2];
    #pragma unroll
    for(int i=0;i<4;i++)
        #pragma unroll
        for(int j=0;j<2;j++) acc[i][j] = (f32x4){0.f,0.f,0.f,0.f};

    // staging: 512 lanes cover 128 rows x 4 slots of 16B; LDS slot written = tid&3
    const int rr1 = tid >> 2;                        // 0..127
    const int ss1 = (tid & 3) ^ ((rr1 >> 1) & 3);    // swizzled global slot
    const size_t aoff = (size_t)(row0 + rr1) * lda + (size_t)z*za + ss1 * 8;
    const size_t boff = (size_t)(col0 + rr1) * ldb + (size_t)z*zb + ss1 * 8;

    typedef __attribute__((address_space(3))) char lds_char;
    lds_char* dA = (lds_char*)(&lA[0][0]) + w*1024;
    lds_char* dB = (lds_char*)(&lB[0][0]) + w*1024;

    int arow[4], brow[2];
    const int slotx = ((lane >> 4) ^ ((lane >> 1) & 3)) << 4;
    #pragma unroll
    for(int i=0;i<4;i++)
        arow[i] = (wm*64 + i*16 + (lane & 15)) * 64 + slotx;
    #pragma unroll
    for(int j=0;j<2;j++)
        brow[j] = (wn*32 + j*16 + (lane & 15)) * 64 + slotx;

    #define GLDS(src, dst) __builtin_amdgcn_global_load_lds( \
        (__attribute__((address_space(1))) void*)(src), \
        (__attribute__((address_space(3))) void*)(dst), 16, 0, 0)
    GLDS(A + aoff, dA);
    GLDS(B + boff, dB);
    __syncthreads();

    #pragma unroll 1
    for(int k0 = 0, kb = 0; k0 < K; k0 += 32, kb ^= 1){
        if(k0 + 32 < K){
            const int nb = kb ^ 1;
            GLDS(A + aoff + k0 + 32, dA + nb*8192);
            GLDS(B + boff + k0 + 32, dB + nb*8192);
        }
        const char* pA = (const char*)(&lA[0][0]) + kb*8192;
        const char* pB = (const char*)(&lB[0][0]) + kb*8192;
        half8 af[4];
        #pragma unroll
        for(int i=0;i<4;i++) af[i] = *(const half8*)(pA + arow[i]);
        #pragma unroll
        for(int j=0;j<2;j++){
            half8 bf = *(const half8*)(pB + brow[j]);
            #pragma unroll
            for(int i=0;i<4;i++)
                acc[i][j] = __builtin_amdgcn_mfma_f32_16x16x32_f16(af[i], bf, acc[i][j], 0, 0, 0);
        }
        __syncthreads();
    }
    #undef GLDS

    // epilogue: C/D layout col=lane&15, row=(lane>>4)*4+reg
    #pragma unroll
    for(int i=0;i<4;i++){
        const int rr = row0 + wm*64 + i*16 + ((lane >> 4) << 2);
        #pragma unroll
        for(int j=0;j<2;j++){
            const int gc = z*zc + col0 + wn*32 + j*16 + (lane & 15);
            float b = FUSE ? bias[gc] : 0.f;
            #pragma unroll
            for(int rg=0;rg<4;rg++){
                float v = acc[i][j][rg];
                if(FUSE) v = fmaxf(v + b, 0.f);
                O[(size_t)(rr + rg) * ldc + gc] = (_Float16)v;
            }
        }
    }
}

// ---------------- alpha from fp16 h: H=8, C=128 ----------------
__global__ __launch_bounds__(128) void alpha16_h8_kernel(const _Float16* __restrict__ hbuf,
                                                         const float* __restrict__ a_src,
                                                         const float* __restrict__ a_dst,
                                                         float* __restrict__ asrc, float* __restrict__ adst){
    int node = blockIdx.x;
    int t = threadIdx.x;          // 128 threads; features 8t..8t+7, head t>>4
    half8 v = ((const half8*)(hbuf + (size_t)node*F1))[t];
    const float4* ap = (const float4*)(a_src + 8*t);
    const float4* dp = (const float4*)(a_dst + 8*t);
    float4 a0 = ap[0], a1 = ap[1];
    float4 d0 = dp[0], d1 = dp[1];
    float av[8] = {a0.x,a0.y,a0.z,a0.w, a1.x,a1.y,a1.z,a1.w};
    float dv[8] = {d0.x,d0.y,d0.z,d0.w, d1.x,d1.y,d1.z,d1.w};
    float ps = 0.f, pd = 0.f;
    #pragma unroll
    for(int k=0;k<8;k++){
        float f = (float)v[k];
        ps += f * av[k];
        pd += f * dv[k];
    }
    #pragma unroll
    for(int off=8; off; off>>=1){ ps += __shfl_down(ps, off); pd += __shfl_down(pd, off); }
    if((t & 15) == 0){
        asrc[(size_t)node*8 + (t>>4)] = ps;
        adst[(size_t)node*8 + (t>>4)] = pd;
    }
}

// ---------------- alpha from fp16 h: H=1, C=512 ----------------
__global__ __launch_bounds__(128) void alpha16_h1_kernel(const _Float16* __restrict__ hbuf,
                                                         const float* __restrict__ a_src,
                                                         const float* __restrict__ a_dst,
                                                         float* __restrict__ asrc, float* __restrict__ adst){
    int node = blockIdx.x;
    int t = threadIdx.x;          // 128 threads; features 4t..4t+3
    half4 v = ((const half4*)(hbuf + (size_t)node*INT_DIM))[t];
    float4 a = ((const float4*)a_src)[t];
    float4 d = ((const float4*)a_dst)[t];
    float ps = (float)v[0]*a.x + (float)v[1]*a.y + (float)v[2]*a.z + (float)v[3]*a.w;
    float pd = (float)v[0]*d.x + (float)v[1]*d.y + (float)v[2]*d.z + (float)v[3]*d.w;
    #pragma unroll
    for(int off=32; off; off>>=1){ ps += __shfl_down(ps, off); pd += __shfl_down(pd, off); }
    __shared__ float shs[2], shd[2];
    int wv = t >> 6;
    if((t & 63) == 0){ shs[wv] = ps; shd[wv] = pd; }
    __syncthreads();
    if(t == 0){
        asrc[node] = shs[0] + shs[1];
        adst[node] = shd[0] + shd[1];
    }
}

// ---------------- classifier: out[n,3] = h16[n,:512] @ Wc + bc ----------------
__global__ __launch_bounds__(256) void cls16_kernel(const _Float16* __restrict__ h, const float* __restrict__ Wc,
                                                    const float* __restrict__ bc, float* __restrict__ out, int n){
    int node = blockIdx.x*4 + (threadIdx.x >> 6);
    int lane = threadIdx.x & 63;
    if(node >= n) return;
    half8 v = ((const half8*)(h + (size_t)node*INT_DIM))[lane];  // features 8l..8l+7
    float s0=0.f, s1=0.f, s2=0.f;
    #pragma unroll
    for(int k=0;k<8;k++){
        float f = (float)v[k];
        const float* wr = Wc + (8*lane + k)*3;
        s0 += f * wr[0];
        s1 += f * wr[1];
        s2 += f * wr[2];
    }
    #pragma unroll
    for(int off=32; off; off>>=1){
        s0 += __shfl_down(s0, off);
        s1 += __shfl_down(s1, off);
        s2 += __shfl_down(s2, off);
    }
    if(lane==0){
        out[(size_t)node*3+0] = s0 + bc[0];
        out[(size_t)node*3+1] = s1 + bc[1];
        out[(size_t)node*3+2] = s2 + bc[2];
    }
}

extern "C" void kernel_launch(void* const* d_in, const int* in_sizes, int n_in,
                              void* d_out, int out_size, void* d_ws, size_t ws_size,
                              hipStream_t stream){
    const float* x      = (const float*)d_in[0];
    const int*   ei     = (const int*)d_in[1];
    const float* W1     = (const float*)d_in[2];
    const float* a_src1 = (const float*)d_in[3];
    const float* a_dst1 = (const float*)d_in[4];
    const float* b1     = (const float*)d_in[5];
    const float* W2     = (const float*)d_in[6];
    const float* a_src2 = (const float*)d_in[7];
    const float* a_dst2 = (const float*)d_in[8];
    const float* b2     = (const float*)d_in[9];
    const float* W3     = (const float*)d_in[10];
    const float* a_src3 = (const float*)d_in[11];
    const float* a_dst3 = (const float*)d_in[12];
    const float* b3     = (const float*)d_in[13];
    const float* Wl     = (const float*)d_in[14];
    const float* bl     = (const float*)d_in[15];
    const float* Wc     = (const float*)d_in[16];
    const float* bc     = (const float*)d_in[17];
    float* out = (float*)d_out;

    const int* src = ei;
    const int* dst = ei + EE;

    // workspace carve
    char* p = (char*)d_ws;
    char* regA = p;  p += (size_t)MPAD*F1*4;            // fp16 ping
    char* regB = p;  p += (size_t)MPAD*F1*4;            // fp16 pong
    _Float16* wt16 = (_Float16*)p;  p += (size_t)F1*F1*2;   // 2.1 MB fp16 weights
    _Float16* x16  = (_Float16*)p;  p += (size_t)NN*IN_DIM*2; // 2.56 MB fp16 x
    float* aw1  = (float*)p;  p += 16*IN_DIM*4;
    float* asrc = (float*)p;  p += (size_t)NN*HEADS*4;
    float* adst = (float*)p;  p += (size_t)NN*HEADS*4;
    int* cnt    = (int*)p;    p += NN*4;
    int* rowp   = (int*)p;    p += (NN+1)*4;
    int* cursor = (int*)p;    p += NN*4;
    int* colsrc = (int*)p;    p += EE*4;

    _Float16* hA = (_Float16*)regA;      // xa -> h2 -> h3 -> Af
    _Float16* hB = (_Float16*)regB;      // out1 -> out2 -> out3

    // ---- CSR build (by dst) ----
    hipMemsetAsync(cnt, 0, NN*sizeof(int), stream);
    count_kernel<<<(EE+255)/256, 256, 0, stream>>>(dst, EE, cnt);
    scan_kernel<<<1, 256, 0, stream>>>(cnt, rowp, cursor, NN);
    fill_kernel<<<(EE+255)/256, 256, 0, stream>>>(src, dst, EE, cursor, colsrc);

    // ---- Layer 1 (agg-first via linearity) ----
    x16_kernel<<<(NN*IN_DIM/4 + 255)/256, 256, 0, stream>>>(x, x16, NN*IN_DIM/4);
    splitT16_kernel<<<dim3(F1/32, IN_DIM/32), 256, 0, stream>>>(W1, wt16, IN_DIM, F1);
    aw1_kernel<<<8, 256, 0, stream>>>(W1, a_src1, a_dst1, aw1);
    alpha1_kernel<<<NN/16, 256, 0, stream>>>(x, aw1, asrc, adst);
    agg1_kernel<<<NN/4, 256, 0, stream>>>(x16, asrc, adst, rowp, colsrc, hA);
    // out1 = relu(xa @ W1 + b1), block-diagonal per head -> hB (fp16)
    mfma16_gemm_kernel<1><<<dim3(MPAD/128, 1, HEADS), 512, 0, stream>>>(
        hA, F1, 128,  wt16, IN_DIM, 128*IN_DIM,
        b1, hB, F1, 128,  IN_DIM, 1);

    // ---- Layer 2 (project-first, fp16) ----
    splitT16_kernel<<<dim3(F1/32, F1/32), 256, 0, stream>>>(W2, wt16, F1, F1);
    mfma16_gemm_kernel<0><<<dim3((F1/128)*(MPAD/128), 1, 1), 512, 0, stream>>>(
        hB, F1, 0,  wt16, F1, 0,
        nullptr, hA, F1, 0,  F1, F1/128);
    alpha16_h8_kernel<<<NN, 128, 0, stream>>>(hA, a_src2, a_dst2, asrc, adst);
    agg2_kernel<<<NN/4, 256, 0, stream>>>(hA, asrc, adst, rowp, colsrc, b2, hB);

    // ---- Layer 3 (project-first, H=1, fp16) ----
    splitT16_kernel<<<dim3(INT_DIM/32, F1/32), 256, 0, stream>>>(W3, wt16, F1, INT_DIM);
    mfma16_gemm_kernel<0><<<dim3((INT_DIM/128)*(MPAD/128), 1, 1), 512, 0, stream>>>(
        hB, F1, 0,  wt16, F1, 0,
        nullptr, hA, INT_DIM, 0,  F1, INT_DIM/128);
    alpha16_h1_kernel<<<NN, 128, 0, stream>>>(hA, a_src3, a_dst3, asrc, adst);
    agg3_kernel<<<NN/4, 256, 0, stream>>>(hA, asrc, adst, rowp, colsrc, b3, hB);

    // ---- Linear: relu(out3 @ Wl + bl) -> hA fp16 [NN,512] ----
    splitT16_kernel<<<dim3(INT_DIM/32, INT_DIM/32), 256, 0, stream>>>(Wl, wt16, INT_DIM, INT_DIM);
    mfma16_gemm_kernel<1><<<dim3((INT_DIM/128)*(MPAD/128), 1, 1), 512, 0, stream>>>(
        hB, INT_DIM, 0,  wt16, INT_DIM, 0,
        bl, hA, INT_DIM, 0,  INT_DIM, INT_DIM/128);

    // ---- Classifier ----
    cls16_kernel<<<(NN+3)/4, 256, 0, stream>>>(hA, Wc, bc, out, NN);
}